// Round 2
// baseline (1460.708 us; speedup 1.0000x reference)
//
#include <hip/hip_runtime.h>

#define T_SEQ 2048
#define HID 4096
#define NH 32
#define NKV 8
#define HD 128
#define KDIM 4096

typedef unsigned short u16;
typedef __attribute__((ext_vector_type(4))) float f32x4;
typedef __attribute__((ext_vector_type(4))) int i32x4;
typedef __attribute__((ext_vector_type(8))) short s16x8;
typedef __attribute__((ext_vector_type(4))) short s16x4;
typedef __attribute__((ext_vector_type(8))) __bf16 bf16x8;

static __device__ __forceinline__ u16 f2bf(float f) {
    __bf16 b = (__bf16)f;
    return __builtin_bit_cast(unsigned short, b);
}
static __device__ __forceinline__ float bf2f(u16 b) {
    unsigned u = ((unsigned)b) << 16;
    return __builtin_bit_cast(float, u);
}

// ---------------- per-row int4 quant of hidden_states -> bf16 ints + scale ----
__global__ __launch_bounds__(256) void k_quant(const float* __restrict__ x,
                                               u16* __restrict__ qb,
                                               float* __restrict__ srow) {
    int row = blockIdx.x, tid = threadIdx.x;
    const float* xr = x + (size_t)row * HID;
    f32x4 v[4];
    float amax = 0.f;
#pragma unroll
    for (int i = 0; i < 4; ++i) {
        v[i] = *(const f32x4*)(xr + i * 1024 + tid * 4);
#pragma unroll
        for (int j = 0; j < 4; ++j) amax = fmaxf(amax, fabsf(v[i][j]));
    }
#pragma unroll
    for (int off = 32; off >= 1; off >>= 1)
        amax = fmaxf(amax, __shfl_xor(amax, off));
    __shared__ float red[4];
    if ((tid & 63) == 0) red[tid >> 6] = amax;
    __syncthreads();
    amax = fmaxf(fmaxf(red[0], red[1]), fmaxf(red[2], red[3]));
    float s = fmaxf(amax / 7.f, 1e-8f);
    if (tid == 0) srow[row] = s;
    u16* qr = qb + (size_t)row * HID;
#pragma unroll
    for (int i = 0; i < 4; ++i) {
        s16x4 o;
#pragma unroll
        for (int j = 0; j < 4; ++j) {
            float q = rintf(v[i][j] / s);
            q = fminf(fmaxf(q, -8.f), 7.f);
            o[j] = (short)f2bf(q);
        }
        *(s16x4*)(qr + i * 1024 + tid * 4) = o;
    }
}

// ---------------- bf16 MFMA GEMM: out[m][n] = sum_k A[m][k]*W[n][k] * sRow[m]*sCol[n]
// Integer-valued bf16 inputs -> fp32 MFMA accumulation is EXACT (sums < 2^24).
// MODE 0: f32 row-major out.  MODE 1: bf16 hi/lo transposed out (out[n][m]).
template <int MODE>
__global__ __launch_bounds__(256) void k_gemm(const u16* __restrict__ A,
        const int* __restrict__ W, const float* __restrict__ sRow,
        const float* __restrict__ sCol, void* __restrict__ outp,
        void* __restrict__ outp2, int M, int N, int K) {
    __shared__ u16 sA[128][72];  // +8 pad
    __shared__ u16 sB[128][72];
    int tid = threadIdx.x;
    int brow = blockIdx.x * 128, bcol = blockIdx.y * 128;
    int wid = tid >> 6, lane = tid & 63;
    int wr = (wid >> 1) * 64, wc = (wid & 1) * 64;
    int lr = lane & 15, lc = lane >> 4;
    f32x4 acc[4][4] = {};
    int arow = tid >> 3, acol = (tid & 7) * 8;
    int brr = tid >> 4, bcc = (tid & 15) * 4;
    for (int k0 = 0; k0 < K; k0 += 64) {
#pragma unroll
        for (int t = 0; t < 4; ++t) {
            int r = t * 32 + arow;
            *(s16x8*)&sA[r][acol] =
                *(const s16x8*)(A + (size_t)(brow + r) * K + k0 + acol);
        }
#pragma unroll
        for (int t = 0; t < 8; ++t) {
            int r = t * 16 + brr;
            i32x4 w = *(const i32x4*)(W + (size_t)(bcol + r) * K + k0 + bcc);
            s16x4 hh;
#pragma unroll
            for (int j = 0; j < 4; ++j) hh[j] = (short)f2bf((float)w[j]);
            *(s16x4*)&sB[r][bcc] = hh;
        }
        __syncthreads();
#pragma unroll
        for (int kk = 0; kk < 64; kk += 32) {
            bf16x8 af[4], bf[4];
#pragma unroll
            for (int m = 0; m < 4; ++m)
                af[m] = *(const bf16x8*)&sA[wr + m * 16 + lr][kk + lc * 8];
#pragma unroll
            for (int n = 0; n < 4; ++n)
                bf[n] = *(const bf16x8*)&sB[wc + n * 16 + lr][kk + lc * 8];
#pragma unroll
            for (int m = 0; m < 4; ++m)
#pragma unroll
                for (int n = 0; n < 4; ++n)
                    acc[m][n] = __builtin_amdgcn_mfma_f32_16x16x32_bf16(
                        af[m], bf[n], acc[m][n], 0, 0, 0);
        }
        __syncthreads();
    }
#pragma unroll
    for (int m = 0; m < 4; ++m) {
        int row0 = brow + wr + m * 16 + lc * 4;
#pragma unroll
        for (int n = 0; n < 4; ++n) {
            int col = bcol + wc + n * 16 + lr;
            float scl = sCol[col];
            if (MODE == 0) {
                float* o = (float*)outp;
#pragma unroll
                for (int r = 0; r < 4; ++r)
                    o[(size_t)(row0 + r) * N + col] =
                        acc[m][n][r] * sRow[row0 + r] * scl;
            } else {
                u16* oh = (u16*)outp;
                u16* ol = (u16*)outp2;
                s16x4 hh, ll;
#pragma unroll
                for (int r = 0; r < 4; ++r) {
                    float val = acc[m][n][r] * sRow[row0 + r] * scl;
                    u16 hb = f2bf(val);
                    hh[r] = (short)hb;
                    ll[r] = (short)f2bf(val - bf2f(hb));
                }
                *(s16x4*)(oh + (size_t)col * M + row0) = hh;
                *(s16x4*)(ol + (size_t)col * M + row0) = ll;
            }
        }
    }
}

// ---------------- RoPE: q rotated in-place (fp32); k -> hi/lo bf16 ----------
__global__ __launch_bounds__(256) void k_rope(float* __restrict__ qf,
        const float* __restrict__ kf, const int* __restrict__ pos,
        u16* __restrict__ khb, u16* __restrict__ klb) {
    int t = blockIdx.x, tid = threadIdx.x;
    float p = (float)pos[t];
    for (int idx = tid; idx < (NH + NKV) * 64; idx += 256) {
        int hd6 = idx >> 6, d = idx & 63;
        // correctly-rounded f32 inv_freq via double pow; f32 angle (matches np)
        float inv = (float)pow(10000.0, -(double)d / 64.0);
        float ang = p * inv;
        double dsn, dcs;
        sincos((double)ang, &dsn, &dcs);
        float sn = (float)dsn, cs = (float)dcs;
        if (hd6 < NH) {
            size_t base = (size_t)t * HID + hd6 * HD;
            float x1 = qf[base + d], x2 = qf[base + d + 64];
            qf[base + d] = x1 * cs - x2 * sn;
            qf[base + d + 64] = x2 * cs + x1 * sn;
        } else {
            size_t base = (size_t)t * (NKV * HD) + (hd6 - NH) * HD;
            float x1 = kf[base + d], x2 = kf[base + d + 64];
            float r1 = x1 * cs - x2 * sn;
            float r2 = x2 * cs + x1 * sn;
            u16 h1 = f2bf(r1);
            khb[base + d] = h1;
            klb[base + d] = f2bf(r1 - bf2f(h1));
            u16 h2 = f2bf(r2);
            khb[base + d + 64] = h2;
            klb[base + d + 64] = f2bf(r2 - bf2f(h2));
        }
    }
}

// ---------------- GQA causal flash attention, hi/lo split MFMA --------------
// grid = (T/64, NH); 4 waves/block, each wave owns 16 q rows independently.
// Q read fp32 (split in-register); output written IN-PLACE over Q region.
__global__ __launch_bounds__(256) void k_attn(float* __restrict__ qf,
        const u16* __restrict__ khb, const u16* __restrict__ klb,
        const u16* __restrict__ vhb, const u16* __restrict__ vlb) {
    int h = blockIdx.y, kvh = h >> 2;
    int tid = threadIdx.x, wid = tid >> 6, lane = tid & 63;
    int lr = lane & 15, lc = lane >> 4;
    int q0 = blockIdx.x * 64 + wid * 16;
    __shared__ u16 pbh[4][16][48], pbl[4][16][48];
    bf16x8 aqh[4], aql[4];
    {
        const float* qrow = qf + (size_t)(q0 + lr) * HID + h * HD;
#pragma unroll
        for (int dc = 0; dc < 4; ++dc)
#pragma unroll
            for (int j = 0; j < 8; ++j) {
                float v = qrow[dc * 32 + lc * 8 + j];
                u16 hb = f2bf(v);
                aqh[dc][j] = __builtin_bit_cast(__bf16, hb);
                aql[dc][j] = __builtin_bit_cast(__bf16, f2bf(v - bf2f(hb)));
            }
    }
    f32x4 oacc[8] = {};
    float m[4], l[4];
#pragma unroll
    for (int r = 0; r < 4; ++r) { m[r] = -1e30f; l[r] = 0.f; }
    int ntiles = ((q0 + 15) >> 5) + 1;
    for (int kt = 0; kt < ntiles; ++kt) {
        int k0 = kt * 32;
        f32x4 s[2] = {};
#pragma unroll
        for (int c = 0; c < 2; ++c) {
            size_t koff = (size_t)(k0 + c * 16 + lr) * (NKV * HD) + kvh * HD;
#pragma unroll
            for (int dc = 0; dc < 4; ++dc) {
                bf16x8 kfh = *(const bf16x8*)(khb + koff + dc * 32 + lc * 8);
                bf16x8 kfl = *(const bf16x8*)(klb + koff + dc * 32 + lc * 8);
                s[c] = __builtin_amdgcn_mfma_f32_16x16x32_bf16(aqh[dc], kfh, s[c], 0, 0, 0);
                s[c] = __builtin_amdgcn_mfma_f32_16x16x32_bf16(aql[dc], kfh, s[c], 0, 0, 0);
                s[c] = __builtin_amdgcn_mfma_f32_16x16x32_bf16(aqh[dc], kfl, s[c], 0, 0, 0);
                s[c] = __builtin_amdgcn_mfma_f32_16x16x32_bf16(aql[dc], kfl, s[c], 0, 0, 0);
            }
        }
        bool need_mask = (k0 + 31 > q0);
        float tmax[4] = {-1e30f, -1e30f, -1e30f, -1e30f};
#pragma unroll
        for (int c = 0; c < 2; ++c)
#pragma unroll
            for (int r = 0; r < 4; ++r) {
                float sv = s[c][r] * 0.08838834764831845f;
                if (need_mask) {
                    int key = k0 + c * 16 + lr, qr = q0 + lc * 4 + r;
                    if (key > qr) sv = -1e30f;
                }
                s[c][r] = sv;
                tmax[r] = fmaxf(tmax[r], sv);
            }
#pragma unroll
        for (int off = 1; off < 16; off <<= 1)
#pragma unroll
            for (int r = 0; r < 4; ++r)
                tmax[r] = fmaxf(tmax[r], __shfl_xor(tmax[r], off));
        float alpha[4], psum[4] = {0.f, 0.f, 0.f, 0.f};
#pragma unroll
        for (int r = 0; r < 4; ++r) {
            float mn = fmaxf(m[r], tmax[r]);
            alpha[r] = expf(m[r] - mn);
            m[r] = mn;
        }
#pragma unroll
        for (int c = 0; c < 2; ++c)
#pragma unroll
            for (int r = 0; r < 4; ++r) {
                float pv = expf(s[c][r] - m[r]);
                s[c][r] = pv;
                psum[r] += pv;
            }
#pragma unroll
        for (int off = 1; off < 16; off <<= 1)
#pragma unroll
            for (int r = 0; r < 4; ++r) psum[r] += __shfl_xor(psum[r], off);
#pragma unroll
        for (int r = 0; r < 4; ++r) l[r] = l[r] * alpha[r] + psum[r];
#pragma unroll
        for (int n = 0; n < 8; ++n)
#pragma unroll
            for (int r = 0; r < 4; ++r) oacc[n][r] *= alpha[r];
        // P (acc layout: col=key=lr, row=q=lc*4+r) -> LDS hi/lo -> A-operand
#pragma unroll
        for (int c = 0; c < 2; ++c)
#pragma unroll
            for (int r = 0; r < 4; ++r) {
                float pv = s[c][r];
                u16 hb = f2bf(pv);
                pbh[wid][lc * 4 + r][c * 16 + lr] = hb;
                pbl[wid][lc * 4 + r][c * 16 + lr] = f2bf(pv - bf2f(hb));
            }
        asm volatile("s_waitcnt lgkmcnt(0)" ::: "memory");
        bf16x8 pah = *(const bf16x8*)&pbh[wid][lr][lc * 8];
        bf16x8 pal = *(const bf16x8*)&pbl[wid][lr][lc * 8];
        size_t vbase = (size_t)(kvh * HD) * T_SEQ;
#pragma unroll
        for (int n = 0; n < 8; ++n) {
            size_t voff = vbase + (size_t)(n * 16 + lr) * T_SEQ + k0 + lc * 8;
            bf16x8 vfh = *(const bf16x8*)(vhb + voff);
            bf16x8 vfl = *(const bf16x8*)(vlb + voff);
            oacc[n] = __builtin_amdgcn_mfma_f32_16x16x32_bf16(pah, vfh, oacc[n], 0, 0, 0);
            oacc[n] = __builtin_amdgcn_mfma_f32_16x16x32_bf16(pal, vfh, oacc[n], 0, 0, 0);
            oacc[n] = __builtin_amdgcn_mfma_f32_16x16x32_bf16(pah, vfl, oacc[n], 0, 0, 0);
            oacc[n] = __builtin_amdgcn_mfma_f32_16x16x32_bf16(pal, vfl, oacc[n], 0, 0, 0);
        }
    }
#pragma unroll
    for (int n = 0; n < 8; ++n) {
        int col = h * HD + n * 16 + lr;
#pragma unroll
        for (int r = 0; r < 4; ++r)
            qf[(size_t)(q0 + lc * 4 + r) * HID + col] = oacc[n][r] / l[r];
    }
}

// ---------------- Hadamard head-mix + per-row int4 requant ------------------
__global__ __launch_bounds__(256) void k_hadq(const float* __restrict__ attn,
        u16* __restrict__ a2, float* __restrict__ sa) {
    int t = blockIdx.x, tid = threadIdx.x;
    __shared__ float rowb[HID];
    const float* ar = attn + (size_t)t * HID;
#pragma unroll
    for (int i = 0; i < 4; ++i)
        *(f32x4*)&rowb[i * 1024 + tid * 4] = *(const f32x4*)(ar + i * 1024 + tid * 4);
    __syncthreads();
    float out[16], amax = 0.f;
#pragma unroll
    for (int i = 0; i < 16; ++i) {
        int o = tid + i * 256;
        int g = o >> 7, d = o & 127;
        float acc = 0.f;
#pragma unroll
        for (int hh = 0; hh < 32; ++hh) {
            float v = rowb[hh * 128 + d];
            acc += (__popc(g & hh) & 1) ? -v : v;
        }
        out[i] = acc * 0.17677669529663687f;  // 1/sqrt(32)
        amax = fmaxf(amax, fabsf(out[i]));
    }
#pragma unroll
    for (int off = 32; off >= 1; off >>= 1)
        amax = fmaxf(amax, __shfl_xor(amax, off));
    __shared__ float red[4];
    if ((tid & 63) == 0) red[tid >> 6] = amax;
    __syncthreads();
    amax = fmaxf(fmaxf(red[0], red[1]), fmaxf(red[2], red[3]));
    float s = fmaxf(amax / 7.f, 1e-8f);
    if (tid == 0) sa[t] = s;
    u16* o2 = a2 + (size_t)t * HID;
#pragma unroll
    for (int i = 0; i < 16; ++i) {
        float q = rintf(out[i] / s);
        q = fminf(fmaxf(q, -8.f), 7.f);
        o2[tid + i * 256] = f2bf(q);
    }
}

extern "C" void kernel_launch(void* const* d_in, const int* in_sizes, int n_in,
                              void* d_out, int out_size, void* d_ws, size_t ws_size,
                              hipStream_t stream) {
    const int* positions = (const int*)d_in[0];
    const float* hidden = (const float*)d_in[1];
    const int* wq = (const int*)d_in[2];
    const float* wq_s = (const float*)d_in[3];
    const int* wk = (const int*)d_in[4];
    const float* wk_s = (const float*)d_in[5];
    const int* wv = (const int*)d_in[6];
    const float* wv_s = (const float*)d_in[7];
    const int* wo = (const int*)d_in[8];
    const float* wo_s = (const float*)d_in[9];

    char* ws = (char*)d_ws;
    size_t off = 0;
    float* s_x = (float*)(ws + off); off += 8192;
    float* s_a = (float*)(ws + off); off += 8192;
    u16* a_bf = (u16*)(ws + off); off += 16777216;            // 2048x4096 bf16
    float* q_f = (float*)(ws + off); off += 33554432;         // 2048x4096 f32
    float* k_f = (float*)(ws + off); off += 8388608;          // 2048x1024 f32
    u16* kh_bf = (u16*)(ws + off); off += 4194304;            // 2048x1024 bf16
    u16* kl_bf = (u16*)(ws + off); off += 4194304;
    u16* vh_t = (u16*)(ws + off); off += 4194304;             // 1024x2048 bf16 (V^T)
    u16* vl_t = (u16*)(ws + off); off += 4194304;
    float* attn = q_f;  // attention writes in-place over rotated Q
    u16* a2 = a_bf;     // a_bf dead after QKV GEMMs

    k_quant<<<T_SEQ, 256, 0, stream>>>(hidden, a_bf, s_x);
    k_gemm<0><<<dim3(16, 32), 256, 0, stream>>>(a_bf, wq, s_x, wq_s, q_f,
                                                nullptr, T_SEQ, HID, KDIM);
    k_gemm<0><<<dim3(16, 8), 256, 0, stream>>>(a_bf, wk, s_x, wk_s, k_f,
                                               nullptr, T_SEQ, NKV * HD, KDIM);
    k_gemm<1><<<dim3(16, 8), 256, 0, stream>>>(a_bf, wv, s_x, wv_s, vh_t,
                                               vl_t, T_SEQ, NKV * HD, KDIM);
    k_rope<<<T_SEQ, 256, 0, stream>>>(q_f, k_f, positions, kh_bf, kl_bf);
    k_attn<<<dim3(T_SEQ / 64, NH), 256, 0, stream>>>(q_f, kh_bf, kl_bf,
                                                     vh_t, vl_t);
    k_hadq<<<T_SEQ, 256, 0, stream>>>(attn, a2, s_a);
    k_gemm<0><<<dim3(16, 32), 256, 0, stream>>>(a2, wo, s_a, wo_s,
                                                (float*)d_out, nullptr,
                                                T_SEQ, HID, KDIM);
}

// Round 3
// 818.308 us; speedup vs baseline: 1.7850x; 1.7850x over previous
//
#include <hip/hip_runtime.h>

#define T_SEQ 2048
#define HID 4096
#define NH 32
#define NKV 8
#define HD 128
#define KDIM 4096

typedef unsigned short u16;
typedef __attribute__((ext_vector_type(4))) float f32x4;
typedef __attribute__((ext_vector_type(4))) int i32x4;
typedef __attribute__((ext_vector_type(8))) short s16x8;
typedef __attribute__((ext_vector_type(4))) short s16x4;
typedef __attribute__((ext_vector_type(8))) __bf16 bf16x8;

static __device__ __forceinline__ u16 f2bf(float f) {
    __bf16 b = (__bf16)f;
    return __builtin_bit_cast(unsigned short, b);
}
static __device__ __forceinline__ float bf2f(u16 b) {
    unsigned u = ((unsigned)b) << 16;
    return __builtin_bit_cast(float, u);
}
static __device__ __forceinline__ __bf16 bfbits(u16 b) {
    return __builtin_bit_cast(__bf16, b);
}

typedef __attribute__((address_space(1))) const void gas_t;
typedef __attribute__((address_space(3))) void las_t;
static __device__ __forceinline__ void gll16(const void* g, void* l) {
    __builtin_amdgcn_global_load_lds((gas_t*)g, (las_t*)l, 16, 0, 0);
}

// ---------------- per-row int4 quant of hidden_states -> bf16 ints + scale ----
__global__ __launch_bounds__(256) void k_quant(const float* __restrict__ x,
                                               u16* __restrict__ qb,
                                               float* __restrict__ srow) {
    int row = blockIdx.x, tid = threadIdx.x;
    const float* xr = x + (size_t)row * HID;
    f32x4 v[4];
    float amax = 0.f;
#pragma unroll
    for (int i = 0; i < 4; ++i) {
        v[i] = *(const f32x4*)(xr + i * 1024 + tid * 4);
#pragma unroll
        for (int j = 0; j < 4; ++j) amax = fmaxf(amax, fabsf(v[i][j]));
    }
#pragma unroll
    for (int off = 32; off >= 1; off >>= 1)
        amax = fmaxf(amax, __shfl_xor(amax, off));
    __shared__ float red[4];
    if ((tid & 63) == 0) red[tid >> 6] = amax;
    __syncthreads();
    amax = fmaxf(fmaxf(red[0], red[1]), fmaxf(red[2], red[3]));
    float s = fmaxf(amax / 7.f, 1e-8f);
    if (tid == 0) srow[row] = s;
    u16* qr = qb + (size_t)row * HID;
#pragma unroll
    for (int i = 0; i < 4; ++i) {
        s16x4 o;
#pragma unroll
        for (int j = 0; j < 4; ++j) {
            float q = rintf(v[i][j] / s);
            q = fminf(fmaxf(q, -8.f), 7.f);
            o[j] = (short)f2bf(q);
        }
        *(s16x4*)(qr + i * 1024 + tid * 4) = o;
    }
}

// ---------------- bf16 MFMA GEMM (integer-valued inputs -> exact) ------------
// MODE 0: f32 row-major out.  MODE 1: fragment-ordered V^T hi/lo bf16 out.
template <int MODE>
__global__ __launch_bounds__(256) void k_gemm(const u16* __restrict__ A,
        const int* __restrict__ W, const float* __restrict__ sRow,
        const float* __restrict__ sCol, void* __restrict__ outp,
        void* __restrict__ outp2, int M, int N, int K) {
    __shared__ u16 sA[128][72];
    __shared__ u16 sB[128][72];
    int tid = threadIdx.x;
    int brow = blockIdx.x * 128, bcol = blockIdx.y * 128;
    int wid = tid >> 6, lane = tid & 63;
    int wr = (wid >> 1) * 64, wc = (wid & 1) * 64;
    int lr = lane & 15, lc = lane >> 4;
    f32x4 acc[4][4] = {};
    int arow = tid >> 3, acol = (tid & 7) * 8;
    int brr = tid >> 4, bcc = (tid & 15) * 4;
    for (int k0 = 0; k0 < K; k0 += 64) {
#pragma unroll
        for (int t = 0; t < 4; ++t) {
            int r = t * 32 + arow;
            *(s16x8*)&sA[r][acol] =
                *(const s16x8*)(A + (size_t)(brow + r) * K + k0 + acol);
        }
#pragma unroll
        for (int t = 0; t < 8; ++t) {
            int r = t * 16 + brr;
            i32x4 w = *(const i32x4*)(W + (size_t)(bcol + r) * K + k0 + bcc);
            s16x4 hh;
#pragma unroll
            for (int j = 0; j < 4; ++j) hh[j] = (short)f2bf((float)w[j]);
            *(s16x4*)&sB[r][bcc] = hh;
        }
        __syncthreads();
#pragma unroll
        for (int kk = 0; kk < 64; kk += 32) {
            bf16x8 af[4], bf[4];
#pragma unroll
            for (int m = 0; m < 4; ++m)
                af[m] = *(const bf16x8*)&sA[wr + m * 16 + lr][kk + lc * 8];
#pragma unroll
            for (int n = 0; n < 4; ++n)
                bf[n] = *(const bf16x8*)&sB[wc + n * 16 + lr][kk + lc * 8];
#pragma unroll
            for (int m = 0; m < 4; ++m)
#pragma unroll
                for (int n = 0; n < 4; ++n)
                    acc[m][n] = __builtin_amdgcn_mfma_f32_16x16x32_bf16(
                        af[m], bf[n], acc[m][n], 0, 0, 0);
        }
        __syncthreads();
    }
#pragma unroll
    for (int m = 0; m < 4; ++m) {
        int row0 = brow + wr + m * 16 + lc * 4;
#pragma unroll
        for (int n = 0; n < 4; ++n) {
            int col = bcol + wc + n * 16 + lr;
            float scl = sCol[col];
            if (MODE == 0) {
                float* o = (float*)outp;
#pragma unroll
                for (int r = 0; r < 4; ++r)
                    o[(size_t)(row0 + r) * N + col] =
                        acc[m][n][r] * sRow[row0 + r] * scl;
            } else {
                // fragment-ordered V^T: col = kvh*128 + d; rows = keys
                u16* oh = (u16*)outp;
                u16* ol = (u16*)outp2;
                int kvh = col >> 7, d = col & 127;
                int nn = d >> 4, lrv = d & 15;
                int kt = row0 >> 6, rem = row0 & 63;
                int kc = rem >> 5, lcv = (rem & 31) >> 3, j0 = rem & 7;
                size_t base =
                    ((((size_t)(kvh * 32 + kt) * 2 + kc) * 8 + nn) * 64 +
                     lcv * 16 + lrv) * 8 + j0;
                s16x4 hh, ll;
#pragma unroll
                for (int r = 0; r < 4; ++r) {
                    float val = acc[m][n][r] * sRow[row0 + r] * scl;
                    u16 hb = f2bf(val);
                    hh[r] = (short)hb;
                    ll[r] = (short)f2bf(val - bf2f(hb));
                }
                *(s16x4*)(oh + base) = hh;
                *(s16x4*)(ol + base) = ll;
            }
        }
    }
}

// ---------------- RoPE: q in-place fp32; k -> fragment-ordered hi/lo bf16 ---
__global__ __launch_bounds__(256) void k_rope(float* __restrict__ qf,
        const float* __restrict__ kf, const int* __restrict__ pos,
        u16* __restrict__ khf, u16* __restrict__ klf) {
    int t = blockIdx.x, tid = threadIdx.x;
    __shared__ float scs[64], ssn[64];
    if (tid < 64) {
        float p = (float)pos[t];
        float inv = (float)pow(10000.0, -(double)tid / 64.0);
        float ang = p * inv;
        double dsn, dcs;
        sincos((double)ang, &dsn, &dcs);
        scs[tid] = (float)dcs;
        ssn[tid] = (float)dsn;
    }
    __syncthreads();
    int kt = t >> 6, rem = t & 63, cblk = rem >> 4, lrk = rem & 15;
    for (int idx = tid; idx < (NH + NKV) * 64; idx += 256) {
        int hd6 = idx >> 6, d = idx & 63;
        float cs = scs[d], sn = ssn[d];
        if (hd6 < NH) {
            size_t base = (size_t)t * HID + hd6 * HD;
            float x1 = qf[base + d], x2 = qf[base + d + 64];
            qf[base + d] = x1 * cs - x2 * sn;
            qf[base + d + 64] = x2 * cs + x1 * sn;
        } else {
            int kh = hd6 - NH;
            size_t base = (size_t)t * (NKV * HD) + kh * HD;
            float x1 = kf[base + d], x2 = kf[base + d + 64];
            float r1 = x1 * cs - x2 * sn;
            float r2 = x2 * cs + x1 * sn;
            size_t tb = (((size_t)(kh * 32 + kt) * 4 + cblk) * 4) * 512;
#pragma unroll
            for (int half = 0; half < 2; ++half) {
                int x = d + half * 64;
                float rv = half ? r2 : r1;
                int dcx = x >> 5, lcx = (x & 31) >> 3, jx = x & 7;
                size_t ii = tb + (size_t)dcx * 512 + (lcx * 16 + lrk) * 8 + jx;
                u16 hb = f2bf(rv);
                khf[ii] = hb;
                klf[ii] = f2bf(rv - bf2f(hb));
            }
        }
    }
}

// ---------------- GQA causal flash attention, LDS-staged KV tiles -----------
// grid = (T/64, NH); 4 waves/block; KVBLK=64; fragment-ordered K/V tiles.
__global__ __launch_bounds__(256) void k_attn(float* __restrict__ qf,
        const u16* __restrict__ khf, const u16* __restrict__ klf,
        const u16* __restrict__ vhf, const u16* __restrict__ vlf) {
    int h = blockIdx.y, kvh = h >> 2;
    int tid = threadIdx.x, wid = tid >> 6, lane = tid & 63;
    int lr = lane & 15, lc = lane >> 4;
    int q0 = blockIdx.x * 64 + wid * 16;
    int q_hi = q0 + 15;
    __shared__ __align__(16) u16 sKh[8192], sKl[8192], sVh[8192], sVl[8192];
    __shared__ __align__(16) u16 pbuf[4][16][72];
    // Q fragments (fp32 -> hi/lo bf16)
    bf16x8 aqh[4], aql[4];
    {
        const float* qrow = qf + (size_t)(q0 + lr) * HID + h * HD;
#pragma unroll
        for (int dc = 0; dc < 4; ++dc)
#pragma unroll
            for (int j = 0; j < 8; ++j) {
                float v = qrow[dc * 32 + lc * 8 + j];
                u16 hb = f2bf(v);
                aqh[dc][j] = bfbits(hb);
                aql[dc][j] = bfbits(f2bf(v - bf2f(hb)));
            }
    }
    f32x4 oacc[8] = {};
    float m[4], l[4];
#pragma unroll
    for (int r = 0; r < 4; ++r) { m[r] = -1e30f; l[r] = 0.f; }
    int NT = blockIdx.x + 1;
    const u16* khg = khf + (size_t)kvh * 32 * 8192;
    const u16* klg = klf + (size_t)kvh * 32 * 8192;
    const u16* vhg = vhf + (size_t)kvh * 32 * 8192;
    const u16* vlg = vlf + (size_t)kvh * 32 * 8192;
    for (int kt = 0; kt < NT; ++kt) {
        int k0 = kt * 64;
        __syncthreads();  // previous tile's compute done
        {
            const char* gk = (const char*)(khg + (size_t)kt * 8192);
            const char* gl = (const char*)(klg + (size_t)kt * 8192);
            const char* gv = (const char*)(vhg + (size_t)kt * 8192);
            const char* gw = (const char*)(vlg + (size_t)kt * 8192);
            int lo16 = lane * 16;
#pragma unroll
            for (int j = 0; j < 4; ++j) {
                int off = wid * 4096 + j * 1024;
                gll16(gk + off + lo16, (char*)sKh + off);
                gll16(gl + off + lo16, (char*)sKl + off);
                gll16(gv + off + lo16, (char*)sVh + off);
                gll16(gw + off + lo16, (char*)sVl + off);
            }
        }
        asm volatile("s_waitcnt vmcnt(0)" ::: "memory");
        __syncthreads();  // tile staged
        // ---- QK^T (4-term hi/lo split: exact to ~2^-24) ----
        f32x4 s[4];
#pragma unroll
        for (int c = 0; c < 4; ++c) {
            if (k0 + c * 16 <= q_hi) {
                f32x4 a = {};
#pragma unroll
                for (int dc = 0; dc < 4; ++dc) {
                    bf16x8 kh8 = *(const bf16x8*)&sKh[((c * 4 + dc) * 64 + lane) * 8];
                    bf16x8 kl8 = *(const bf16x8*)&sKl[((c * 4 + dc) * 64 + lane) * 8];
                    a = __builtin_amdgcn_mfma_f32_16x16x32_bf16(aqh[dc], kh8, a, 0, 0, 0);
                    a = __builtin_amdgcn_mfma_f32_16x16x32_bf16(aql[dc], kh8, a, 0, 0, 0);
                    a = __builtin_amdgcn_mfma_f32_16x16x32_bf16(aqh[dc], kl8, a, 0, 0, 0);
                    a = __builtin_amdgcn_mfma_f32_16x16x32_bf16(aql[dc], kl8, a, 0, 0, 0);
                }
                s[c] = a;
            }
        }
        // ---- scale + causal mask + running max ----
        float tmax[4] = {-1e30f, -1e30f, -1e30f, -1e30f};
#pragma unroll
        for (int c = 0; c < 4; ++c) {
            bool active = (k0 + c * 16 <= q_hi);
            bool edge = (k0 + c * 16 + 15 > q_hi) || (k0 + c * 16 + 15 >= q0);
#pragma unroll
            for (int r = 0; r < 4; ++r) {
                float sv;
                if (active) {
                    sv = s[c][r] * 0.08838834764831845f;
                    if (edge) {
                        int key = k0 + c * 16 + lr, qr = q0 + lc * 4 + r;
                        if (key > qr) sv = -1e30f;
                    }
                } else {
                    sv = -1e30f;
                }
                s[c][r] = sv;
                tmax[r] = fmaxf(tmax[r], sv);
            }
        }
#pragma unroll
        for (int off = 1; off < 16; off <<= 1)
#pragma unroll
            for (int r = 0; r < 4; ++r)
                tmax[r] = fmaxf(tmax[r], __shfl_xor(tmax[r], off));
        float alpha[4], psum[4] = {0.f, 0.f, 0.f, 0.f};
#pragma unroll
        for (int r = 0; r < 4; ++r) {
            float mn = fmaxf(m[r], tmax[r]);
            alpha[r] = expf(m[r] - mn);
            m[r] = mn;
        }
#pragma unroll
        for (int c = 0; c < 4; ++c)
#pragma unroll
            for (int r = 0; r < 4; ++r) {
                float pv = expf(s[c][r] - m[r]);
                s[c][r] = pv;
                psum[r] += pv;
            }
#pragma unroll
        for (int off = 1; off < 16; off <<= 1)
#pragma unroll
            for (int r = 0; r < 4; ++r) psum[r] += __shfl_xor(psum[r], off);
#pragma unroll
        for (int r = 0; r < 4; ++r) l[r] = l[r] * alpha[r] + psum[r];
#pragma unroll
        for (int n = 0; n < 8; ++n)
#pragma unroll
            for (int r = 0; r < 4; ++r) oacc[n][r] *= alpha[r];
        // ---- P -> LDS (hi), read A-frags, then (lo) ----
#pragma unroll
        for (int c = 0; c < 4; ++c)
#pragma unroll
            for (int r = 0; r < 4; ++r)
                pbuf[wid][lc * 4 + r][c * 16 + lr] = f2bf(s[c][r]);
        asm volatile("s_waitcnt lgkmcnt(0)" ::: "memory");
        bf16x8 pah[2], pal[2];
#pragma unroll
        for (int kc = 0; kc < 2; ++kc)
            pah[kc] = *(const bf16x8*)&pbuf[wid][lr][kc * 32 + lc * 8];
        asm volatile("s_waitcnt lgkmcnt(0)" ::: "memory");
#pragma unroll
        for (int c = 0; c < 4; ++c)
#pragma unroll
            for (int r = 0; r < 4; ++r) {
                float pv = s[c][r];
                pbuf[wid][lc * 4 + r][c * 16 + lr] = f2bf(pv - bf2f(f2bf(pv)));
            }
        asm volatile("s_waitcnt lgkmcnt(0)" ::: "memory");
#pragma unroll
        for (int kc = 0; kc < 2; ++kc)
            pal[kc] = *(const bf16x8*)&pbuf[wid][lr][kc * 32 + lc * 8];
        // ---- PV (3-term: ph*vh + pl*vh + ph*vl) ----
#pragma unroll
        for (int kc = 0; kc < 2; ++kc) {
            if (k0 + kc * 32 <= q_hi) {
#pragma unroll
                for (int n = 0; n < 8; ++n) {
                    bf16x8 vh8 = *(const bf16x8*)&sVh[((kc * 8 + n) * 64 + lane) * 8];
                    bf16x8 vl8 = *(const bf16x8*)&sVl[((kc * 8 + n) * 64 + lane) * 8];
                    oacc[n] = __builtin_amdgcn_mfma_f32_16x16x32_bf16(pah[kc], vh8, oacc[n], 0, 0, 0);
                    oacc[n] = __builtin_amdgcn_mfma_f32_16x16x32_bf16(pal[kc], vh8, oacc[n], 0, 0, 0);
                    oacc[n] = __builtin_amdgcn_mfma_f32_16x16x32_bf16(pah[kc], vl8, oacc[n], 0, 0, 0);
                }
            }
        }
    }
#pragma unroll
    for (int n = 0; n < 8; ++n) {
        int col = h * HD + n * 16 + lr;
#pragma unroll
        for (int r = 0; r < 4; ++r)
            qf[(size_t)(q0 + lc * 4 + r) * HID + col] = oacc[n][r] / l[r];
    }
}

// ---------------- Hadamard head-mix + per-row int4 requant ------------------
__global__ __launch_bounds__(256) void k_hadq(const float* __restrict__ attn,
        u16* __restrict__ a2, float* __restrict__ sa) {
    int t = blockIdx.x, tid = threadIdx.x;
    __shared__ float rowb[HID];
    const float* ar = attn + (size_t)t * HID;
#pragma unroll
    for (int i = 0; i < 4; ++i)
        *(f32x4*)&rowb[i * 1024 + tid * 4] = *(const f32x4*)(ar + i * 1024 + tid * 4);
    __syncthreads();
    float out[16], amax = 0.f;
#pragma unroll
    for (int i = 0; i < 16; ++i) {
        int o = tid + i * 256;
        int g = o >> 7, d = o & 127;
        float acc = 0.f;
#pragma unroll
        for (int hh = 0; hh < 32; ++hh) {
            float v = rowb[hh * 128 + d];
            acc += (__popc(g & hh) & 1) ? -v : v;
        }
        out[i] = acc * 0.17677669529663687f;
        amax = fmaxf(amax, fabsf(out[i]));
    }
#pragma unroll
    for (int off = 32; off >= 1; off >>= 1)
        amax = fmaxf(amax, __shfl_xor(amax, off));
    __shared__ float red[4];
    if ((tid & 63) == 0) red[tid >> 6] = amax;
    __syncthreads();
    amax = fmaxf(fmaxf(red[0], red[1]), fmaxf(red[2], red[3]));
    float s = fmaxf(amax / 7.f, 1e-8f);
    if (tid == 0) sa[t] = s;
    u16* o2 = a2 + (size_t)t * HID;
#pragma unroll
    for (int i = 0; i < 16; ++i) {
        float q = rintf(out[i] / s);
        q = fminf(fmaxf(q, -8.f), 7.f);
        o2[tid + i * 256] = f2bf(q);
    }
}

extern "C" void kernel_launch(void* const* d_in, const int* in_sizes, int n_in,
                              void* d_out, int out_size, void* d_ws, size_t ws_size,
                              hipStream_t stream) {
    const int* positions = (const int*)d_in[0];
    const float* hidden = (const float*)d_in[1];
    const int* wq = (const int*)d_in[2];
    const float* wq_s = (const float*)d_in[3];
    const int* wk = (const int*)d_in[4];
    const float* wk_s = (const float*)d_in[5];
    const int* wv = (const int*)d_in[6];
    const float* wv_s = (const float*)d_in[7];
    const int* wo = (const int*)d_in[8];
    const float* wo_s = (const float*)d_in[9];

    char* ws = (char*)d_ws;
    size_t off = 0;
    float* s_x = (float*)(ws + off); off += 8192;
    float* s_a = (float*)(ws + off); off += 8192;
    u16* a_bf = (u16*)(ws + off); off += 16777216;   // 2048x4096 bf16
    float* q_f = (float*)(ws + off); off += 33554432; // 2048x4096 f32
    float* k_f = (float*)(ws + off); off += 8388608;  // 2048x1024 f32
    u16* khf = (u16*)(ws + off); off += 4194304;      // frag-ordered K hi
    u16* klf = (u16*)(ws + off); off += 4194304;      // frag-ordered K lo
    u16* vhf = (u16*)(ws + off); off += 4194304;      // frag-ordered V^T hi
    u16* vlf = (u16*)(ws + off); off += 4194304;      // frag-ordered V^T lo
    float* attn = q_f;  // attention writes in-place over rotated Q
    u16* a2 = a_bf;     // a_bf dead after QKV GEMMs

    k_quant<<<T_SEQ, 256, 0, stream>>>(hidden, a_bf, s_x);
    k_gemm<0><<<dim3(16, 32), 256, 0, stream>>>(a_bf, wq, s_x, wq_s, q_f,
                                                nullptr, T_SEQ, HID, KDIM);
    k_gemm<0><<<dim3(16, 8), 256, 0, stream>>>(a_bf, wk, s_x, wk_s, k_f,
                                               nullptr, T_SEQ, NKV * HD, KDIM);
    k_gemm<1><<<dim3(16, 8), 256, 0, stream>>>(a_bf, wv, s_x, wv_s, vhf,
                                               vlf, T_SEQ, NKV * HD, KDIM);
    k_rope<<<T_SEQ, 256, 0, stream>>>(q_f, k_f, positions, khf, klf);
    k_attn<<<dim3(T_SEQ / 64, NH), 256, 0, stream>>>(q_f, khf, klf, vhf, vlf);
    k_hadq<<<T_SEQ, 256, 0, stream>>>(attn, a2, s_a);
    k_gemm<0><<<dim3(16, 32), 256, 0, stream>>>(a2, wo, s_a, wo_s,
                                                (float*)d_out, nullptr,
                                                T_SEQ, HID, KDIM);
}

// Round 4
// 523.682 us; speedup vs baseline: 2.7893x; 1.5626x over previous
//
#include <hip/hip_runtime.h>

#define T_SEQ 2048
#define HID 4096
#define NH 32
#define NKV 8
#define HD 128
#define KDIM 4096

typedef unsigned short u16;
typedef signed char s8;
typedef __attribute__((ext_vector_type(4))) float f32x4;
typedef __attribute__((ext_vector_type(4))) int i32x4;
typedef __attribute__((ext_vector_type(8))) short s16x8;
typedef __attribute__((ext_vector_type(4))) short s16x4;
typedef __attribute__((ext_vector_type(8))) __bf16 bf16x8;

static __device__ __forceinline__ u16 f2bf(float f) {
    __bf16 b = (__bf16)f;
    return __builtin_bit_cast(unsigned short, b);
}
static __device__ __forceinline__ float bf2f(u16 b) {
    unsigned u = ((unsigned)b) << 16;
    return __builtin_bit_cast(float, u);
}
static __device__ __forceinline__ __bf16 bfbits(u16 b) {
    return __builtin_bit_cast(__bf16, b);
}

typedef __attribute__((address_space(1))) const void gas_t;
typedef __attribute__((address_space(3))) void las_t;
static __device__ __forceinline__ void gll16(const void* g, void* l) {
    __builtin_amdgcn_global_load_lds((gas_t*)g, (las_t*)l, 16, 0, 0);
}

// ---------------- per-row int4 quant of hidden_states -> int8 + scale -------
__global__ __launch_bounds__(256) void k_quant(const float* __restrict__ x,
                                               s8* __restrict__ qb,
                                               float* __restrict__ srow) {
    int row = blockIdx.x, tid = threadIdx.x;
    const float* xr = x + (size_t)row * HID;
    f32x4 v[4];
    float amax = 0.f;
#pragma unroll
    for (int i = 0; i < 4; ++i) {
        v[i] = *(const f32x4*)(xr + i * 1024 + tid * 4);
#pragma unroll
        for (int j = 0; j < 4; ++j) amax = fmaxf(amax, fabsf(v[i][j]));
    }
#pragma unroll
    for (int off = 32; off >= 1; off >>= 1)
        amax = fmaxf(amax, __shfl_xor(amax, off));
    __shared__ float red[4];
    if ((tid & 63) == 0) red[tid >> 6] = amax;
    __syncthreads();
    amax = fmaxf(fmaxf(red[0], red[1]), fmaxf(red[2], red[3]));
    float s = fmaxf(amax / 7.f, 1e-8f);
    if (tid == 0) srow[row] = s;
    int* qr = (int*)(qb + (size_t)row * HID);
#pragma unroll
    for (int i = 0; i < 4; ++i) {
        int p = 0;
#pragma unroll
        for (int j = 0; j < 4; ++j) {
            float q = rintf(v[i][j] / s);
            q = fminf(fmaxf(q, -8.f), 7.f);
            p |= ((int)q & 0xff) << (8 * j);
        }
        qr[i * 256 + tid] = p;
    }
}

// ---------------- weight pack int32 -> int8 ---------------------------------
__global__ __launch_bounds__(256) void k_w8(const int* __restrict__ w,
                                            s8* __restrict__ w8, int n4) {
    int i = blockIdx.x * 256 + threadIdx.x;
    if (i < n4) {
        i32x4 v = *(const i32x4*)(w + i * 4);
        int p = (v[0] & 0xff) | ((v[1] & 0xff) << 8) | ((v[2] & 0xff) << 16) |
                (v[3] << 24);
        ((int*)w8)[i] = p;
    }
}

// ---------------- int8 MFMA GEMM (exact): out = (A.W^T) * sRow * sCol -------
// MODE 0: f32 row-major out.  MODE 1: fragment-ordered V^T hi/lo bf16 out.
template <int MODE>
__global__ __launch_bounds__(256) void k_gemm8(const s8* __restrict__ A,
        const s8* __restrict__ W, const float* __restrict__ sRow,
        const float* __restrict__ sCol, void* __restrict__ outp,
        void* __restrict__ outp2, int M, int N, int K) {
    __shared__ __align__(16) s8 sA[16384], sB[16384];  // [128][128], XOR-swizzled
    int tid = threadIdx.x;
    int brow = blockIdx.x * 128, bcol = blockIdx.y * 128;
    int wid = tid >> 6, lane = tid & 63;
    int wr = (wid >> 1) * 64, wc = (wid & 1) * 64;
    int lr = lane & 15, lc = lane >> 4;
    i32x4 acc[4][4] = {};
    for (int k0 = 0; k0 < K; k0 += 128) {
        __syncthreads();
#pragma unroll
        for (int j = 0; j < 4; ++j) {
            int base = wid * 1024 + j * 4096;
            int o = base + lane * 16;
            int r = o >> 7;
            int c = (o & 127) ^ ((r & 7) << 4);  // inverse-swizzled source
            gll16(A + (size_t)(brow + r) * K + (k0 + c), (char*)sA + base);
            gll16(W + (size_t)(bcol + r) * K + (k0 + c), (char*)sB + base);
        }
        asm volatile("s_waitcnt vmcnt(0)" ::: "memory");
        __syncthreads();
#pragma unroll
        for (int kk = 0; kk < 2; ++kk) {
            i32x4 af[4], bf[4];
#pragma unroll
            for (int m = 0; m < 4; ++m) {
                int r = wr + m * 16 + lr;
                int sl = ((kk * 4 + lc) ^ (r & 7)) * 16;  // swizzled read
                af[m] = *(const i32x4*)&sA[r * 128 + sl];
            }
#pragma unroll
            for (int n = 0; n < 4; ++n) {
                int r = wc + n * 16 + lr;
                int sl = ((kk * 4 + lc) ^ (r & 7)) * 16;
                bf[n] = *(const i32x4*)&sB[r * 128 + sl];
            }
#pragma unroll
            for (int m = 0; m < 4; ++m)
#pragma unroll
                for (int n = 0; n < 4; ++n)
                    acc[m][n] = __builtin_amdgcn_mfma_i32_16x16x64_i8(
                        af[m], bf[n], acc[m][n], 0, 0, 0);
        }
    }
#pragma unroll
    for (int m = 0; m < 4; ++m) {
        int row0 = brow + wr + m * 16 + lc * 4;
#pragma unroll
        for (int n = 0; n < 4; ++n) {
            int col = bcol + wc + n * 16 + lr;
            float scl = sCol[col];
            if (MODE == 0) {
                float* o = (float*)outp;
#pragma unroll
                for (int r = 0; r < 4; ++r)
                    o[(size_t)(row0 + r) * N + col] =
                        (float)acc[m][n][r] * sRow[row0 + r] * scl;
            } else {
                u16* oh = (u16*)outp;
                u16* ol = (u16*)outp2;
                int kvh = col >> 7, d = col & 127;
                int nn = d >> 4, lrv = d & 15;
                int kt = row0 >> 6, rem = row0 & 63;
                int kc = rem >> 5, lcv = (rem & 31) >> 3, j0 = rem & 7;
                size_t base =
                    ((((size_t)(kvh * 32 + kt) * 2 + kc) * 8 + nn) * 64 +
                     lcv * 16 + lrv) * 8 + j0;
                s16x4 hh, ll;
#pragma unroll
                for (int r = 0; r < 4; ++r) {
                    float val = (float)acc[m][n][r] * sRow[row0 + r] * scl;
                    u16 hb = f2bf(val);
                    hh[r] = (short)hb;
                    ll[r] = (short)f2bf(val - bf2f(hb));
                }
                *(s16x4*)(oh + base) = hh;
                *(s16x4*)(ol + base) = ll;
            }
        }
    }
}

// ---------------- RoPE: q in-place fp32; k -> fragment-ordered hi/lo bf16 ---
__global__ __launch_bounds__(256) void k_rope(float* __restrict__ qf,
        const float* __restrict__ kf, const int* __restrict__ pos,
        u16* __restrict__ khf, u16* __restrict__ klf) {
    int t = blockIdx.x, tid = threadIdx.x;
    __shared__ float scs[64], ssn[64];
    if (tid < 64) {
        float p = (float)pos[t];
        float inv = (float)pow(10000.0, -(double)tid / 64.0);
        float ang = p * inv;
        double dsn, dcs;
        sincos((double)ang, &dsn, &dcs);
        scs[tid] = (float)dcs;
        ssn[tid] = (float)dsn;
    }
    __syncthreads();
    int kt = t >> 6, rem = t & 63, cblk = rem >> 4, lrk = rem & 15;
    for (int idx = tid; idx < (NH + NKV) * 64; idx += 256) {
        int hd6 = idx >> 6, d = idx & 63;
        float cs = scs[d], sn = ssn[d];
        if (hd6 < NH) {
            size_t base = (size_t)t * HID + hd6 * HD;
            float x1 = qf[base + d], x2 = qf[base + d + 64];
            qf[base + d] = x1 * cs - x2 * sn;
            qf[base + d + 64] = x2 * cs + x1 * sn;
        } else {
            int kh = hd6 - NH;
            size_t base = (size_t)t * (NKV * HD) + kh * HD;
            float x1 = kf[base + d], x2 = kf[base + d + 64];
            float r1 = x1 * cs - x2 * sn;
            float r2 = x2 * cs + x1 * sn;
            size_t tb = (((size_t)(kh * 32 + kt) * 4 + cblk) * 4) * 512;
#pragma unroll
            for (int half = 0; half < 2; ++half) {
                int x = d + half * 64;
                float rv = half ? r2 : r1;
                int dcx = x >> 5, lcx = (x & 31) >> 3, jx = x & 7;
                size_t ii = tb + (size_t)dcx * 512 + (lcx * 16 + lrk) * 8 + jx;
                u16 hb = f2bf(rv);
                khf[ii] = hb;
                klf[ii] = f2bf(rv - bf2f(hb));
            }
        }
    }
}

// ---------------- GQA causal flash attention: 8 waves, dbuf prefetch --------
// grid = (T/128, NH); 512 threads; KVBLK=64; softmax in exp2 domain.
__global__ __launch_bounds__(512, 2) void k_attn(float* __restrict__ qf,
        const u16* __restrict__ khf, const u16* __restrict__ klf,
        const u16* __restrict__ vhf, const u16* __restrict__ vlf) {
    int h = blockIdx.y, kvh = h >> 2;
    int tid = threadIdx.x, wid = tid >> 6, lane = tid & 63;
    int lr = lane & 15, lc = lane >> 4;
    int bx = gridDim.x - 1 - blockIdx.x;  // LPT: heavy tiles dispatch first
    int q0 = bx * 128 + wid * 16;
    int q_hi = q0 + 15;
    __shared__ __align__(16) u16 sKh[2][8192], sKl[2][8192];
    __shared__ __align__(16) u16 sVh[2][8192], sVl[2][8192];
    __shared__ __align__(16) u16 pbuf[8][16][72];
    const float SCL = 0.12751744f;  // 1/sqrt(128) * log2(e)
    bf16x8 aqh[4], aql[4];
    {
        const float* qrow = qf + (size_t)(q0 + lr) * HID + h * HD;
#pragma unroll
        for (int dc = 0; dc < 4; ++dc) {
            f32x4 p0 = *(const f32x4*)(qrow + dc * 32 + lc * 8);
            f32x4 p1 = *(const f32x4*)(qrow + dc * 32 + lc * 8 + 4);
#pragma unroll
            for (int j = 0; j < 8; ++j) {
                float v = (j < 4 ? p0[j] : p1[j - 4]) * SCL;
                u16 hb = f2bf(v);
                aqh[dc][j] = bfbits(hb);
                aql[dc][j] = bfbits(f2bf(v - bf2f(hb)));
            }
        }
    }
    f32x4 oacc[8] = {};
    float m[4], l[4];
#pragma unroll
    for (int r = 0; r < 4; ++r) { m[r] = -1e30f; l[r] = 0.f; }
    int NT = 2 * bx + 2;
    size_t kvbase = (size_t)kvh * 32 * 8192;
    // wave -> (buffer, half) staging assignment
    const u16* gsel;
    int sel = wid >> 1;
    u16* lsel0;
    u16* lsel1;
    if (sel == 0)      { gsel = khf; lsel0 = sKh[0]; lsel1 = sKh[1]; }
    else if (sel == 1) { gsel = klf; lsel0 = sKl[0]; lsel1 = sKl[1]; }
    else if (sel == 2) { gsel = vhf; lsel0 = sVh[0]; lsel1 = sVh[1]; }
    else               { gsel = vlf; lsel0 = sVl[0]; lsel1 = sVl[1]; }
    int halfoff = (wid & 1) * 8192;  // bytes
    auto stage = [&](int buf, int kt) {
        const char* g = (const char*)(gsel + kvbase + (size_t)kt * 8192);
        char* dst = (char*)(buf ? lsel1 : lsel0);
#pragma unroll
        for (int j = 0; j < 8; ++j) {
            int off = halfoff + j * 1024;
            gll16(g + off + lane * 16, dst + off);
        }
    };
    stage(0, 0);
    asm volatile("s_waitcnt vmcnt(0)" ::: "memory");
    __syncthreads();
    int cur = 0;
    for (int kt = 0; kt < NT; ++kt) {
        if (kt + 1 < NT) stage(cur ^ 1, kt + 1);
        int k0 = kt * 64;
        if (k0 <= q_hi) {
            // ---- QK^T: 3-term hi/lo (lo*lo dropped, <=4e-6 rel) ----
            f32x4 s[4];
#pragma unroll
            for (int c = 0; c < 4; ++c) {
                if (k0 + c * 16 <= q_hi) {
                    f32x4 a = {};
#pragma unroll
                    for (int dc = 0; dc < 4; ++dc) {
                        bf16x8 kh8 = *(const bf16x8*)&sKh[cur][((c * 4 + dc) * 64 + lane) * 8];
                        bf16x8 kl8 = *(const bf16x8*)&sKl[cur][((c * 4 + dc) * 64 + lane) * 8];
                        a = __builtin_amdgcn_mfma_f32_16x16x32_bf16(aqh[dc], kh8, a, 0, 0, 0);
                        a = __builtin_amdgcn_mfma_f32_16x16x32_bf16(aql[dc], kh8, a, 0, 0, 0);
                        a = __builtin_amdgcn_mfma_f32_16x16x32_bf16(aqh[dc], kl8, a, 0, 0, 0);
                    }
                    s[c] = a;
                }
            }
            // ---- mask + running max (scores already in log2 units) ----
            float tmax[4] = {-1e30f, -1e30f, -1e30f, -1e30f};
#pragma unroll
            for (int c = 0; c < 4; ++c) {
                bool active = (k0 + c * 16 <= q_hi);
                bool edge = (k0 + c * 16 + 15 >= q0);
#pragma unroll
                for (int r = 0; r < 4; ++r) {
                    float sv = active ? s[c][r] : -1e30f;
                    if (active && edge) {
                        int key = k0 + c * 16 + lr, qr = q0 + lc * 4 + r;
                        if (key > qr) sv = -1e30f;
                    }
                    s[c][r] = sv;
                    tmax[r] = fmaxf(tmax[r], sv);
                }
            }
#pragma unroll
            for (int off = 1; off < 16; off <<= 1)
#pragma unroll
                for (int r = 0; r < 4; ++r)
                    tmax[r] = fmaxf(tmax[r], __shfl_xor(tmax[r], off));
            float alpha[4], psum[4] = {0.f, 0.f, 0.f, 0.f};
            bool anyup = false;
#pragma unroll
            for (int r = 0; r < 4; ++r) {
                float mn = fmaxf(m[r], tmax[r]);
                alpha[r] = exp2f(m[r] - mn);
                anyup |= (mn > m[r]);
                m[r] = mn;
            }
#pragma unroll
            for (int c = 0; c < 4; ++c)
#pragma unroll
                for (int r = 0; r < 4; ++r) {
                    float pv = exp2f(s[c][r] - m[r]);
                    s[c][r] = pv;
                    psum[r] += pv;
                }
#pragma unroll
            for (int off = 1; off < 16; off <<= 1)
#pragma unroll
                for (int r = 0; r < 4; ++r) psum[r] += __shfl_xor(psum[r], off);
#pragma unroll
            for (int r = 0; r < 4; ++r) l[r] = l[r] * alpha[r] + psum[r];
            if (__any(anyup)) {
#pragma unroll
                for (int n = 0; n < 8; ++n)
#pragma unroll
                    for (int r = 0; r < 4; ++r) oacc[n][r] *= alpha[r];
            }
            // ---- P -> pbuf (hi pass, then lo pass) ----
#pragma unroll
            for (int c = 0; c < 4; ++c)
#pragma unroll
                for (int r = 0; r < 4; ++r)
                    pbuf[wid][lc * 4 + r][c * 16 + lr] = f2bf(s[c][r]);
            asm volatile("s_waitcnt lgkmcnt(0)" ::: "memory");
            bf16x8 pah[2], pal[2];
#pragma unroll
            for (int kc = 0; kc < 2; ++kc)
                pah[kc] = *(const bf16x8*)&pbuf[wid][lr][kc * 32 + lc * 8];
            asm volatile("s_waitcnt lgkmcnt(0)" ::: "memory");
#pragma unroll
            for (int c = 0; c < 4; ++c)
#pragma unroll
                for (int r = 0; r < 4; ++r) {
                    float pv = s[c][r];
                    pbuf[wid][lc * 4 + r][c * 16 + lr] = f2bf(pv - bf2f(f2bf(pv)));
                }
            asm volatile("s_waitcnt lgkmcnt(0)" ::: "memory");
#pragma unroll
            for (int kc = 0; kc < 2; ++kc)
                pal[kc] = *(const bf16x8*)&pbuf[wid][lr][kc * 32 + lc * 8];
            // ---- PV (3-term) ----
#pragma unroll
            for (int kc = 0; kc < 2; ++kc) {
                if (k0 + kc * 32 <= q_hi) {
#pragma unroll
                    for (int n = 0; n < 8; ++n) {
                        bf16x8 vh8 = *(const bf16x8*)&sVh[cur][((kc * 8 + n) * 64 + lane) * 8];
                        bf16x8 vl8 = *(const bf16x8*)&sVl[cur][((kc * 8 + n) * 64 + lane) * 8];
                        oacc[n] = __builtin_amdgcn_mfma_f32_16x16x32_bf16(pah[kc], vh8, oacc[n], 0, 0, 0);
                        oacc[n] = __builtin_amdgcn_mfma_f32_16x16x32_bf16(pal[kc], vh8, oacc[n], 0, 0, 0);
                        oacc[n] = __builtin_amdgcn_mfma_f32_16x16x32_bf16(pah[kc], vl8, oacc[n], 0, 0, 0);
                    }
                }
            }
        }
        asm volatile("s_waitcnt vmcnt(0)" ::: "memory");
        __syncthreads();
        cur ^= 1;
    }
#pragma unroll
    for (int n = 0; n < 8; ++n) {
        int col = h * HD + n * 16 + lr;
#pragma unroll
        for (int r = 0; r < 4; ++r)
            qf[(size_t)(q0 + lc * 4 + r) * HID + col] = oacc[n][r] / l[r];
    }
}

// ---------------- Hadamard head-mix + per-row int4 requant -> int8 ----------
__global__ __launch_bounds__(256) void k_hadq(const float* __restrict__ attn,
        s8* __restrict__ a2, float* __restrict__ sa) {
    int t = blockIdx.x, tid = threadIdx.x;
    __shared__ float rowb[HID];
    const float* ar = attn + (size_t)t * HID;
#pragma unroll
    for (int i = 0; i < 4; ++i)
        *(f32x4*)&rowb[i * 1024 + tid * 4] = *(const f32x4*)(ar + i * 1024 + tid * 4);
    __syncthreads();
    float out[16], amax = 0.f;
#pragma unroll
    for (int i = 0; i < 16; ++i) {
        int o = tid + i * 256;
        int g = o >> 7, d = o & 127;
        float acc = 0.f;
#pragma unroll
        for (int hh = 0; hh < 32; ++hh) {
            float v = rowb[hh * 128 + d];
            acc += (__popc(g & hh) & 1) ? -v : v;
        }
        out[i] = acc * 0.17677669529663687f;
        amax = fmaxf(amax, fabsf(out[i]));
    }
#pragma unroll
    for (int off = 32; off >= 1; off >>= 1)
        amax = fmaxf(amax, __shfl_xor(amax, off));
    __shared__ float red[4];
    if ((tid & 63) == 0) red[tid >> 6] = amax;
    __syncthreads();
    amax = fmaxf(fmaxf(red[0], red[1]), fmaxf(red[2], red[3]));
    float s = fmaxf(amax / 7.f, 1e-8f);
    if (tid == 0) sa[t] = s;
    s8* o2 = a2 + (size_t)t * HID;
#pragma unroll
    for (int i = 0; i < 16; ++i) {
        float q = rintf(out[i] / s);
        q = fminf(fmaxf(q, -8.f), 7.f);
        o2[tid + i * 256] = (s8)(int)q;
    }
}

extern "C" void kernel_launch(void* const* d_in, const int* in_sizes, int n_in,
                              void* d_out, int out_size, void* d_ws, size_t ws_size,
                              hipStream_t stream) {
    const int* positions = (const int*)d_in[0];
    const float* hidden = (const float*)d_in[1];
    const int* wq = (const int*)d_in[2];
    const float* wq_s = (const float*)d_in[3];
    const int* wk = (const int*)d_in[4];
    const float* wk_s = (const float*)d_in[5];
    const int* wv = (const int*)d_in[6];
    const float* wv_s = (const float*)d_in[7];
    const int* wo = (const int*)d_in[8];
    const float* wo_s = (const float*)d_in[9];

    char* ws = (char*)d_ws;
    float* s_x = (float*)(ws);                      // 8 KB
    float* s_a = (float*)(ws + 8192);               // 8 KB
    s8* a8 = (s8*)(ws + 16384);                     // 8.39 MB (also a2)
    float* q_f = (float*)(ws + 16384 + 8388608);    // 33.55 MB
    float* k_f = (float*)(ws + 16384 + 8388608 + 33554432);  // 8.39 MB
    char* X = ws + 16384 + 8388608 + 33554432 + 8388608;     // 16.78 MB scratch
    u16* khf = (u16*)(X);
    u16* klf = (u16*)(X + 4194304);
    u16* vhf = (u16*)(X + 8388608);
    u16* vlf = (u16*)(X + 12582912);
    s8* w8 = (s8*)X;  // weight-pack slot (reused per GEMM)

    k_quant<<<T_SEQ, 256, 0, stream>>>(hidden, a8, s_x);
    // Q proj
    k_w8<<<(HID * KDIM / 4 + 255) / 256, 256, 0, stream>>>(wq, w8, HID * KDIM / 4);
    k_gemm8<0><<<dim3(16, 32), 256, 0, stream>>>(a8, w8, s_x, wq_s, q_f,
                                                 nullptr, T_SEQ, HID, KDIM);
    // K proj
    k_w8<<<(NKV * HD * KDIM / 4 + 255) / 256, 256, 0, stream>>>(wk, w8, NKV * HD * KDIM / 4);
    k_gemm8<0><<<dim3(16, 8), 256, 0, stream>>>(a8, w8, s_x, wk_s, k_f,
                                                nullptr, T_SEQ, NKV * HD, KDIM);
    // V proj (writes frag-ordered V^T hi/lo into X tail; reads wv8 from X head)
    k_w8<<<(NKV * HD * KDIM / 4 + 255) / 256, 256, 0, stream>>>(wv, w8, NKV * HD * KDIM / 4);
    k_gemm8<1><<<dim3(16, 8), 256, 0, stream>>>(a8, w8, s_x, wv_s, vhf,
                                                vlf, T_SEQ, NKV * HD, KDIM);
    k_rope<<<T_SEQ, 256, 0, stream>>>(q_f, k_f, positions, khf, klf);
    k_attn<<<dim3(T_SEQ / 128, NH), 512, 0, stream>>>(q_f, khf, klf, vhf, vlf);
    // O proj (X fully dead after attn)
    k_w8<<<(HID * KDIM / 4 + 255) / 256, 256, 0, stream>>>(wo, w8, HID * KDIM / 4);
    k_hadq<<<T_SEQ, 256, 0, stream>>>(q_f, a8, s_a);
    k_gemm8<0><<<dim3(16, 32), 256, 0, stream>>>(a8, w8, s_a, wo_s,
                                                 (float*)d_out, nullptr,
                                                 T_SEQ, HID, KDIM);
}

// Round 5
// 399.430 us; speedup vs baseline: 3.6570x; 1.3111x over previous
//
#include <hip/hip_runtime.h>

#define T_SEQ 2048
#define HID 4096
#define NH 32
#define NKV 8
#define HD 128
#define KDIM 4096

typedef unsigned short u16;
typedef signed char s8;
typedef __attribute__((ext_vector_type(4))) float f32x4;
typedef __attribute__((ext_vector_type(4))) int i32x4;
typedef __attribute__((ext_vector_type(8))) short s16x8;
typedef __attribute__((ext_vector_type(4))) short s16x4;
typedef __attribute__((ext_vector_type(8))) __bf16 bf16x8;

static __device__ __forceinline__ u16 f2bf(float f) {
    __bf16 b = (__bf16)f;
    return __builtin_bit_cast(unsigned short, b);
}
static __device__ __forceinline__ float bf2f(u16 b) {
    unsigned u = ((unsigned)b) << 16;
    return __builtin_bit_cast(float, u);
}
static __device__ __forceinline__ __bf16 bfbits(u16 b) {
    return __builtin_bit_cast(__bf16, b);
}

typedef __attribute__((address_space(1))) const void gas_t;
typedef __attribute__((address_space(3))) void las_t;
static __device__ __forceinline__ void gll16(const void* g, void* l) {
    __builtin_amdgcn_global_load_lds((gas_t*)g, (las_t*)l, 16, 0, 0);
}

// ---------------- per-row int4 quant of hidden_states -> int8 + scale -------
__global__ __launch_bounds__(256) void k_quant(const float* __restrict__ x,
                                               s8* __restrict__ qb,
                                               float* __restrict__ srow) {
    int row = blockIdx.x, tid = threadIdx.x;
    const float* xr = x + (size_t)row * HID;
    f32x4 v[4];
    float amax = 0.f;
#pragma unroll
    for (int i = 0; i < 4; ++i) {
        v[i] = *(const f32x4*)(xr + i * 1024 + tid * 4);
#pragma unroll
        for (int j = 0; j < 4; ++j) amax = fmaxf(amax, fabsf(v[i][j]));
    }
#pragma unroll
    for (int off = 32; off >= 1; off >>= 1)
        amax = fmaxf(amax, __shfl_xor(amax, off));
    __shared__ float red[4];
    if ((tid & 63) == 0) red[tid >> 6] = amax;
    __syncthreads();
    amax = fmaxf(fmaxf(red[0], red[1]), fmaxf(red[2], red[3]));
    float s = fmaxf(amax / 7.f, 1e-8f);
    if (tid == 0) srow[row] = s;
    int* qr = (int*)(qb + (size_t)row * HID);
#pragma unroll
    for (int i = 0; i < 4; ++i) {
        int p = 0;
#pragma unroll
        for (int j = 0; j < 4; ++j) {
            float q = rintf(v[i][j] / s);
            q = fminf(fmaxf(q, -8.f), 7.f);
            p |= ((int)q & 0xff) << (8 * j);
        }
        qr[i * 256 + tid] = p;
    }
}

// ---------------- weight pack int32 -> int8 ---------------------------------
__global__ __launch_bounds__(256) void k_w8(const int* __restrict__ w,
                                            s8* __restrict__ w8, int n4) {
    int i = blockIdx.x * 256 + threadIdx.x;
    if (i < n4) {
        i32x4 v = *(const i32x4*)(w + i * 4);
        int p = (v[0] & 0xff) | ((v[1] & 0xff) << 8) | ((v[2] & 0xff) << 16) |
                (v[3] << 24);
        ((int*)w8)[i] = p;
    }
}

// ---------------- int8 MFMA GEMM (exact): out = (A.W^T) * sRow * sCol -------
// MODE 0: f32 row-major out.  MODE 1: fragment-ordered V^T hi/lo bf16 out.
template <int MODE>
__global__ __launch_bounds__(256) void k_gemm8(const s8* __restrict__ A,
        const s8* __restrict__ W, const float* __restrict__ sRow,
        const float* __restrict__ sCol, void* __restrict__ outp,
        void* __restrict__ outp2, int M, int N, int K) {
    __shared__ __align__(16) s8 sA[16384], sB[16384];  // [128][128], XOR-swizzled
    int tid = threadIdx.x;
    int brow = blockIdx.x * 128, bcol = blockIdx.y * 128;
    int wid = tid >> 6, lane = tid & 63;
    int wr = (wid >> 1) * 64, wc = (wid & 1) * 64;
    int lr = lane & 15, lc = lane >> 4;
    i32x4 acc[4][4] = {};
    for (int k0 = 0; k0 < K; k0 += 128) {
        __syncthreads();
#pragma unroll
        for (int j = 0; j < 4; ++j) {
            int base = wid * 1024 + j * 4096;
            int o = base + lane * 16;
            int r = o >> 7;
            int c = (o & 127) ^ ((r & 7) << 4);  // inverse-swizzled source
            gll16(A + (size_t)(brow + r) * K + (k0 + c), (char*)sA + base);
            gll16(W + (size_t)(bcol + r) * K + (k0 + c), (char*)sB + base);
        }
        asm volatile("s_waitcnt vmcnt(0)" ::: "memory");
        __syncthreads();
#pragma unroll
        for (int kk = 0; kk < 2; ++kk) {
            i32x4 af[4], bf[4];
#pragma unroll
            for (int m = 0; m < 4; ++m) {
                int r = wr + m * 16 + lr;
                int sl = ((kk * 4 + lc) ^ (r & 7)) * 16;  // swizzled read
                af[m] = *(const i32x4*)&sA[r * 128 + sl];
            }
#pragma unroll
            for (int n = 0; n < 4; ++n) {
                int r = wc + n * 16 + lr;
                int sl = ((kk * 4 + lc) ^ (r & 7)) * 16;
                bf[n] = *(const i32x4*)&sB[r * 128 + sl];
            }
#pragma unroll
            for (int m = 0; m < 4; ++m)
#pragma unroll
                for (int n = 0; n < 4; ++n)
                    acc[m][n] = __builtin_amdgcn_mfma_i32_16x16x64_i8(
                        af[m], bf[n], acc[m][n], 0, 0, 0);
        }
    }
#pragma unroll
    for (int m = 0; m < 4; ++m) {
        int row0 = brow + wr + m * 16 + lc * 4;
#pragma unroll
        for (int n = 0; n < 4; ++n) {
            int col = bcol + wc + n * 16 + lr;
            float scl = sCol[col];
            if (MODE == 0) {
                float* o = (float*)outp;
#pragma unroll
                for (int r = 0; r < 4; ++r)
                    o[(size_t)(row0 + r) * N + col] =
                        (float)acc[m][n][r] * sRow[row0 + r] * scl;
            } else {
                u16* oh = (u16*)outp;
                u16* ol = (u16*)outp2;
                int kvh = col >> 7, d = col & 127;
                int nn = d >> 4, lrv = d & 15;
                int kt = row0 >> 6, rem = row0 & 63;
                int kc = rem >> 5, lcv = (rem & 31) >> 3, j0 = rem & 7;
                size_t base =
                    ((((size_t)(kvh * 32 + kt) * 2 + kc) * 8 + nn) * 64 +
                     lcv * 16 + lrv) * 8 + j0;
                s16x4 hh, ll;
#pragma unroll
                for (int r = 0; r < 4; ++r) {
                    float val = (float)acc[m][n][r] * sRow[row0 + r] * scl;
                    u16 hb = f2bf(val);
                    hh[r] = (short)hb;
                    ll[r] = (short)f2bf(val - bf2f(hb));
                }
                *(s16x4*)(oh + base) = hh;
                *(s16x4*)(ol + base) = ll;
            }
        }
    }
}

// ---------------- trig tables: one double pow/sincos per (t,d) --------------
__global__ __launch_bounds__(256) void k_trig(const int* __restrict__ pos,
        float* __restrict__ ctab, float* __restrict__ stab) {
    int idx = blockIdx.x * 256 + threadIdx.x;
    int t = idx >> 6, d = idx & 63;
    float p = (float)pos[t];
    float inv = (float)pow(10000.0, -(double)d / 64.0);
    float ang = p * inv;
    double dsn, dcs;
    sincos((double)ang, &dsn, &dcs);
    ctab[idx] = (float)dcs;
    stab[idx] = (float)dsn;
}

// ---------------- RoPE on K only -> fragment-ordered hi/lo bf16 -------------
__global__ __launch_bounds__(256) void k_ropek(const float* __restrict__ kf,
        const float* __restrict__ ctab, const float* __restrict__ stab,
        u16* __restrict__ khf, u16* __restrict__ klf) {
    int t = blockIdx.x, tid = threadIdx.x;
    int kt = t >> 6, rem = t & 63, cblk = rem >> 4, lrk = rem & 15;
    for (int idx = tid; idx < NKV * 64; idx += 256) {
        int kh = idx >> 6, d = idx & 63;
        float cs = ctab[t * 64 + d], sn = stab[t * 64 + d];
        size_t base = (size_t)t * (NKV * HD) + kh * HD;
        float x1 = kf[base + d], x2 = kf[base + d + 64];
        float r1 = x1 * cs - x2 * sn;
        float r2 = x2 * cs + x1 * sn;
        size_t tb = (((size_t)(kh * 32 + kt) * 4 + cblk) * 4) * 512;
#pragma unroll
        for (int half = 0; half < 2; ++half) {
            int x = d + half * 64;
            float rv = half ? r2 : r1;
            int dcx = x >> 5, lcx = (x & 31) >> 3, jx = x & 7;
            size_t ii = tb + (size_t)dcx * 512 + (lcx * 16 + lrk) * 8 + jx;
            u16 hb = f2bf(rv);
            khf[ii] = hb;
            klf[ii] = f2bf(rv - bf2f(hb));
        }
    }
}

// ---------------- GQA causal flash attention: paired q-tiles, 8 waves -------
// grid = (8, NH); block handles q-tiles {px, 15-px} -> uniform 34 kv-tiles.
// Q-RoPE fused into the Q load (reads raw q_f + trig tables).
__global__ __launch_bounds__(512, 2) void k_attn(float* __restrict__ qf,
        const u16* __restrict__ khf, const u16* __restrict__ klf,
        const u16* __restrict__ vhf, const u16* __restrict__ vlf,
        const float* __restrict__ ctab, const float* __restrict__ stab) {
    int h = blockIdx.y, kvh = h >> 2;
    int px = blockIdx.x;
    int tid = threadIdx.x, wid = tid >> 6, lane = tid & 63;
    int lr = lane & 15, lc = lane >> 4;
    __shared__ __align__(16) u16 sKh[2][8192], sKl[2][8192];
    __shared__ __align__(16) u16 sVh[2][8192], sVl[2][8192];
    __shared__ __align__(16) u16 pbuf[8][16][72];
    const float SCL = 0.12751744f;  // 1/sqrt(128) * log2(e)
    size_t kvbase = (size_t)kvh * 32 * 8192;
    // wave -> (array, half) staging assignment
    const u16* gsel;
    int sel = wid >> 1;
    u16* lsel0;
    u16* lsel1;
    if (sel == 0)      { gsel = khf; lsel0 = sKh[0]; lsel1 = sKh[1]; }
    else if (sel == 1) { gsel = klf; lsel0 = sKl[0]; lsel1 = sKl[1]; }
    else if (sel == 2) { gsel = vhf; lsel0 = sVh[0]; lsel1 = sVh[1]; }
    else               { gsel = vlf; lsel0 = sVl[0]; lsel1 = sVl[1]; }
    int halfoff = (wid & 1) * 8192;  // bytes
    auto stage = [&](int buf, int kt) {
        const char* g = (const char*)(gsel + kvbase + (size_t)kt * 8192);
        char* dst = (char*)(buf ? lsel1 : lsel0);
#pragma unroll
        for (int j = 0; j < 8; ++j) {
            int off = halfoff + j * 1024;
            gll16(g + off + lane * 16, dst + off);
        }
    };
    for (int phase = 0; phase < 2; ++phase) {
        int bx = phase == 0 ? px : 15 - px;
        int q0 = bx * 128 + wid * 16;
        int q_hi = q0 + 15;
        // ---- Q load + fused RoPE + scale + hi/lo split ----
        bf16x8 aqh[4], aql[4];
        {
            const float* qrow = qf + (size_t)(q0 + lr) * HID + h * HD;
            const float* ct = ctab + (size_t)(q0 + lr) * 64 + lc * 8;
            const float* st = stab + (size_t)(q0 + lr) * 64 + lc * 8;
            float qv[4][8];
#pragma unroll
            for (int dc = 0; dc < 4; ++dc) {
                f32x4 a = *(const f32x4*)(qrow + dc * 32 + lc * 8);
                f32x4 b = *(const f32x4*)(qrow + dc * 32 + lc * 8 + 4);
#pragma unroll
                for (int j = 0; j < 4; ++j) { qv[dc][j] = a[j]; qv[dc][j + 4] = b[j]; }
            }
            float cs[2][8], sn[2][8];
#pragma unroll
            for (int hf = 0; hf < 2; ++hf) {
                f32x4 c0 = *(const f32x4*)(ct + hf * 32);
                f32x4 c1 = *(const f32x4*)(ct + hf * 32 + 4);
                f32x4 s0 = *(const f32x4*)(st + hf * 32);
                f32x4 s1 = *(const f32x4*)(st + hf * 32 + 4);
#pragma unroll
                for (int j = 0; j < 4; ++j) {
                    cs[hf][j] = c0[j]; cs[hf][j + 4] = c1[j];
                    sn[hf][j] = s0[j]; sn[hf][j + 4] = s1[j];
                }
            }
#pragma unroll
            for (int dc0 = 0; dc0 < 2; ++dc0)
#pragma unroll
                for (int j = 0; j < 8; ++j) {
                    float c = cs[dc0][j], s2 = sn[dc0][j];
                    float x1 = qv[dc0][j], x2 = qv[dc0 + 2][j];
                    qv[dc0][j] = x1 * c - x2 * s2;
                    qv[dc0 + 2][j] = x2 * c + x1 * s2;
                }
#pragma unroll
            for (int dc = 0; dc < 4; ++dc)
#pragma unroll
                for (int j = 0; j < 8; ++j) {
                    float v = qv[dc][j] * SCL;
                    u16 hb = f2bf(v);
                    aqh[dc][j] = bfbits(hb);
                    aql[dc][j] = bfbits(f2bf(v - bf2f(hb)));
                }
        }
        f32x4 oacc[8] = {};
        float m[4], l[4];
#pragma unroll
        for (int r = 0; r < 4; ++r) { m[r] = -1e30f; l[r] = 0.f; }
        int NT = 2 * bx + 2;
        stage(0, 0);
        asm volatile("s_waitcnt vmcnt(0)" ::: "memory");
        __syncthreads();
        int cur = 0;
        for (int kt = 0; kt < NT; ++kt) {
            if (kt + 1 < NT) stage(cur ^ 1, kt + 1);
            int k0 = kt * 64;
            if (k0 <= q_hi) {
                // ---- QK^T: 3-term hi/lo ----
                f32x4 s[4];
                __builtin_amdgcn_s_setprio(1);
#pragma unroll
                for (int c = 0; c < 4; ++c) {
                    if (k0 + c * 16 <= q_hi) {
                        f32x4 a = {};
#pragma unroll
                        for (int dc = 0; dc < 4; ++dc) {
                            bf16x8 kh8 = *(const bf16x8*)&sKh[cur][((c * 4 + dc) * 64 + lane) * 8];
                            bf16x8 kl8 = *(const bf16x8*)&sKl[cur][((c * 4 + dc) * 64 + lane) * 8];
                            a = __builtin_amdgcn_mfma_f32_16x16x32_bf16(aqh[dc], kh8, a, 0, 0, 0);
                            a = __builtin_amdgcn_mfma_f32_16x16x32_bf16(aql[dc], kh8, a, 0, 0, 0);
                            a = __builtin_amdgcn_mfma_f32_16x16x32_bf16(aqh[dc], kl8, a, 0, 0, 0);
                        }
                        s[c] = a;
                    }
                }
                __builtin_amdgcn_s_setprio(0);
                // ---- mask + running max (log2 units) ----
                float tmax[4] = {-1e30f, -1e30f, -1e30f, -1e30f};
#pragma unroll
                for (int c = 0; c < 4; ++c) {
                    bool active = (k0 + c * 16 <= q_hi);
                    bool edge = (k0 + c * 16 + 15 >= q0);
#pragma unroll
                    for (int r = 0; r < 4; ++r) {
                        float sv = active ? s[c][r] : -1e30f;
                        if (active && edge) {
                            int key = k0 + c * 16 + lr, qr = q0 + lc * 4 + r;
                            if (key > qr) sv = -1e30f;
                        }
                        s[c][r] = sv;
                        tmax[r] = fmaxf(tmax[r], sv);
                    }
                }
#pragma unroll
                for (int off = 1; off < 16; off <<= 1)
#pragma unroll
                    for (int r = 0; r < 4; ++r)
                        tmax[r] = fmaxf(tmax[r], __shfl_xor(tmax[r], off));
                float alpha[4], psum[4] = {0.f, 0.f, 0.f, 0.f};
                bool anyup = false;
#pragma unroll
                for (int r = 0; r < 4; ++r) {
                    float mn = fmaxf(m[r], tmax[r]);
                    alpha[r] = exp2f(m[r] - mn);
                    anyup |= (mn > m[r]);
                    m[r] = mn;
                }
#pragma unroll
                for (int c = 0; c < 4; ++c)
#pragma unroll
                    for (int r = 0; r < 4; ++r) {
                        float pv = exp2f(s[c][r] - m[r]);
                        s[c][r] = pv;
                        psum[r] += pv;
                    }
#pragma unroll
                for (int off = 1; off < 16; off <<= 1)
#pragma unroll
                    for (int r = 0; r < 4; ++r) psum[r] += __shfl_xor(psum[r], off);
#pragma unroll
                for (int r = 0; r < 4; ++r) l[r] = l[r] * alpha[r] + psum[r];
                if (__any(anyup)) {
#pragma unroll
                    for (int n = 0; n < 8; ++n)
#pragma unroll
                        for (int r = 0; r < 4; ++r) oacc[n][r] *= alpha[r];
                }
                // ---- P -> pbuf (hi pass, then lo pass) ----
#pragma unroll
                for (int c = 0; c < 4; ++c)
#pragma unroll
                    for (int r = 0; r < 4; ++r)
                        pbuf[wid][lc * 4 + r][c * 16 + lr] = f2bf(s[c][r]);
                asm volatile("s_waitcnt lgkmcnt(0)" ::: "memory");
                bf16x8 pah[2], pal[2];
#pragma unroll
                for (int kc = 0; kc < 2; ++kc)
                    pah[kc] = *(const bf16x8*)&pbuf[wid][lr][kc * 32 + lc * 8];
                asm volatile("s_waitcnt lgkmcnt(0)" ::: "memory");
#pragma unroll
                for (int c = 0; c < 4; ++c)
#pragma unroll
                    for (int r = 0; r < 4; ++r) {
                        float pv = s[c][r];
                        pbuf[wid][lc * 4 + r][c * 16 + lr] = f2bf(pv - bf2f(f2bf(pv)));
                    }
                asm volatile("s_waitcnt lgkmcnt(0)" ::: "memory");
#pragma unroll
                for (int kc = 0; kc < 2; ++kc)
                    pal[kc] = *(const bf16x8*)&pbuf[wid][lr][kc * 32 + lc * 8];
                // ---- PV (3-term) ----
                __builtin_amdgcn_s_setprio(1);
#pragma unroll
                for (int kc = 0; kc < 2; ++kc) {
                    if (k0 + kc * 32 <= q_hi) {
#pragma unroll
                        for (int n = 0; n < 8; ++n) {
                            bf16x8 vh8 = *(const bf16x8*)&sVh[cur][((kc * 8 + n) * 64 + lane) * 8];
                            bf16x8 vl8 = *(const bf16x8*)&sVl[cur][((kc * 8 + n) * 64 + lane) * 8];
                            oacc[n] = __builtin_amdgcn_mfma_f32_16x16x32_bf16(pah[kc], vh8, oacc[n], 0, 0, 0);
                            oacc[n] = __builtin_amdgcn_mfma_f32_16x16x32_bf16(pal[kc], vh8, oacc[n], 0, 0, 0);
                            oacc[n] = __builtin_amdgcn_mfma_f32_16x16x32_bf16(pah[kc], vl8, oacc[n], 0, 0, 0);
                        }
                    }
                }
                __builtin_amdgcn_s_setprio(0);
            }
            asm volatile("s_waitcnt vmcnt(0)" ::: "memory");
            __syncthreads();
            cur ^= 1;
        }
        // ---- write O for this phase (in-place over this block's Q region) ----
#pragma unroll
        for (int n = 0; n < 8; ++n) {
            int col = h * HD + n * 16 + lr;
#pragma unroll
            for (int r = 0; r < 4; ++r)
                qf[(size_t)(q0 + lc * 4 + r) * HID + col] = oacc[n][r] / l[r];
        }
        __syncthreads();  // O-writes before next phase re-stages LDS
    }
}

// ---------------- Hadamard head-mix (register FWHT) + int4 requant ----------
__global__ __launch_bounds__(256) void k_hadq(const float* __restrict__ attn,
        s8* __restrict__ a2, float* __restrict__ sa) {
    int t = blockIdx.x, tid = threadIdx.x;
    int w = tid >> 6, lane = tid & 63;
    int d = (w & 1) * 64 + lane;  // 0..127
    int half = w >> 1;            // h-half: 0 or 1
    __shared__ float rowb[HID];
    const float* ar = attn + (size_t)t * HID;
#pragma unroll
    for (int i = 0; i < 4; ++i)
        *(f32x4*)&rowb[i * 1024 + tid * 4] = *(const f32x4*)(ar + i * 1024 + tid * 4);
    __syncthreads();
    // load own 16 h-values for column d
    float u[16];
#pragma unroll
    for (int i = 0; i < 16; ++i) u[i] = rowb[(half * 16 + i) * 128 + d];
    // in-register FWHT16 (natural/Sylvester ordering)
#pragma unroll
    for (int s = 1; s < 16; s <<= 1)
#pragma unroll
        for (int i = 0; i < 16; ++i)
            if (!(i & s)) {
                float a = u[i], b = u[i | s];
                u[i] = a + b;
                u[i | s] = a - b;
            }
    // exchange halves via LDS (overwrite own x slots; no cross-thread hazard)
#pragma unroll
    for (int i = 0; i < 16; ++i) rowb[(half * 16 + i) * 128 + d] = u[i];
    __syncthreads();
    float y[16], amax = 0.f;
#pragma unroll
    for (int i = 0; i < 16; ++i) {
        float o = rowb[((half ^ 1) * 16 + i) * 128 + d];
        float yv = half ? (o - u[i]) : (u[i] + o);
        yv *= 0.17677669529663687f;  // 1/sqrt(32)
        y[i] = yv;
        amax = fmaxf(amax, fabsf(yv));
    }
#pragma unroll
    for (int off = 32; off >= 1; off >>= 1)
        amax = fmaxf(amax, __shfl_xor(amax, off));
    __shared__ float red[4];
    if ((tid & 63) == 0) red[tid >> 6] = amax;
    __syncthreads();
    amax = fmaxf(fmaxf(red[0], red[1]), fmaxf(red[2], red[3]));
    float s = fmaxf(amax / 7.f, 1e-8f);
    if (tid == 0) sa[t] = s;
    s8* o2 = a2 + (size_t)t * HID;
#pragma unroll
    for (int i = 0; i < 16; ++i) {
        float q = rintf(y[i] / s);
        q = fminf(fmaxf(q, -8.f), 7.f);
        o2[(half * 16 + i) * 128 + d] = (s8)(int)q;
    }
}

extern "C" void kernel_launch(void* const* d_in, const int* in_sizes, int n_in,
                              void* d_out, int out_size, void* d_ws, size_t ws_size,
                              hipStream_t stream) {
    const int* positions = (const int*)d_in[0];
    const float* hidden = (const float*)d_in[1];
    const int* wq = (const int*)d_in[2];
    const float* wq_s = (const float*)d_in[3];
    const int* wk = (const int*)d_in[4];
    const float* wk_s = (const float*)d_in[5];
    const int* wv = (const int*)d_in[6];
    const float* wv_s = (const float*)d_in[7];
    const int* wo = (const int*)d_in[8];
    const float* wo_s = (const float*)d_in[9];

    char* ws = (char*)d_ws;
    float* s_x = (float*)(ws);                      // 8 KB
    float* s_a = (float*)(ws + 8192);               // 8 KB
    float* ctab = (float*)(ws + 16384);             // 512 KB
    float* stab = (float*)(ws + 16384 + 524288);    // 512 KB
    char* base1 = ws + 16384 + 1048576;
    s8* a8 = (s8*)base1;                            // 8.39 MB (also a2)
    float* q_f = (float*)(base1 + 8388608);         // 33.55 MB
    float* k_f = (float*)(base1 + 8388608 + 33554432);       // 8.39 MB
    char* X = base1 + 8388608 + 33554432 + 8388608;          // 16.78 MB scratch
    u16* khf = (u16*)(X);
    u16* klf = (u16*)(X + 4194304);
    u16* vhf = (u16*)(X + 8388608);
    u16* vlf = (u16*)(X + 12582912);
    s8* w8 = (s8*)X;  // weight-pack slot (reused per GEMM)

    k_trig<<<T_SEQ * 64 / 256, 256, 0, stream>>>(positions, ctab, stab);
    k_quant<<<T_SEQ, 256, 0, stream>>>(hidden, a8, s_x);
    // Q proj
    k_w8<<<(HID * KDIM / 4 + 255) / 256, 256, 0, stream>>>(wq, w8, HID * KDIM / 4);
    k_gemm8<0><<<dim3(16, 32), 256, 0, stream>>>(a8, w8, s_x, wq_s, q_f,
                                                 nullptr, T_SEQ, HID, KDIM);
    // K proj
    k_w8<<<(NKV * HD * KDIM / 4 + 255) / 256, 256, 0, stream>>>(wk, w8, NKV * HD * KDIM / 4);
    k_gemm8<0><<<dim3(16, 8), 256, 0, stream>>>(a8, w8, s_x, wk_s, k_f,
                                                nullptr, T_SEQ, NKV * HD, KDIM);
    // V proj (writes frag-ordered V^T hi/lo into X tail)
    k_w8<<<(NKV * HD * KDIM / 4 + 255) / 256, 256, 0, stream>>>(wv, w8, NKV * HD * KDIM / 4);
    k_gemm8<1><<<dim3(16, 8), 256, 0, stream>>>(a8, w8, s_x, wv_s, vhf,
                                                vlf, T_SEQ, NKV * HD, KDIM);
    k_ropek<<<T_SEQ, 256, 0, stream>>>(k_f, ctab, stab, khf, klf);
    k_attn<<<dim3(8, NH), 512, 0, stream>>>(q_f, khf, klf, vhf, vlf, ctab, stab);
    // O proj (X fully dead after attn)
    k_w8<<<(HID * KDIM / 4 + 255) / 256, 256, 0, stream>>>(wo, w8, HID * KDIM / 4);
    k_hadq<<<T_SEQ, 256, 0, stream>>>(q_f, a8, s_a);
    k_gemm8<0><<<dim3(16, 32), 256, 0, stream>>>(a8, w8, s_a, wo_s,
                                                 (float*)d_out, nullptr,
                                                 T_SEQ, HID, KDIM);
}

// Round 6
// 354.953 us; speedup vs baseline: 4.1152x; 1.1253x over previous
//
#include <hip/hip_runtime.h>

#define T_SEQ 2048
#define HID 4096
#define NH 32
#define NKV 8
#define HD 128
#define KDIM 4096

typedef unsigned short u16;
typedef signed char s8;
typedef __attribute__((ext_vector_type(4))) float f32x4;
typedef __attribute__((ext_vector_type(4))) int i32x4;
typedef __attribute__((ext_vector_type(8))) short s16x8;
typedef __attribute__((ext_vector_type(4))) short s16x4;
typedef __attribute__((ext_vector_type(8))) __bf16 bf16x8;

static __device__ __forceinline__ u16 f2bf(float f) {
    __bf16 b = (__bf16)f;
    return __builtin_bit_cast(unsigned short, b);
}
static __device__ __forceinline__ float bf2f(u16 b) {
    unsigned u = ((unsigned)b) << 16;
    return __builtin_bit_cast(float, u);
}
static __device__ __forceinline__ __bf16 bfbits(u16 b) {
    return __builtin_bit_cast(__bf16, b);
}

typedef __attribute__((address_space(1))) const void gas_t;
typedef __attribute__((address_space(3))) void las_t;
static __device__ __forceinline__ void gll16(const void* g, void* l) {
    __builtin_amdgcn_global_load_lds((gas_t*)g, (las_t*)l, 16, 0, 0);
}

// ---------------- per-row int4 quant of hidden_states -> int8 + scale -------
__global__ __launch_bounds__(256) void k_quant(const float* __restrict__ x,
                                               s8* __restrict__ qb,
                                               float* __restrict__ srow) {
    int row = blockIdx.x, tid = threadIdx.x;
    const float* xr = x + (size_t)row * HID;
    f32x4 v[4];
    float amax = 0.f;
#pragma unroll
    for (int i = 0; i < 4; ++i) {
        v[i] = *(const f32x4*)(xr + i * 1024 + tid * 4);
#pragma unroll
        for (int j = 0; j < 4; ++j) amax = fmaxf(amax, fabsf(v[i][j]));
    }
#pragma unroll
    for (int off = 32; off >= 1; off >>= 1)
        amax = fmaxf(amax, __shfl_xor(amax, off));
    __shared__ float red[4];
    if ((tid & 63) == 0) red[tid >> 6] = amax;
    __syncthreads();
    amax = fmaxf(fmaxf(red[0], red[1]), fmaxf(red[2], red[3]));
    float s = fmaxf(amax / 7.f, 1e-8f);
    if (tid == 0) srow[row] = s;
    int* qr = (int*)(qb + (size_t)row * HID);
#pragma unroll
    for (int i = 0; i < 4; ++i) {
        int p = 0;
#pragma unroll
        for (int j = 0; j < 4; ++j) {
            float q = rintf(v[i][j] / s);
            q = fminf(fmaxf(q, -8.f), 7.f);
            p |= ((int)q & 0xff) << (8 * j);
        }
        qr[i * 256 + tid] = p;
    }
}

// ---------------- merged weight pack (wq,wk,wv) int32 -> int8, 16B/thread ---
__global__ __launch_bounds__(256) void k_w8x3(const int* __restrict__ wq,
        const int* __restrict__ wk, const int* __restrict__ wv,
        s8* __restrict__ q8, s8* __restrict__ k8, s8* __restrict__ v8) {
    size_t i = ((size_t)blockIdx.x * 256 + threadIdx.x) * 16;
    const int* src; s8* dst; size_t off;
    if (i < 16777216) { src = wq; dst = q8; off = i; }
    else if (i < 20971520) { src = wk; dst = k8; off = i - 16777216; }
    else { src = wv; dst = v8; off = i - 20971520; }
    i32x4 o;
#pragma unroll
    for (int j = 0; j < 4; ++j) {
        i32x4 v = *(const i32x4*)(src + off + j * 4);
        o[j] = (v[0] & 0xff) | ((v[1] & 0xff) << 8) | ((v[2] & 0xff) << 16) |
               (v[3] << 24);
    }
    *(i32x4*)(dst + off) = o;
}

// ---------------- weight pack int32 -> int8 (wo), 16B/thread ----------------
__global__ __launch_bounds__(256) void k_w8(const int* __restrict__ w,
                                            s8* __restrict__ w8) {
    size_t i = ((size_t)blockIdx.x * 256 + threadIdx.x) * 16;
    i32x4 o;
#pragma unroll
    for (int j = 0; j < 4; ++j) {
        i32x4 v = *(const i32x4*)(w + i + j * 4);
        o[j] = (v[0] & 0xff) | ((v[1] & 0xff) << 8) | ((v[2] & 0xff) << 16) |
               (v[3] << 24);
    }
    *(i32x4*)(w8 + i) = o;
}

// ---------------- int8 MFMA GEMM (exact), f32 row-major out -----------------
__global__ __launch_bounds__(256) void k_gemm8(const s8* __restrict__ A,
        const s8* __restrict__ W, const float* __restrict__ sRow,
        const float* __restrict__ sCol, float* __restrict__ outp,
        int M, int N, int K) {
    __shared__ __align__(16) s8 sA[16384], sB[16384];  // [128][128], XOR-swizzled
    int tid = threadIdx.x;
    int brow = blockIdx.x * 128, bcol = blockIdx.y * 128;
    int wid = tid >> 6, lane = tid & 63;
    int wr = (wid >> 1) * 64, wc = (wid & 1) * 64;
    int lr = lane & 15, lc = lane >> 4;
    i32x4 acc[4][4] = {};
    for (int k0 = 0; k0 < K; k0 += 128) {
        __syncthreads();
#pragma unroll
        for (int j = 0; j < 4; ++j) {
            int base = wid * 1024 + j * 4096;
            int o = base + lane * 16;
            int r = o >> 7;
            int c = (o & 127) ^ ((r & 7) << 4);
            gll16(A + (size_t)(brow + r) * K + (k0 + c), (char*)sA + base);
            gll16(W + (size_t)(bcol + r) * K + (k0 + c), (char*)sB + base);
        }
        asm volatile("s_waitcnt vmcnt(0)" ::: "memory");
        __syncthreads();
#pragma unroll
        for (int kk = 0; kk < 2; ++kk) {
            i32x4 af[4], bf[4];
#pragma unroll
            for (int m = 0; m < 4; ++m) {
                int r = wr + m * 16 + lr;
                int sl = ((kk * 4 + lc) ^ (r & 7)) * 16;
                af[m] = *(const i32x4*)&sA[r * 128 + sl];
            }
#pragma unroll
            for (int n = 0; n < 4; ++n) {
                int r = wc + n * 16 + lr;
                int sl = ((kk * 4 + lc) ^ (r & 7)) * 16;
                bf[n] = *(const i32x4*)&sB[r * 128 + sl];
            }
#pragma unroll
            for (int m = 0; m < 4; ++m)
#pragma unroll
                for (int n = 0; n < 4; ++n)
                    acc[m][n] = __builtin_amdgcn_mfma_i32_16x16x64_i8(
                        af[m], bf[n], acc[m][n], 0, 0, 0);
        }
    }
#pragma unroll
    for (int m = 0; m < 4; ++m) {
        int row0 = brow + wr + m * 16 + lc * 4;
#pragma unroll
        for (int n = 0; n < 4; ++n) {
            int col = bcol + wc + n * 16 + lr;
            float scl = sCol[col];
#pragma unroll
            for (int r = 0; r < 4; ++r)
                outp[(size_t)(row0 + r) * N + col] =
                    (float)acc[m][n][r] * sRow[row0 + r] * scl;
        }
    }
}

// ---------------- fused K+V int8 GEMM: by<8 -> K (f32), by>=8 -> V (frag) ---
__global__ __launch_bounds__(256) void k_gemmkv(const s8* __restrict__ A,
        const s8* __restrict__ Wk, const s8* __restrict__ Wv,
        const float* __restrict__ sRow, const float* __restrict__ sColK,
        const float* __restrict__ sColV, float* __restrict__ kout,
        u16* __restrict__ vouth, u16* __restrict__ voutl) {
    __shared__ __align__(16) s8 sA[16384], sB[16384];
    int tid = threadIdx.x;
    int by = blockIdx.y;
    int isV = by >> 3;
    const s8* W = isV ? Wv : Wk;
    int brow = blockIdx.x * 128, bcol = (by & 7) * 128;
    const int K = KDIM, M = T_SEQ, N = NKV * HD;
    int wid = tid >> 6, lane = tid & 63;
    int wr = (wid >> 1) * 64, wc = (wid & 1) * 64;
    int lr = lane & 15, lc = lane >> 4;
    i32x4 acc[4][4] = {};
    for (int k0 = 0; k0 < K; k0 += 128) {
        __syncthreads();
#pragma unroll
        for (int j = 0; j < 4; ++j) {
            int base = wid * 1024 + j * 4096;
            int o = base + lane * 16;
            int r = o >> 7;
            int c = (o & 127) ^ ((r & 7) << 4);
            gll16(A + (size_t)(brow + r) * K + (k0 + c), (char*)sA + base);
            gll16(W + (size_t)(bcol + r) * K + (k0 + c), (char*)sB + base);
        }
        asm volatile("s_waitcnt vmcnt(0)" ::: "memory");
        __syncthreads();
#pragma unroll
        for (int kk = 0; kk < 2; ++kk) {
            i32x4 af[4], bf[4];
#pragma unroll
            for (int m = 0; m < 4; ++m) {
                int r = wr + m * 16 + lr;
                int sl = ((kk * 4 + lc) ^ (r & 7)) * 16;
                af[m] = *(const i32x4*)&sA[r * 128 + sl];
            }
#pragma unroll
            for (int n = 0; n < 4; ++n) {
                int r = wc + n * 16 + lr;
                int sl = ((kk * 4 + lc) ^ (r & 7)) * 16;
                bf[n] = *(const i32x4*)&sB[r * 128 + sl];
            }
#pragma unroll
            for (int m = 0; m < 4; ++m)
#pragma unroll
                for (int n = 0; n < 4; ++n)
                    acc[m][n] = __builtin_amdgcn_mfma_i32_16x16x64_i8(
                        af[m], bf[n], acc[m][n], 0, 0, 0);
        }
    }
#pragma unroll
    for (int m = 0; m < 4; ++m) {
        int row0 = brow + wr + m * 16 + lc * 4;
#pragma unroll
        for (int n = 0; n < 4; ++n) {
            int col = bcol + wc + n * 16 + lr;
            if (!isV) {
                float scl = sColK[col];
#pragma unroll
                for (int r = 0; r < 4; ++r)
                    kout[(size_t)(row0 + r) * N + col] =
                        (float)acc[m][n][r] * sRow[row0 + r] * scl;
            } else {
                float scl = sColV[col];
                int kvh = col >> 7, d = col & 127;
                int nn = d >> 4, lrv = d & 15;
                int kt = row0 >> 6, rem = row0 & 63;
                int kc = rem >> 5, lcv = (rem & 31) >> 3, j0 = rem & 7;
                size_t base =
                    ((((size_t)(kvh * 32 + kt) * 2 + kc) * 8 + nn) * 64 +
                     lcv * 16 + lrv) * 8 + j0;
                s16x4 hh, ll;
#pragma unroll
                for (int r = 0; r < 4; ++r) {
                    float val = (float)acc[m][n][r] * sRow[row0 + r] * scl;
                    u16 hb = f2bf(val);
                    hh[r] = (short)hb;
                    ll[r] = (short)f2bf(val - bf2f(hb));
                }
                *(s16x4*)(vouth + base) = hh;
                *(s16x4*)(voutl + base) = ll;
            }
        }
    }
}

// ---------------- trig tables: one double pow/sincos per (t,d) --------------
__global__ __launch_bounds__(256) void k_trig(const int* __restrict__ pos,
        float* __restrict__ ctab, float* __restrict__ stab) {
    int idx = blockIdx.x * 256 + threadIdx.x;
    int t = idx >> 6, d = idx & 63;
    float p = (float)pos[t];
    float inv = (float)pow(10000.0, -(double)d / 64.0);
    float ang = p * inv;
    double dsn, dcs;
    sincos((double)ang, &dsn, &dcs);
    ctab[idx] = (float)dcs;
    stab[idx] = (float)dsn;
}

// ---------------- RoPE on K only -> fragment-ordered hi/lo bf16 -------------
__global__ __launch_bounds__(256) void k_ropek(const float* __restrict__ kf,
        const float* __restrict__ ctab, const float* __restrict__ stab,
        u16* __restrict__ khf, u16* __restrict__ klf) {
    int t = blockIdx.x, tid = threadIdx.x;
    int kt = t >> 6, rem = t & 63, cblk = rem >> 4, lrk = rem & 15;
    for (int idx = tid; idx < NKV * 64; idx += 256) {
        int kh = idx >> 6, d = idx & 63;
        float cs = ctab[t * 64 + d], sn = stab[t * 64 + d];
        size_t base = (size_t)t * (NKV * HD) + kh * HD;
        float x1 = kf[base + d], x2 = kf[base + d + 64];
        float r1 = x1 * cs - x2 * sn;
        float r2 = x2 * cs + x1 * sn;
        size_t tb = (((size_t)(kh * 32 + kt) * 4 + cblk) * 4) * 512;
#pragma unroll
        for (int half = 0; half < 2; ++half) {
            int x = d + half * 64;
            float rv = half ? r2 : r1;
            int dcx = x >> 5, lcx = (x & 31) >> 3, jx = x & 7;
            size_t ii = tb + (size_t)dcx * 512 + (lcx * 16 + lrk) * 8 + jx;
            u16 hb = f2bf(rv);
            khf[ii] = hb;
            klf[ii] = f2bf(rv - bf2f(hb));
        }
    }
}

// ---------------- GQA causal flash attention ---------------------------------
// 512 blocks (complementary-pair swizzle: bid & bid+256 -> same CU, bx & 15-bx),
// 8 waves, KVBLK=64 single-buffered, LDS 75.8KB -> 2 blocks/CU.
// QK^T 3-term hi/lo; PV 2-term with l-consistent bf16-rounded P.
__global__ __launch_bounds__(512, 4) void k_attn(float* __restrict__ qf,
        const u16* __restrict__ khf, const u16* __restrict__ klf,
        const u16* __restrict__ vhf, const u16* __restrict__ vlf,
        const float* __restrict__ ctab, const float* __restrict__ stab) {
    int bid = blockIdx.x;
    int lo = bid & 255, hi = bid >> 8;
    int h = lo & 31;
    int bx = hi ? 15 - (lo >> 5) : (lo >> 5);
    int kvh = h >> 2;
    int tid = threadIdx.x, wid = tid >> 6, lane = tid & 63;
    int lr = lane & 15, lc = lane >> 4;
    int q0 = bx * 128 + wid * 16, q_hi = q0 + 15;
    __shared__ __align__(16) u16 smem[37888];  // K hi/lo, V hi/lo, pbuf
    u16* pb = smem + 32768 + wid * 640;        // per-wave [16][40]
    const float SCL = 0.12751744f;             // 1/sqrt(128) * log2(e)
    size_t kvbase = (size_t)kvh * 32 * 8192;
    int sel = wid >> 1;
    const u16* gsel = sel == 0 ? khf : sel == 1 ? klf : sel == 2 ? vhf : vlf;
    char* ldst = (char*)smem + sel * 16384 + (wid & 1) * 8192;
    // ---- Q load + fused RoPE + scale + hi/lo split ----
    bf16x8 aqh[4], aql[4];
    {
        const float* qrow = qf + (size_t)(q0 + lr) * HID + h * HD;
        const float* ct = ctab + (size_t)(q0 + lr) * 64 + lc * 8;
        const float* st = stab + (size_t)(q0 + lr) * 64 + lc * 8;
        float qv[4][8];
#pragma unroll
        for (int dc = 0; dc < 4; ++dc) {
            f32x4 a = *(const f32x4*)(qrow + dc * 32 + lc * 8);
            f32x4 b = *(const f32x4*)(qrow + dc * 32 + lc * 8 + 4);
#pragma unroll
            for (int j = 0; j < 4; ++j) { qv[dc][j] = a[j]; qv[dc][j + 4] = b[j]; }
        }
        float cs[2][8], sn[2][8];
#pragma unroll
        for (int hf = 0; hf < 2; ++hf) {
            f32x4 c0 = *(const f32x4*)(ct + hf * 32);
            f32x4 c1 = *(const f32x4*)(ct + hf * 32 + 4);
            f32x4 s0 = *(const f32x4*)(st + hf * 32);
            f32x4 s1 = *(const f32x4*)(st + hf * 32 + 4);
#pragma unroll
            for (int j = 0; j < 4; ++j) {
                cs[hf][j] = c0[j]; cs[hf][j + 4] = c1[j];
                sn[hf][j] = s0[j]; sn[hf][j + 4] = s1[j];
            }
        }
#pragma unroll
        for (int dc0 = 0; dc0 < 2; ++dc0)
#pragma unroll
            for (int j = 0; j < 8; ++j) {
                float c = cs[dc0][j], s2 = sn[dc0][j];
                float x1 = qv[dc0][j], x2 = qv[dc0 + 2][j];
                qv[dc0][j] = x1 * c - x2 * s2;
                qv[dc0 + 2][j] = x2 * c + x1 * s2;
            }
#pragma unroll
        for (int dc = 0; dc < 4; ++dc)
#pragma unroll
            for (int j = 0; j < 8; ++j) {
                float v = qv[dc][j] * SCL;
                u16 hb = f2bf(v);
                aqh[dc][j] = bfbits(hb);
                aql[dc][j] = bfbits(f2bf(v - bf2f(hb)));
            }
    }
    f32x4 oacc[8] = {};
    float m[4], l[4];
#pragma unroll
    for (int r = 0; r < 4; ++r) { m[r] = -1e30f; l[r] = 0.f; }
    int NT = 2 * bx + 2;
    for (int kt = 0; kt < NT; ++kt) {
        // ---- stage tile (single-buffered; prior barrier guarantees LDS free)
        {
            const char* g =
                (const char*)(gsel + kvbase + (size_t)kt * 8192) + (wid & 1) * 8192;
#pragma unroll
            for (int j = 0; j < 8; ++j)
                gll16(g + j * 1024 + lane * 16, ldst + j * 1024);
        }
        asm volatile("s_waitcnt vmcnt(0)" ::: "memory");
        __syncthreads();
        int k0 = kt * 64;
        // ---- QK^T: 3-term hi/lo ----
        f32x4 s[4] = {};
        __builtin_amdgcn_s_setprio(1);
#pragma unroll
        for (int c = 0; c < 4; ++c) {
            if (k0 + c * 16 <= q_hi) {
                f32x4 a = {};
#pragma unroll
                for (int dc = 0; dc < 4; ++dc) {
                    bf16x8 kh8 = *(const bf16x8*)&smem[((c * 4 + dc) * 64 + lane) * 8];
                    bf16x8 kl8 =
                        *(const bf16x8*)&smem[8192 + ((c * 4 + dc) * 64 + lane) * 8];
                    a = __builtin_amdgcn_mfma_f32_16x16x32_bf16(aqh[dc], kh8, a, 0, 0, 0);
                    a = __builtin_amdgcn_mfma_f32_16x16x32_bf16(aql[dc], kh8, a, 0, 0, 0);
                    a = __builtin_amdgcn_mfma_f32_16x16x32_bf16(aqh[dc], kl8, a, 0, 0, 0);
                }
                s[c] = a;
            }
        }
        __builtin_amdgcn_s_setprio(0);
        // ---- mask + running max (log2 units) ----
        float tmax[4] = {-1e30f, -1e30f, -1e30f, -1e30f};
#pragma unroll
        for (int c = 0; c < 4; ++c) {
            bool active = (k0 + c * 16 <= q_hi);
            bool edge = (k0 + c * 16 + 15 >= q0);
#pragma unroll
            for (int r = 0; r < 4; ++r) {
                float sv = active ? s[c][r] : -1e30f;
                if (active && edge) {
                    int key = k0 + c * 16 + lr, qr = q0 + lc * 4 + r;
                    if (key > qr) sv = -1e30f;
                }
                s[c][r] = sv;
                tmax[r] = fmaxf(tmax[r], sv);
            }
        }
#pragma unroll
        for (int off = 1; off < 16; off <<= 1)
#pragma unroll
            for (int r = 0; r < 4; ++r)
                tmax[r] = fmaxf(tmax[r], __shfl_xor(tmax[r], off));
        float alpha[4], psum[4] = {0.f, 0.f, 0.f, 0.f};
        bool anyup = false;
#pragma unroll
        for (int r = 0; r < 4; ++r) {
            float mn = fmaxf(m[r], tmax[r]);
            alpha[r] = exp2f(m[r] - mn);
            anyup |= (mn > m[r]);
            m[r] = mn;
        }
        // P rounded to bf16; l accumulates the SAME rounded values so the
        // coherent truncation error cancels in O = (P_bf.V)/l.
        u16 pbf[4][4];
#pragma unroll
        for (int c = 0; c < 4; ++c)
#pragma unroll
            for (int r = 0; r < 4; ++r) {
                float pv = exp2f(s[c][r] - m[r]);
                u16 pbits = f2bf(pv);
                pbf[c][r] = pbits;
                psum[r] += bf2f(pbits);
            }
#pragma unroll
        for (int off = 1; off < 16; off <<= 1)
#pragma unroll
            for (int r = 0; r < 4; ++r) psum[r] += __shfl_xor(psum[r], off);
#pragma unroll
        for (int r = 0; r < 4; ++r) l[r] = l[r] * alpha[r] + psum[r];
        if (__any(anyup)) {
#pragma unroll
            for (int n = 0; n < 8; ++n)
#pragma unroll
                for (int r = 0; r < 4; ++r) oacc[n][r] *= alpha[r];
        }
        // ---- PV per 32-key chunk: pack P -> pb, 2-term (vh + vl) ----
#pragma unroll
        for (int kc = 0; kc < 2; ++kc) {
            if (k0 + kc * 32 <= q_hi) {
#pragma unroll
                for (int c2 = 0; c2 < 2; ++c2)
#pragma unroll
                    for (int r = 0; r < 4; ++r)
                        pb[(lc * 4 + r) * 40 + c2 * 16 + lr] = pbf[kc * 2 + c2][r];
                asm volatile("s_waitcnt lgkmcnt(0)" ::: "memory");
                bf16x8 pa = *(const bf16x8*)&pb[lr * 40 + lc * 8];
                __builtin_amdgcn_s_setprio(1);
#pragma unroll
                for (int n = 0; n < 8; ++n) {
                    bf16x8 vh8 =
                        *(const bf16x8*)&smem[16384 + ((kc * 8 + n) * 64 + lane) * 8];
                    bf16x8 vl8 =
                        *(const bf16x8*)&smem[24576 + ((kc * 8 + n) * 64 + lane) * 8];
                    oacc[n] = __builtin_amdgcn_mfma_f32_16x16x32_bf16(pa, vh8, oacc[n], 0, 0, 0);
                    oacc[n] = __builtin_amdgcn_mfma_f32_16x16x32_bf16(pa, vl8, oacc[n], 0, 0, 0);
                }
                __builtin_amdgcn_s_setprio(0);
            }
        }
        __syncthreads();  // all compute done -> safe to restage
    }
    // ---- write O in-place over this block's Q region ----
#pragma unroll
    for (int n = 0; n < 8; ++n) {
        int col = h * HD + n * 16 + lr;
#pragma unroll
        for (int r = 0; r < 4; ++r)
            qf[(size_t)(q0 + lc * 4 + r) * HID + col] = oacc[n][r] / l[r];
    }
}

// ---------------- Hadamard head-mix (register FWHT) + int4 requant ----------
__global__ __launch_bounds__(256) void k_hadq(const float* __restrict__ attn,
        s8* __restrict__ a2, float* __restrict__ sa) {
    int t = blockIdx.x, tid = threadIdx.x;
    int w = tid >> 6, lane = tid & 63;
    int d = (w & 1) * 64 + lane;
    int half = w >> 1;
    __shared__ float rowb[HID];
    const float* ar = attn + (size_t)t * HID;
#pragma unroll
    for (int i = 0; i < 4; ++i)
        *(f32x4*)&rowb[i * 1024 + tid * 4] = *(const f32x4*)(ar + i * 1024 + tid * 4);
    __syncthreads();
    float u[16];
#pragma unroll
    for (int i = 0; i < 16; ++i) u[i] = rowb[(half * 16 + i) * 128 + d];
#pragma unroll
    for (int s = 1; s < 16; s <<= 1)
#pragma unroll
        for (int i = 0; i < 16; ++i)
            if (!(i & s)) {
                float a = u[i], b = u[i | s];
                u[i] = a + b;
                u[i | s] = a - b;
            }
#pragma unroll
    for (int i = 0; i < 16; ++i) rowb[(half * 16 + i) * 128 + d] = u[i];
    __syncthreads();
    float y[16], amax = 0.f;
#pragma unroll
    for (int i = 0; i < 16; ++i) {
        float o = rowb[((half ^ 1) * 16 + i) * 128 + d];
        float yv = half ? (o - u[i]) : (u[i] + o);
        yv *= 0.17677669529663687f;
        y[i] = yv;
        amax = fmaxf(amax, fabsf(yv));
    }
#pragma unroll
    for (int off = 32; off >= 1; off >>= 1)
        amax = fmaxf(amax, __shfl_xor(amax, off));
    __shared__ float red[4];
    if ((tid & 63) == 0) red[tid >> 6] = amax;
    __syncthreads();
    amax = fmaxf(fmaxf(red[0], red[1]), fmaxf(red[2], red[3]));
    float s = fmaxf(amax / 7.f, 1e-8f);
    if (tid == 0) sa[t] = s;
    s8* o2 = a2 + (size_t)t * HID;
#pragma unroll
    for (int i = 0; i < 16; ++i) {
        float q = rintf(y[i] / s);
        q = fminf(fmaxf(q, -8.f), 7.f);
        o2[(half * 16 + i) * 128 + d] = (s8)(int)q;
    }
}

extern "C" void kernel_launch(void* const* d_in, const int* in_sizes, int n_in,
                              void* d_out, int out_size, void* d_ws, size_t ws_size,
                              hipStream_t stream) {
    const int* positions = (const int*)d_in[0];
    const float* hidden = (const float*)d_in[1];
    const int* wq = (const int*)d_in[2];
    const float* wq_s = (const float*)d_in[3];
    const int* wk = (const int*)d_in[4];
    const float* wk_s = (const float*)d_in[5];
    const int* wv = (const int*)d_in[6];
    const float* wv_s = (const float*)d_in[7];
    const int* wo = (const int*)d_in[8];
    const float* wo_s = (const float*)d_in[9];

    char* ws = (char*)d_ws;
    float* s_x = (float*)(ws);
    float* s_a = (float*)(ws + 8192);
    float* ctab = (float*)(ws + 16384);
    float* stab = (float*)(ws + 16384 + 524288);
    char* base1 = ws + 16384 + 1048576;
    s8* a8 = (s8*)base1;                                 // 8.39 MB
    float* q_f = (float*)(base1 + 8388608);              // 33.55 MB
    float* k_f = (float*)(base1 + 8388608 + 33554432);   // 8.39 MB
    char* X = base1 + 8388608 + 33554432 + 8388608;      // 16.78 MB
    char* W2 = X + 16777216;                             // 8.39 MB
    s8* wq8 = (s8*)X;                 // dead after Q-GEMM
    u16* khf = (u16*)(X);             // written by ropek (after Q-GEMM)
    u16* klf = (u16*)(X + 4194304);
    u16* vhf = (u16*)(X + 8388608);   // written by KV-GEMM (after Q-GEMM)
    u16* vlf = (u16*)(X + 12582912);
    s8* wk8 = (s8*)W2;
    s8* wv8 = (s8*)(W2 + 4194304);
    s8* wo8 = (s8*)X;                 // packed after attn

    k_trig<<<T_SEQ * 64 / 256, 256, 0, stream>>>(positions, ctab, stab);
    k_w8x3<<<6144, 256, 0, stream>>>(wq, wk, wv, wq8, wk8, wv8);
    k_quant<<<T_SEQ, 256, 0, stream>>>(hidden, a8, s_x);
    k_gemm8<<<dim3(16, 32), 256, 0, stream>>>(a8, wq8, s_x, wq_s, q_f,
                                              T_SEQ, HID, KDIM);
    k_gemmkv<<<dim3(16, 16), 256, 0, stream>>>(a8, wk8, wv8, s_x, wk_s, wv_s,
                                               k_f, vhf, vlf);
    k_ropek<<<T_SEQ, 256, 0, stream>>>(k_f, ctab, stab, khf, klf);
    k_attn<<<512, 512, 0, stream>>>(q_f, khf, klf, vhf, vlf, ctab, stab);
    k_w8<<<4096, 256, 0, stream>>>(wo, wo8);
    k_hadq<<<T_SEQ, 256, 0, stream>>>(q_f, a8, s_a);
    k_gemm8<<<dim3(16, 32), 256, 0, stream>>>(a8, wo8, s_a, wo_s,
                                              (float*)d_out, T_SEQ, HID, KDIM);
}

// Round 7
// 329.801 us; speedup vs baseline: 4.4291x; 1.0763x over previous
//
#include <hip/hip_runtime.h>

#define T_SEQ 2048
#define HID 4096
#define NH 32
#define NKV 8
#define HD 128
#define KDIM 4096

typedef unsigned short u16;
typedef signed char s8;
typedef __attribute__((ext_vector_type(4))) float f32x4;
typedef __attribute__((ext_vector_type(4))) int i32x4;
typedef __attribute__((ext_vector_type(8))) short s16x8;
typedef __attribute__((ext_vector_type(4))) short s16x4;
typedef __attribute__((ext_vector_type(8))) __bf16 bf16x8;
typedef __attribute__((ext_vector_type(8))) _Float16 f16x8;

static __device__ __forceinline__ u16 f2bf(float f) {
    __bf16 b = (__bf16)f;
    return __builtin_bit_cast(unsigned short, b);
}
static __device__ __forceinline__ float bf2f(u16 b) {
    unsigned u = ((unsigned)b) << 16;
    return __builtin_bit_cast(float, u);
}
static __device__ __forceinline__ __bf16 bfbits(u16 b) {
    return __builtin_bit_cast(__bf16, b);
}
static __device__ __forceinline__ u16 f2h(float f) {
    _Float16 h = (_Float16)f;
    return __builtin_bit_cast(unsigned short, h);
}

typedef __attribute__((address_space(1))) const void gas_t;
typedef __attribute__((address_space(3))) void las_t;
static __device__ __forceinline__ void gll16(const void* g, void* l) {
    __builtin_amdgcn_global_load_lds((gas_t*)g, (las_t*)l, 16, 0, 0);
}

// ---- fused pre-pass: trig tables | activation int4-quant | QKV weight pack --
__global__ __launch_bounds__(256) void k_pre(const int* __restrict__ pos,
        const float* __restrict__ x, const int* __restrict__ wq,
        const int* __restrict__ wk, const int* __restrict__ wv,
        float* __restrict__ ctab, float* __restrict__ stab,
        s8* __restrict__ a8, float* __restrict__ srow,
        s8* __restrict__ q8, s8* __restrict__ k8, s8* __restrict__ v8) {
    int b = blockIdx.x, tid = threadIdx.x;
    if (b < 512) {
        int idx = b * 256 + tid;
        int t = idx >> 6, d = idx & 63;
        float p = (float)pos[t];
        float inv = (float)pow(10000.0, -(double)d / 64.0);
        float ang = p * inv;
        double dsn, dcs;
        sincos((double)ang, &dsn, &dcs);
        ctab[idx] = (float)dcs;
        stab[idx] = (float)dsn;
    } else if (b < 512 + 2048) {
        int row = b - 512;
        const float* xr = x + (size_t)row * HID;
        f32x4 v[4];
        float amax = 0.f;
#pragma unroll
        for (int i = 0; i < 4; ++i) {
            v[i] = *(const f32x4*)(xr + i * 1024 + tid * 4);
#pragma unroll
            for (int j = 0; j < 4; ++j) amax = fmaxf(amax, fabsf(v[i][j]));
        }
#pragma unroll
        for (int off = 32; off >= 1; off >>= 1)
            amax = fmaxf(amax, __shfl_xor(amax, off));
        __shared__ float red[4];
        if ((tid & 63) == 0) red[tid >> 6] = amax;
        __syncthreads();
        amax = fmaxf(fmaxf(red[0], red[1]), fmaxf(red[2], red[3]));
        float s = fmaxf(amax / 7.f, 1e-8f);
        if (tid == 0) srow[row] = s;
        int* qr = (int*)(a8 + (size_t)row * HID);
#pragma unroll
        for (int i = 0; i < 4; ++i) {
            int p = 0;
#pragma unroll
            for (int j = 0; j < 4; ++j) {
                float q = rintf(v[i][j] / s);
                q = fminf(fmaxf(q, -8.f), 7.f);
                p |= ((int)q & 0xff) << (8 * j);
            }
            qr[i * 256 + tid] = p;
        }
    } else {
        size_t i = ((size_t)(b - 2560) * 256 + tid) * 16;
        const int* src; s8* dst; size_t off;
        if (i < 16777216) { src = wq; dst = q8; off = i; }
        else if (i < 20971520) { src = wk; dst = k8; off = i - 16777216; }
        else { src = wv; dst = v8; off = i - 20971520; }
        i32x4 o;
#pragma unroll
        for (int j = 0; j < 4; ++j) {
            i32x4 v = *(const i32x4*)(src + off + j * 4);
            o[j] = (v[0] & 0xff) | ((v[1] & 0xff) << 8) |
                   ((v[2] & 0xff) << 16) | (v[3] << 24);
        }
        *(i32x4*)(dst + off) = o;
    }
}

// ---------------- weight pack int32 -> int8 (wo), 16B/thread ----------------
__global__ __launch_bounds__(256) void k_w8(const int* __restrict__ w,
                                            s8* __restrict__ w8) {
    size_t i = ((size_t)blockIdx.x * 256 + threadIdx.x) * 16;
    i32x4 o;
#pragma unroll
    for (int j = 0; j < 4; ++j) {
        i32x4 v = *(const i32x4*)(w + i + j * 4);
        o[j] = (v[0] & 0xff) | ((v[1] & 0xff) << 8) | ((v[2] & 0xff) << 16) |
               (v[3] << 24);
    }
    *(i32x4*)(w8 + i) = o;
}

// ---------------- int8 MFMA GEMM (exact), f32 row-major out -----------------
__global__ __launch_bounds__(256) void k_gemm8(const s8* __restrict__ A,
        const s8* __restrict__ W, const float* __restrict__ sRow,
        const float* __restrict__ sCol, float* __restrict__ outp,
        int M, int N, int K) {
    __shared__ __align__(16) s8 sA[16384], sB[16384];  // [128][128], XOR-swizzled
    int tid = threadIdx.x;
    int brow = blockIdx.x * 128, bcol = blockIdx.y * 128;
    int wid = tid >> 6, lane = tid & 63;
    int wr = (wid >> 1) * 64, wc = (wid & 1) * 64;
    int lr = lane & 15, lc = lane >> 4;
    i32x4 acc[4][4] = {};
    for (int k0 = 0; k0 < K; k0 += 128) {
        __syncthreads();
#pragma unroll
        for (int j = 0; j < 4; ++j) {
            int base = wid * 1024 + j * 4096;
            int o = base + lane * 16;
            int r = o >> 7;
            int c = (o & 127) ^ ((r & 7) << 4);
            gll16(A + (size_t)(brow + r) * K + (k0 + c), (char*)sA + base);
            gll16(W + (size_t)(bcol + r) * K + (k0 + c), (char*)sB + base);
        }
        asm volatile("s_waitcnt vmcnt(0)" ::: "memory");
        __syncthreads();
#pragma unroll
        for (int kk = 0; kk < 2; ++kk) {
            i32x4 af[4], bf[4];
#pragma unroll
            for (int m = 0; m < 4; ++m) {
                int r = wr + m * 16 + lr;
                int sl = ((kk * 4 + lc) ^ (r & 7)) * 16;
                af[m] = *(const i32x4*)&sA[r * 128 + sl];
            }
#pragma unroll
            for (int n = 0; n < 4; ++n) {
                int r = wc + n * 16 + lr;
                int sl = ((kk * 4 + lc) ^ (r & 7)) * 16;
                bf[n] = *(const i32x4*)&sB[r * 128 + sl];
            }
#pragma unroll
            for (int m = 0; m < 4; ++m)
#pragma unroll
                for (int n = 0; n < 4; ++n)
                    acc[m][n] = __builtin_amdgcn_mfma_i32_16x16x64_i8(
                        af[m], bf[n], acc[m][n], 0, 0, 0);
        }
    }
#pragma unroll
    for (int m = 0; m < 4; ++m) {
        int row0 = brow + wr + m * 16 + lc * 4;
#pragma unroll
        for (int n = 0; n < 4; ++n) {
            int col = bcol + wc + n * 16 + lr;
            float scl = sCol[col];
#pragma unroll
            for (int r = 0; r < 4; ++r)
                outp[(size_t)(row0 + r) * N + col] =
                    (float)acc[m][n][r] * sRow[row0 + r] * scl;
        }
    }
}

// ---------------- fused K+V int8 GEMM: by<8 -> K (f32), by>=8 -> V (f16 frag)
__global__ __launch_bounds__(256) void k_gemmkv(const s8* __restrict__ A,
        const s8* __restrict__ Wk, const s8* __restrict__ Wv,
        const float* __restrict__ sRow, const float* __restrict__ sColK,
        const float* __restrict__ sColV, float* __restrict__ kout,
        u16* __restrict__ voutf) {
    __shared__ __align__(16) s8 sA[16384], sB[16384];
    int tid = threadIdx.x;
    int by = blockIdx.y;
    int isV = by >> 3;
    const s8* W = isV ? Wv : Wk;
    int brow = blockIdx.x * 128, bcol = (by & 7) * 128;
    const int K = KDIM, N = NKV * HD;
    int wid = tid >> 6, lane = tid & 63;
    int wr = (wid >> 1) * 64, wc = (wid & 1) * 64;
    int lr = lane & 15, lc = lane >> 4;
    i32x4 acc[4][4] = {};
    for (int k0 = 0; k0 < K; k0 += 128) {
        __syncthreads();
#pragma unroll
        for (int j = 0; j < 4; ++j) {
            int base = wid * 1024 + j * 4096;
            int o = base + lane * 16;
            int r = o >> 7;
            int c = (o & 127) ^ ((r & 7) << 4);
            gll16(A + (size_t)(brow + r) * K + (k0 + c), (char*)sA + base);
            gll16(W + (size_t)(bcol + r) * K + (k0 + c), (char*)sB + base);
        }
        asm volatile("s_waitcnt vmcnt(0)" ::: "memory");
        __syncthreads();
#pragma unroll
        for (int kk = 0; kk < 2; ++kk) {
            i32x4 af[4], bf[4];
#pragma unroll
            for (int m = 0; m < 4; ++m) {
                int r = wr + m * 16 + lr;
                int sl = ((kk * 4 + lc) ^ (r & 7)) * 16;
                af[m] = *(const i32x4*)&sA[r * 128 + sl];
            }
#pragma unroll
            for (int n = 0; n < 4; ++n) {
                int r = wc + n * 16 + lr;
                int sl = ((kk * 4 + lc) ^ (r & 7)) * 16;
                bf[n] = *(const i32x4*)&sB[r * 128 + sl];
            }
#pragma unroll
            for (int m = 0; m < 4; ++m)
#pragma unroll
                for (int n = 0; n < 4; ++n)
                    acc[m][n] = __builtin_amdgcn_mfma_i32_16x16x64_i8(
                        af[m], bf[n], acc[m][n], 0, 0, 0);
        }
    }
#pragma unroll
    for (int m = 0; m < 4; ++m) {
        int row0 = brow + wr + m * 16 + lc * 4;
#pragma unroll
        for (int n = 0; n < 4; ++n) {
            int col = bcol + wc + n * 16 + lr;
            if (!isV) {
                float scl = sColK[col];
#pragma unroll
                for (int r = 0; r < 4; ++r)
                    kout[(size_t)(row0 + r) * N + col] =
                        (float)acc[m][n][r] * sRow[row0 + r] * scl;
            } else {
                float scl = sColV[col];
                int kvh = col >> 7, d = col & 127;
                int nn = d >> 4, lrv = d & 15;
                int kt = row0 >> 6, rem = row0 & 63;
                int kc = rem >> 5, lcv = (rem & 31) >> 3, j0 = rem & 7;
                size_t base =
                    ((((size_t)(kvh * 32 + kt) * 2 + kc) * 8 + nn) * 64 +
                     lcv * 16 + lrv) * 8 + j0;
                s16x4 hh;
#pragma unroll
                for (int r = 0; r < 4; ++r) {
                    float val = (float)acc[m][n][r] * sRow[row0 + r] * scl;
                    hh[r] = (short)f2h(val);
                }
                *(s16x4*)(voutf + base) = hh;
            }
        }
    }
}

// ---------------- RoPE on K only -> fragment-ordered hi/lo bf16 -------------
__global__ __launch_bounds__(256) void k_ropek(const float* __restrict__ kf,
        const float* __restrict__ ctab, const float* __restrict__ stab,
        u16* __restrict__ khf, u16* __restrict__ klf) {
    int t = blockIdx.x, tid = threadIdx.x;
    int kt = t >> 6, rem = t & 63, cblk = rem >> 4, lrk = rem & 15;
    for (int idx = tid; idx < NKV * 64; idx += 256) {
        int kh = idx >> 6, d = idx & 63;
        float cs = ctab[t * 64 + d], sn = stab[t * 64 + d];
        size_t base = (size_t)t * (NKV * HD) + kh * HD;
        float x1 = kf[base + d], x2 = kf[base + d + 64];
        float r1 = x1 * cs - x2 * sn;
        float r2 = x2 * cs + x1 * sn;
        size_t tb = (((size_t)(kh * 32 + kt) * 4 + cblk) * 4) * 512;
#pragma unroll
        for (int half = 0; half < 2; ++half) {
            int x = d + half * 64;
            float rv = half ? r2 : r1;
            int dcx = x >> 5, lcx = (x & 31) >> 3, jx = x & 7;
            size_t ii = tb + (size_t)dcx * 512 + (lcx * 16 + lrk) * 8 + jx;
            u16 hb = f2bf(rv);
            khf[ii] = hb;
            klf[ii] = f2bf(rv - bf2f(hb));
        }
    }
}

// ---------------- GQA causal flash attention ---------------------------------
// 512 blocks (pair swizzle: bid & bid+256 same CU -> bx & 15-bx), 8 waves.
// KVBLK=64. K single-buffered, V double-buffered; stage of t+1 issued after the
// K-consumed barrier and hidden under softmax+PV. QK 3-term bf16 hi/lo;
// PV 1-term fp16 with l-consistent fp16-rounded P.
__global__ __launch_bounds__(512, 4) void k_attn(float* __restrict__ qf,
        const u16* __restrict__ khf, const u16* __restrict__ klf,
        const u16* __restrict__ vf,
        const float* __restrict__ ctab, const float* __restrict__ stab) {
    int bid = blockIdx.x;
    int lo = bid & 255, hi = bid >> 8;
    int h = lo & 31;
    int bx = hi ? 15 - (lo >> 5) : (lo >> 5);
    int kvh = h >> 2;
    int tid = threadIdx.x, wid = tid >> 6, lane = tid & 63;
    int lr = lane & 15, lc = lane >> 4;
    int q0 = bx * 128 + wid * 16, q_hi = q0 + 15;
    // u16 layout: Kh[0,8192) Kl[8192,16384) V0[16384,24576) V1[24576,32768)
    //             pbuf at 32768 (8 waves x 16x40)
    __shared__ __align__(16) u16 smem[37888];
    u16* pb = smem + 32768 + wid * 640;
    const float SCL = 0.12751744f;  // 1/sqrt(128) * log2(e)
    size_t kvbase = (size_t)kvh * 32 * 8192;
    auto stageK = [&](int kt) {
        const char* gk = (const char*)(khf + kvbase + (size_t)kt * 8192);
        const char* gl = (const char*)(klf + kvbase + (size_t)kt * 8192);
#pragma unroll
        for (int j = 0; j < 4; ++j) {
            int c = wid * 4 + j;
            int sel = c >> 4;
            int inner = (c & 15) * 1024;
            gll16((sel ? gl : gk) + inner + lane * 16,
                  (char*)smem + sel * 16384 + inner);
        }
    };
    auto stageV = [&](int kt, int buf) {
        const char* gv = (const char*)(vf + kvbase + (size_t)kt * 8192);
#pragma unroll
        for (int j = 0; j < 2; ++j) {
            int c = wid * 2 + j;
            gll16(gv + c * 1024 + lane * 16,
                  (char*)smem + 32768 + buf * 16384 + c * 1024);
        }
    };
    // ---- Q load + fused RoPE + scale + hi/lo split ----
    bf16x8 aqh[4], aql[4];
    {
        const float* qrow = qf + (size_t)(q0 + lr) * HID + h * HD;
        const float* ct = ctab + (size_t)(q0 + lr) * 64 + lc * 8;
        const float* st = stab + (size_t)(q0 + lr) * 64 + lc * 8;
        float qv[4][8];
#pragma unroll
        for (int dc = 0; dc < 4; ++dc) {
            f32x4 a = *(const f32x4*)(qrow + dc * 32 + lc * 8);
            f32x4 b = *(const f32x4*)(qrow + dc * 32 + lc * 8 + 4);
#pragma unroll
            for (int j = 0; j < 4; ++j) { qv[dc][j] = a[j]; qv[dc][j + 4] = b[j]; }
        }
        float cs[2][8], sn[2][8];
#pragma unroll
        for (int hf = 0; hf < 2; ++hf) {
            f32x4 c0 = *(const f32x4*)(ct + hf * 32);
            f32x4 c1 = *(const f32x4*)(ct + hf * 32 + 4);
            f32x4 s0 = *(const f32x4*)(st + hf * 32);
            f32x4 s1 = *(const f32x4*)(st + hf * 32 + 4);
#pragma unroll
            for (int j = 0; j < 4; ++j) {
                cs[hf][j] = c0[j]; cs[hf][j + 4] = c1[j];
                sn[hf][j] = s0[j]; sn[hf][j + 4] = s1[j];
            }
        }
#pragma unroll
        for (int dc0 = 0; dc0 < 2; ++dc0)
#pragma unroll
            for (int j = 0; j < 8; ++j) {
                float c = cs[dc0][j], s2 = sn[dc0][j];
                float x1 = qv[dc0][j], x2 = qv[dc0 + 2][j];
                qv[dc0][j] = x1 * c - x2 * s2;
                qv[dc0 + 2][j] = x2 * c + x1 * s2;
            }
#pragma unroll
        for (int dc = 0; dc < 4; ++dc)
#pragma unroll
            for (int j = 0; j < 8; ++j) {
                float v = qv[dc][j] * SCL;
                u16 hb = f2bf(v);
                aqh[dc][j] = bfbits(hb);
                aql[dc][j] = bfbits(f2bf(v - bf2f(hb)));
            }
    }
    f32x4 oacc[8] = {};
    float m[4], l[4];
#pragma unroll
    for (int r = 0; r < 4; ++r) { m[r] = -1e30f; l[r] = 0.f; }
    int NT = 2 * bx + 2;
    stageK(0);
    stageV(0, 0);
    asm volatile("s_waitcnt vmcnt(0)" ::: "memory");
    __syncthreads();
    int cur = 0;
    for (int kt = 0; kt < NT; ++kt) {
        int k0 = kt * 64;
        // ---- QK^T: 3-term hi/lo ----
        f32x4 s[4] = {};
        __builtin_amdgcn_s_setprio(1);
#pragma unroll
        for (int c = 0; c < 4; ++c) {
            if (k0 + c * 16 <= q_hi) {
                f32x4 a = {};
#pragma unroll
                for (int dc = 0; dc < 4; ++dc) {
                    bf16x8 kh8 = *(const bf16x8*)&smem[((c * 4 + dc) * 64 + lane) * 8];
                    bf16x8 kl8 =
                        *(const bf16x8*)&smem[8192 + ((c * 4 + dc) * 64 + lane) * 8];
                    a = __builtin_amdgcn_mfma_f32_16x16x32_bf16(aqh[dc], kh8, a, 0, 0, 0);
                    a = __builtin_amdgcn_mfma_f32_16x16x32_bf16(aql[dc], kh8, a, 0, 0, 0);
                    a = __builtin_amdgcn_mfma_f32_16x16x32_bf16(aqh[dc], kl8, a, 0, 0, 0);
                }
                s[c] = a;
            }
        }
        __builtin_amdgcn_s_setprio(0);
        __syncthreads();  // K consumed by all waves -> safe to restage K
        if (kt + 1 < NT) {
            stageK(kt + 1);
            stageV(kt + 1, cur ^ 1);  // PV below reads buffer `cur`
        }
        // ---- mask + running max (log2 units) ----
        float tmax[4] = {-1e30f, -1e30f, -1e30f, -1e30f};
#pragma unroll
        for (int c = 0; c < 4; ++c) {
            bool active = (k0 + c * 16 <= q_hi);
            bool edge = (k0 + c * 16 + 15 >= q0);
#pragma unroll
            for (int r = 0; r < 4; ++r) {
                float sv = active ? s[c][r] : -1e30f;
                if (active && edge) {
                    int key = k0 + c * 16 + lr, qr = q0 + lc * 4 + r;
                    if (key > qr) sv = -1e30f;
                }
                s[c][r] = sv;
                tmax[r] = fmaxf(tmax[r], sv);
            }
        }
#pragma unroll
        for (int off = 1; off < 16; off <<= 1)
#pragma unroll
            for (int r = 0; r < 4; ++r)
                tmax[r] = fmaxf(tmax[r], __shfl_xor(tmax[r], off));
        float alpha[4], psum[4] = {0.f, 0.f, 0.f, 0.f};
        bool anyup = false;
#pragma unroll
        for (int r = 0; r < 4; ++r) {
            float mn = fmaxf(m[r], tmax[r]);
            alpha[r] = exp2f(m[r] - mn);
            anyup |= (mn > m[r]);
            m[r] = mn;
        }
        // P rounded to fp16; l accumulates the SAME rounded values so the
        // coherent truncation error cancels in O = (P_f16.V)/l.
        u16 pbf[4][4];
#pragma unroll
        for (int c = 0; c < 4; ++c)
#pragma unroll
            for (int r = 0; r < 4; ++r) {
                float pv = exp2f(s[c][r] - m[r]);
                _Float16 ph = (_Float16)pv;
                pbf[c][r] = __builtin_bit_cast(unsigned short, ph);
                psum[r] += (float)ph;
            }
#pragma unroll
        for (int off = 1; off < 16; off <<= 1)
#pragma unroll
            for (int r = 0; r < 4; ++r) psum[r] += __shfl_xor(psum[r], off);
#pragma unroll
        for (int r = 0; r < 4; ++r) l[r] = l[r] * alpha[r] + psum[r];
        if (__any(anyup)) {
#pragma unroll
            for (int n = 0; n < 8; ++n)
#pragma unroll
                for (int r = 0; r < 4; ++r) oacc[n][r] *= alpha[r];
        }
        // ---- PV per 32-key chunk: pack P(fp16) -> pb, 1-term fp16 MFMA ----
#pragma unroll
        for (int kc = 0; kc < 2; ++kc) {
            if (k0 + kc * 32 <= q_hi) {
#pragma unroll
                for (int c2 = 0; c2 < 2; ++c2)
#pragma unroll
                    for (int r = 0; r < 4; ++r)
                        pb[(lc * 4 + r) * 40 + c2 * 16 + lr] = pbf[kc * 2 + c2][r];
                asm volatile("s_waitcnt lgkmcnt(0)" ::: "memory");
                f16x8 pa = *(const f16x8*)&pb[lr * 40 + lc * 8];
                __builtin_amdgcn_s_setprio(1);
#pragma unroll
                for (int n = 0; n < 8; ++n) {
                    f16x8 v8 = *(const f16x8*)&smem[16384 + cur * 8192 +
                                                    ((kc * 8 + n) * 64 + lane) * 8];
                    oacc[n] = __builtin_amdgcn_mfma_f32_16x16x32_f16(pa, v8, oacc[n], 0, 0, 0);
                }
                __builtin_amdgcn_s_setprio(0);
            }
        }
        asm volatile("s_waitcnt vmcnt(0)" ::: "memory");  // own stage loads done
        __syncthreads();  // all waves' stages visible; V[cur] consumed
        cur ^= 1;
    }
    // ---- write O in-place over this block's Q region ----
#pragma unroll
    for (int n = 0; n < 8; ++n) {
        int col = h * HD + n * 16 + lr;
#pragma unroll
        for (int r = 0; r < 4; ++r)
            qf[(size_t)(q0 + lc * 4 + r) * HID + col] = oacc[n][r] / l[r];
    }
}

// ---------------- Hadamard head-mix (register FWHT) + int4 requant ----------
__global__ __launch_bounds__(256) void k_hadq(const float* __restrict__ attn,
        s8* __restrict__ a2, float* __restrict__ sa) {
    int t = blockIdx.x, tid = threadIdx.x;
    int w = tid >> 6, lane = tid & 63;
    int d = (w & 1) * 64 + lane;
    int half = w >> 1;
    __shared__ float rowb[HID];
    const float* ar = attn + (size_t)t * HID;
#pragma unroll
    for (int i = 0; i < 4; ++i)
        *(f32x4*)&rowb[i * 1024 + tid * 4] = *(const f32x4*)(ar + i * 1024 + tid * 4);
    __syncthreads();
    float u[16];
#pragma unroll
    for (int i = 0; i < 16; ++i) u[i] = rowb[(half * 16 + i) * 128 + d];
#pragma unroll
    for (int s = 1; s < 16; s <<= 1)
#pragma unroll
        for (int i = 0; i < 16; ++i)
            if (!(i & s)) {
                float a = u[i], b = u[i | s];
                u[i] = a + b;
                u[i | s] = a - b;
            }
#pragma unroll
    for (int i = 0; i < 16; ++i) rowb[(half * 16 + i) * 128 + d] = u[i];
    __syncthreads();
    float y[16], amax = 0.f;
#pragma unroll
    for (int i = 0; i < 16; ++i) {
        float o = rowb[((half ^ 1) * 16 + i) * 128 + d];
        float yv = half ? (o - u[i]) : (u[i] + o);
        yv *= 0.17677669529663687f;
        y[i] = yv;
        amax = fmaxf(amax, fabsf(yv));
    }
#pragma unroll
    for (int off = 32; off >= 1; off >>= 1)
        amax = fmaxf(amax, __shfl_xor(amax, off));
    __shared__ float red[4];
    if ((tid & 63) == 0) red[tid >> 6] = amax;
    __syncthreads();
    amax = fmaxf(fmaxf(red[0], red[1]), fmaxf(red[2], red[3]));
    float s = fmaxf(amax / 7.f, 1e-8f);
    if (tid == 0) sa[t] = s;
    s8* o2 = a2 + (size_t)t * HID;
#pragma unroll
    for (int i = 0; i < 16; ++i) {
        float q = rintf(y[i] / s);
        q = fminf(fmaxf(q, -8.f), 7.f);
        o2[(half * 16 + i) * 128 + d] = (s8)(int)q;
    }
}

extern "C" void kernel_launch(void* const* d_in, const int* in_sizes, int n_in,
                              void* d_out, int out_size, void* d_ws, size_t ws_size,
                              hipStream_t stream) {
    const int* positions = (const int*)d_in[0];
    const float* hidden = (const float*)d_in[1];
    const int* wq = (const int*)d_in[2];
    const float* wq_s = (const float*)d_in[3];
    const int* wk = (const int*)d_in[4];
    const float* wk_s = (const float*)d_in[5];
    const int* wv = (const int*)d_in[6];
    const float* wv_s = (const float*)d_in[7];
    const int* wo = (const int*)d_in[8];
    const float* wo_s = (const float*)d_in[9];

    char* ws = (char*)d_ws;
    float* s_x = (float*)(ws);
    float* s_a = (float*)(ws + 8192);
    float* ctab = (float*)(ws + 16384);
    float* stab = (float*)(ws + 16384 + 524288);
    char* base1 = ws + 16384 + 1048576;
    s8* a8 = (s8*)base1;                                 // 8.39 MB
    float* q_f = (float*)(base1 + 8388608);              // 33.55 MB
    float* k_f = (float*)(base1 + 8388608 + 33554432);   // 8.39 MB
    char* X = base1 + 8388608 + 33554432 + 8388608;      // 16.78 MB
    char* W2 = X + 16777216;                             // 8.39 MB
    s8* wq8 = (s8*)X;                 // dead after Q-GEMM
    u16* khf = (u16*)(X);             // written by ropek (after Q-GEMM)
    u16* klf = (u16*)(X + 4194304);
    u16* vf = (u16*)(X + 8388608);    // fp16 frag V^T, written by KV-GEMM
    s8* wk8 = (s8*)W2;
    s8* wv8 = (s8*)(W2 + 4194304);
    s8* wo8 = (s8*)X;                 // packed after attn

    k_pre<<<8704, 256, 0, stream>>>(positions, hidden, wq, wk, wv, ctab, stab,
                                    a8, s_x, wq8, wk8, wv8);
    k_gemm8<<<dim3(16, 32), 256, 0, stream>>>(a8, wq8, s_x, wq_s, q_f,
                                              T_SEQ, HID, KDIM);
    k_gemmkv<<<dim3(16, 16), 256, 0, stream>>>(a8, wk8, wv8, s_x, wk_s, wv_s,
                                               k_f, vf);
    k_ropek<<<T_SEQ, 256, 0, stream>>>(k_f, ctab, stab, khf, klf);
    k_attn<<<512, 512, 0, stream>>>(q_f, khf, klf, vf, ctab, stab);
    k_w8<<<4096, 256, 0, stream>>>(wo, wo8);
    k_hadq<<<T_SEQ, 256, 0, stream>>>(q_f, a8, s_a);
    k_gemm8<<<dim3(16, 32), 256, 0, stream>>>(a8, wo8, s_a, wo_s,
                                              (float*)d_out, T_SEQ, HID, KDIM);
}

// Round 8
// 299.132 us; speedup vs baseline: 4.8832x; 1.1025x over previous
//
#include <hip/hip_runtime.h>

#define T_SEQ 2048
#define HID 4096
#define NH 32
#define NKV 8
#define HD 128
#define KDIM 4096

typedef unsigned short u16;
typedef signed char s8;
typedef __attribute__((ext_vector_type(4))) float f32x4;
typedef __attribute__((ext_vector_type(4))) int i32x4;
typedef __attribute__((ext_vector_type(8))) short s16x8;
typedef __attribute__((ext_vector_type(4))) short s16x4;
typedef __attribute__((ext_vector_type(8))) __bf16 bf16x8;
typedef __attribute__((ext_vector_type(8))) _Float16 f16x8;

static __device__ __forceinline__ u16 f2bf(float f) {
    __bf16 b = (__bf16)f;
    return __builtin_bit_cast(unsigned short, b);
}
static __device__ __forceinline__ float bf2f(u16 b) {
    unsigned u = ((unsigned)b) << 16;
    return __builtin_bit_cast(float, u);
}
static __device__ __forceinline__ __bf16 bfbits(u16 b) {
    return __builtin_bit_cast(__bf16, b);
}
static __device__ __forceinline__ u16 f2h(float f) {
    _Float16 h = (_Float16)f;
    return __builtin_bit_cast(unsigned short, h);
}

typedef __attribute__((address_space(1))) const void gas_t;
typedef __attribute__((address_space(3))) void las_t;
static __device__ __forceinline__ void gll16(const void* g, void* l) {
    __builtin_amdgcn_global_load_lds((gas_t*)g, (las_t*)l, 16, 0, 0);
}

// ---- fused pre-pass: trig tables | activation int4-quant | QKV weight pack --
__global__ __launch_bounds__(256) void k_pre(const int* __restrict__ pos,
        const float* __restrict__ x, const int* __restrict__ wq,
        const int* __restrict__ wk, const int* __restrict__ wv,
        float* __restrict__ ctab, float* __restrict__ stab,
        s8* __restrict__ a8, float* __restrict__ srow,
        s8* __restrict__ q8, s8* __restrict__ k8, s8* __restrict__ v8) {
    int b = blockIdx.x, tid = threadIdx.x;
    if (b < 512) {
        int idx = b * 256 + tid;
        int t = idx >> 6, d = idx & 63;
        float p = (float)pos[t];
        float inv = (float)pow(10000.0, -(double)d / 64.0);
        float ang = p * inv;
        double dsn, dcs;
        sincos((double)ang, &dsn, &dcs);
        ctab[idx] = (float)dcs;
        stab[idx] = (float)dsn;
    } else if (b < 512 + 2048) {
        int row = b - 512;
        const float* xr = x + (size_t)row * HID;
        f32x4 v[4];
        float amax = 0.f;
#pragma unroll
        for (int i = 0; i < 4; ++i) {
            v[i] = *(const f32x4*)(xr + i * 1024 + tid * 4);
#pragma unroll
            for (int j = 0; j < 4; ++j) amax = fmaxf(amax, fabsf(v[i][j]));
        }
#pragma unroll
        for (int off = 32; off >= 1; off >>= 1)
            amax = fmaxf(amax, __shfl_xor(amax, off));
        __shared__ float red[4];
        if ((tid & 63) == 0) red[tid >> 6] = amax;
        __syncthreads();
        amax = fmaxf(fmaxf(red[0], red[1]), fmaxf(red[2], red[3]));
        float s = fmaxf(amax / 7.f, 1e-8f);
        if (tid == 0) srow[row] = s;
        int* qr = (int*)(a8 + (size_t)row * HID);
#pragma unroll
        for (int i = 0; i < 4; ++i) {
            int p = 0;
#pragma unroll
            for (int j = 0; j < 4; ++j) {
                float q = rintf(v[i][j] / s);
                q = fminf(fmaxf(q, -8.f), 7.f);
                p |= ((int)q & 0xff) << (8 * j);
            }
            qr[i * 256 + tid] = p;
        }
    } else {
        size_t i = ((size_t)(b - 2560) * 256 + tid) * 16;
        const int* src; s8* dst; size_t off;
        if (i < 16777216) { src = wq; dst = q8; off = i; }
        else if (i < 20971520) { src = wk; dst = k8; off = i - 16777216; }
        else { src = wv; dst = v8; off = i - 20971520; }
        i32x4 o;
#pragma unroll
        for (int j = 0; j < 4; ++j) {
            i32x4 v = *(const i32x4*)(src + off + j * 4);
            o[j] = (v[0] & 0xff) | ((v[1] & 0xff) << 8) |
                   ((v[2] & 0xff) << 16) | (v[3] << 24);
        }
        *(i32x4*)(dst + off) = o;
    }
}

// ---------------- weight pack int32 -> int8 (wo), 16B/thread ----------------
__global__ __launch_bounds__(256) void k_w8(const int* __restrict__ w,
                                            s8* __restrict__ w8) {
    size_t i = ((size_t)blockIdx.x * 256 + threadIdx.x) * 16;
    i32x4 o;
#pragma unroll
    for (int j = 0; j < 4; ++j) {
        i32x4 v = *(const i32x4*)(w + i + j * 4);
        o[j] = (v[0] & 0xff) | ((v[1] & 0xff) << 8) | ((v[2] & 0xff) << 16) |
               (v[3] << 24);
    }
    *(i32x4*)(w8 + i) = o;
}

// ---------------- int8 MFMA GEMM (exact), f32 row-major out -----------------
__global__ __launch_bounds__(256) void k_gemm8(const s8* __restrict__ A,
        const s8* __restrict__ W, const float* __restrict__ sRow,
        const float* __restrict__ sCol, float* __restrict__ outp,
        int M, int N, int K) {
    __shared__ __align__(16) s8 sA[16384], sB[16384];  // [128][128], XOR-swizzled
    int tid = threadIdx.x;
    int brow = blockIdx.x * 128, bcol = blockIdx.y * 128;
    int wid = tid >> 6, lane = tid & 63;
    int wr = (wid >> 1) * 64, wc = (wid & 1) * 64;
    int lr = lane & 15, lc = lane >> 4;
    i32x4 acc[4][4] = {};
    for (int k0 = 0; k0 < K; k0 += 128) {
        __syncthreads();
#pragma unroll
        for (int j = 0; j < 4; ++j) {
            int base = wid * 1024 + j * 4096;
            int o = base + lane * 16;
            int r = o >> 7;
            int c = (o & 127) ^ ((r & 7) << 4);
            gll16(A + (size_t)(brow + r) * K + (k0 + c), (char*)sA + base);
            gll16(W + (size_t)(bcol + r) * K + (k0 + c), (char*)sB + base);
        }
        asm volatile("s_waitcnt vmcnt(0)" ::: "memory");
        __syncthreads();
#pragma unroll
        for (int kk = 0; kk < 2; ++kk) {
            i32x4 af[4], bf[4];
#pragma unroll
            for (int m = 0; m < 4; ++m) {
                int r = wr + m * 16 + lr;
                int sl = ((kk * 4 + lc) ^ (r & 7)) * 16;
                af[m] = *(const i32x4*)&sA[r * 128 + sl];
            }
#pragma unroll
            for (int n = 0; n < 4; ++n) {
                int r = wc + n * 16 + lr;
                int sl = ((kk * 4 + lc) ^ (r & 7)) * 16;
                bf[n] = *(const i32x4*)&sB[r * 128 + sl];
            }
#pragma unroll
            for (int m = 0; m < 4; ++m)
#pragma unroll
                for (int n = 0; n < 4; ++n)
                    acc[m][n] = __builtin_amdgcn_mfma_i32_16x16x64_i8(
                        af[m], bf[n], acc[m][n], 0, 0, 0);
        }
    }
#pragma unroll
    for (int m = 0; m < 4; ++m) {
        int row0 = brow + wr + m * 16 + lc * 4;
#pragma unroll
        for (int n = 0; n < 4; ++n) {
            int col = bcol + wc + n * 16 + lr;
            float scl = sCol[col];
#pragma unroll
            for (int r = 0; r < 4; ++r)
                outp[(size_t)(row0 + r) * N + col] =
                    (float)acc[m][n][r] * sRow[row0 + r] * scl;
        }
    }
}

// ---------------- fused K+V int8 GEMM: by<8 -> K (f32), by>=8 -> V (f16 frag)
__global__ __launch_bounds__(256) void k_gemmkv(const s8* __restrict__ A,
        const s8* __restrict__ Wk, const s8* __restrict__ Wv,
        const float* __restrict__ sRow, const float* __restrict__ sColK,
        const float* __restrict__ sColV, float* __restrict__ kout,
        u16* __restrict__ voutf) {
    __shared__ __align__(16) s8 sA[16384], sB[16384];
    int tid = threadIdx.x;
    int by = blockIdx.y;
    int isV = by >> 3;
    const s8* W = isV ? Wv : Wk;
    int brow = blockIdx.x * 128, bcol = (by & 7) * 128;
    const int K = KDIM, N = NKV * HD;
    int wid = tid >> 6, lane = tid & 63;
    int wr = (wid >> 1) * 64, wc = (wid & 1) * 64;
    int lr = lane & 15, lc = lane >> 4;
    i32x4 acc[4][4] = {};
    for (int k0 = 0; k0 < K; k0 += 128) {
        __syncthreads();
#pragma unroll
        for (int j = 0; j < 4; ++j) {
            int base = wid * 1024 + j * 4096;
            int o = base + lane * 16;
            int r = o >> 7;
            int c = (o & 127) ^ ((r & 7) << 4);
            gll16(A + (size_t)(brow + r) * K + (k0 + c), (char*)sA + base);
            gll16(W + (size_t)(bcol + r) * K + (k0 + c), (char*)sB + base);
        }
        asm volatile("s_waitcnt vmcnt(0)" ::: "memory");
        __syncthreads();
#pragma unroll
        for (int kk = 0; kk < 2; ++kk) {
            i32x4 af[4], bf[4];
#pragma unroll
            for (int m = 0; m < 4; ++m) {
                int r = wr + m * 16 + lr;
                int sl = ((kk * 4 + lc) ^ (r & 7)) * 16;
                af[m] = *(const i32x4*)&sA[r * 128 + sl];
            }
#pragma unroll
            for (int n = 0; n < 4; ++n) {
                int r = wc + n * 16 + lr;
                int sl = ((kk * 4 + lc) ^ (r & 7)) * 16;
                bf[n] = *(const i32x4*)&sB[r * 128 + sl];
            }
#pragma unroll
            for (int m = 0; m < 4; ++m)
#pragma unroll
                for (int n = 0; n < 4; ++n)
                    acc[m][n] = __builtin_amdgcn_mfma_i32_16x16x64_i8(
                        af[m], bf[n], acc[m][n], 0, 0, 0);
        }
    }
#pragma unroll
    for (int m = 0; m < 4; ++m) {
        int row0 = brow + wr + m * 16 + lc * 4;
#pragma unroll
        for (int n = 0; n < 4; ++n) {
            int col = bcol + wc + n * 16 + lr;
            if (!isV) {
                float scl = sColK[col];
#pragma unroll
                for (int r = 0; r < 4; ++r)
                    kout[(size_t)(row0 + r) * N + col] =
                        (float)acc[m][n][r] * sRow[row0 + r] * scl;
            } else {
                float scl = sColV[col];
                int kvh = col >> 7, d = col & 127;
                int nn = d >> 4, lrv = d & 15;
                int kt = row0 >> 6, rem = row0 & 63;
                int kc = rem >> 5, lcv = (rem & 31) >> 3, j0 = rem & 7;
                size_t base =
                    ((((size_t)(kvh * 32 + kt) * 2 + kc) * 8 + nn) * 64 +
                     lcv * 16 + lrv) * 8 + j0;
                s16x4 hh;
#pragma unroll
                for (int r = 0; r < 4; ++r) {
                    float val = (float)acc[m][n][r] * sRow[row0 + r] * scl;
                    hh[r] = (short)f2h(val);
                }
                *(s16x4*)(voutf + base) = hh;
            }
        }
    }
}

// ---------------- RoPE on K only -> fragment-ordered hi/lo bf16 -------------
__global__ __launch_bounds__(256) void k_ropek(const float* __restrict__ kf,
        const float* __restrict__ ctab, const float* __restrict__ stab,
        u16* __restrict__ khf, u16* __restrict__ klf) {
    int t = blockIdx.x, tid = threadIdx.x;
    int kt = t >> 6, rem = t & 63, cblk = rem >> 4, lrk = rem & 15;
    for (int idx = tid; idx < NKV * 64; idx += 256) {
        int kh = idx >> 6, d = idx & 63;
        float cs = ctab[t * 64 + d], sn = stab[t * 64 + d];
        size_t base = (size_t)t * (NKV * HD) + kh * HD;
        float x1 = kf[base + d], x2 = kf[base + d + 64];
        float r1 = x1 * cs - x2 * sn;
        float r2 = x2 * cs + x1 * sn;
        size_t tb = (((size_t)(kh * 32 + kt) * 4 + cblk) * 4) * 512;
#pragma unroll
        for (int half = 0; half < 2; ++half) {
            int x = d + half * 64;
            float rv = half ? r2 : r1;
            int dcx = x >> 5, lcx = (x & 31) >> 3, jx = x & 7;
            size_t ii = tb + (size_t)dcx * 512 + (lcx * 16 + lrk) * 8 + jx;
            u16 hb = f2bf(rv);
            khf[ii] = hb;
            klf[ii] = f2bf(rv - bf2f(hb));
        }
    }
}

// ---------------- GQA causal flash attention ---------------------------------
// 512 blocks (pair swizzle), 8 waves. KVBLK=64; K single-buf, V double-buf.
// SWAPPED QK^T: S = mfma(K,Q) -> acc rows=keys, cols=q. Each lane owns one
// q-row (q=q0+lr) x 16 keys -> in-lane softmax + 2 shuffles. Defer-max (THR=8
// log2-units). PV 1-term fp16 with l-consistent fp16 P.
__global__ __launch_bounds__(512, 4) void k_attn(float* __restrict__ qf,
        const u16* __restrict__ khf, const u16* __restrict__ klf,
        const u16* __restrict__ vf,
        const float* __restrict__ ctab, const float* __restrict__ stab) {
    int bid = blockIdx.x;
    int lo = bid & 255, hi = bid >> 8;
    int h = lo & 31;
    int bx = hi ? 15 - (lo >> 5) : (lo >> 5);
    int kvh = h >> 2;
    int tid = threadIdx.x, wid = tid >> 6, lane = tid & 63;
    int lr = lane & 15, lc = lane >> 4;
    int q0 = bx * 128 + wid * 16, q_hi = q0 + 15;
    __shared__ __align__(16) u16 smem[37888];
    u16* pb = smem + 32768 + wid * 640;  // per-wave [16][40]
    const float SCL = 0.12751744f;       // 1/sqrt(128) * log2(e)
    size_t kvbase = (size_t)kvh * 32 * 8192;
    auto stageK = [&](int kt) {
        const char* gk = (const char*)(khf + kvbase + (size_t)kt * 8192);
        const char* gl = (const char*)(klf + kvbase + (size_t)kt * 8192);
#pragma unroll
        for (int j = 0; j < 4; ++j) {
            int c = wid * 4 + j;
            int sel = c >> 4;
            int inner = (c & 15) * 1024;
            gll16((sel ? gl : gk) + inner + lane * 16,
                  (char*)smem + sel * 16384 + inner);
        }
    };
    auto stageV = [&](int kt, int buf) {
        const char* gv = (const char*)(vf + kvbase + (size_t)kt * 8192);
#pragma unroll
        for (int j = 0; j < 2; ++j) {
            int c = wid * 2 + j;
            gll16(gv + c * 1024 + lane * 16,
                  (char*)smem + 32768 + buf * 16384 + c * 1024);
        }
    };
    // ---- Q load + fused RoPE + scale + hi/lo split ----
    bf16x8 aqh[4], aql[4];
    {
        const float* qrow = qf + (size_t)(q0 + lr) * HID + h * HD;
        const float* ct = ctab + (size_t)(q0 + lr) * 64 + lc * 8;
        const float* st = stab + (size_t)(q0 + lr) * 64 + lc * 8;
        float qv[4][8];
#pragma unroll
        for (int dc = 0; dc < 4; ++dc) {
            f32x4 a = *(const f32x4*)(qrow + dc * 32 + lc * 8);
            f32x4 b = *(const f32x4*)(qrow + dc * 32 + lc * 8 + 4);
#pragma unroll
            for (int j = 0; j < 4; ++j) { qv[dc][j] = a[j]; qv[dc][j + 4] = b[j]; }
        }
        float cs[2][8], sn[2][8];
#pragma unroll
        for (int hf = 0; hf < 2; ++hf) {
            f32x4 c0 = *(const f32x4*)(ct + hf * 32);
            f32x4 c1 = *(const f32x4*)(ct + hf * 32 + 4);
            f32x4 s0 = *(const f32x4*)(st + hf * 32);
            f32x4 s1 = *(const f32x4*)(st + hf * 32 + 4);
#pragma unroll
            for (int j = 0; j < 4; ++j) {
                cs[hf][j] = c0[j]; cs[hf][j + 4] = c1[j];
                sn[hf][j] = s0[j]; sn[hf][j + 4] = s1[j];
            }
        }
#pragma unroll
        for (int dc0 = 0; dc0 < 2; ++dc0)
#pragma unroll
            for (int j = 0; j < 8; ++j) {
                float c = cs[dc0][j], s2 = sn[dc0][j];
                float x1 = qv[dc0][j], x2 = qv[dc0 + 2][j];
                qv[dc0][j] = x1 * c - x2 * s2;
                qv[dc0 + 2][j] = x2 * c + x1 * s2;
            }
#pragma unroll
        for (int dc = 0; dc < 4; ++dc)
#pragma unroll
            for (int j = 0; j < 8; ++j) {
                float v = qv[dc][j] * SCL;
                u16 hb = f2bf(v);
                aqh[dc][j] = bfbits(hb);
                aql[dc][j] = bfbits(f2bf(v - bf2f(hb)));
            }
    }
    f32x4 oacc[8] = {};
    float m = -1e30f, l = 0.f;  // per-lane: q-row q0+lr
    int NT = 2 * bx + 2;
    stageK(0);
    stageV(0, 0);
    asm volatile("s_waitcnt vmcnt(0)" ::: "memory");
    __syncthreads();
    int cur = 0;
    for (int kt = 0; kt < NT; ++kt) {
        int k0 = kt * 64;
        // ---- QK^T swapped: s[c] rows=keys(lc*4+r), cols=q(lr) ----
        f32x4 s[4] = {};
        __builtin_amdgcn_s_setprio(1);
#pragma unroll
        for (int c = 0; c < 4; ++c) {
            if (k0 + c * 16 <= q_hi) {
                f32x4 a = {};
#pragma unroll
                for (int dc = 0; dc < 4; ++dc) {
                    bf16x8 kh8 = *(const bf16x8*)&smem[((c * 4 + dc) * 64 + lane) * 8];
                    bf16x8 kl8 =
                        *(const bf16x8*)&smem[8192 + ((c * 4 + dc) * 64 + lane) * 8];
                    a = __builtin_amdgcn_mfma_f32_16x16x32_bf16(kh8, aqh[dc], a, 0, 0, 0);
                    a = __builtin_amdgcn_mfma_f32_16x16x32_bf16(kh8, aql[dc], a, 0, 0, 0);
                    a = __builtin_amdgcn_mfma_f32_16x16x32_bf16(kl8, aqh[dc], a, 0, 0, 0);
                }
                s[c] = a;
            }
        }
        __builtin_amdgcn_s_setprio(0);
        __syncthreads();  // K consumed by all waves -> safe to restage K
        if (kt + 1 < NT) {
            stageK(kt + 1);
            stageV(kt + 1, cur ^ 1);
        }
        // ---- mask + in-lane row max ----
        int q = q0 + lr;
        float tmax = -1e30f;
#pragma unroll
        for (int c = 0; c < 4; ++c) {
            bool active = (k0 + c * 16 <= q_hi);
            bool edge = (k0 + c * 16 + 15 >= q0);
#pragma unroll
            for (int r = 0; r < 4; ++r) {
                float sv = active ? s[c][r] : -1e30f;
                if (active && edge) {
                    int key = k0 + c * 16 + lc * 4 + r;
                    if (key > q) sv = -1e30f;
                }
                s[c][r] = sv;
                tmax = fmaxf(tmax, sv);
            }
        }
        tmax = fmaxf(tmax, __shfl_xor(tmax, 16));
        tmax = fmaxf(tmax, __shfl_xor(tmax, 32));
        // ---- defer-max: rescale only when the row max grew by > 8 ----
        if (__any(tmax > m + 8.0f)) {
            float mn = fmaxf(m, tmax);
            float alpha = exp2f(m - mn);
            m = mn;
            l *= alpha;
            float a0 = __shfl(alpha, lc * 4 + 0);
            float a1 = __shfl(alpha, lc * 4 + 1);
            float a2 = __shfl(alpha, lc * 4 + 2);
            float a3 = __shfl(alpha, lc * 4 + 3);
#pragma unroll
            for (int n = 0; n < 8; ++n) {
                oacc[n][0] *= a0; oacc[n][1] *= a1;
                oacc[n][2] *= a2; oacc[n][3] *= a3;
            }
        }
        // ---- P = exp2(s-m) in fp16 (l-consistent), in-lane psum ----
        u16 pbf[4][4];
        float psum = 0.f;
#pragma unroll
        for (int c = 0; c < 4; ++c)
#pragma unroll
            for (int r = 0; r < 4; ++r) {
                float pv = exp2f(s[c][r] - m);
                _Float16 ph = (_Float16)pv;
                pbf[c][r] = __builtin_bit_cast(unsigned short, ph);
                psum += (float)ph;
            }
        psum += __shfl_xor(psum, 16);
        psum += __shfl_xor(psum, 32);
        l += psum;
        // ---- PV per 32-key chunk: 2x ds_write_b64 pack, 1-term fp16 MFMA ----
#pragma unroll
        for (int kc = 0; kc < 2; ++kc) {
            if (k0 + kc * 32 <= q_hi) {
                s16x4 w0, w1;
#pragma unroll
                for (int r = 0; r < 4; ++r) {
                    w0[r] = (short)pbf[kc * 2][r];
                    w1[r] = (short)pbf[kc * 2 + 1][r];
                }
                *(s16x4*)&pb[lr * 40 + lc * 4] = w0;
                *(s16x4*)&pb[lr * 40 + 16 + lc * 4] = w1;
                asm volatile("s_waitcnt lgkmcnt(0)" ::: "memory");
                f16x8 pa = *(const f16x8*)&pb[lr * 40 + lc * 8];
                __builtin_amdgcn_s_setprio(1);
#pragma unroll
                for (int n = 0; n < 8; ++n) {
                    f16x8 v8 = *(const f16x8*)&smem[16384 + cur * 8192 +
                                                    ((kc * 8 + n) * 64 + lane) * 8];
                    oacc[n] = __builtin_amdgcn_mfma_f32_16x16x32_f16(pa, v8, oacc[n], 0, 0, 0);
                }
                __builtin_amdgcn_s_setprio(0);
            }
        }
        asm volatile("s_waitcnt vmcnt(0)" ::: "memory");
        __syncthreads();
        cur ^= 1;
    }
    // ---- write O in-place; l lives at lane (lr = q-row), redistribute ----
    float l0 = __shfl(l, lc * 4 + 0);
    float l1 = __shfl(l, lc * 4 + 1);
    float l2 = __shfl(l, lc * 4 + 2);
    float l3 = __shfl(l, lc * 4 + 3);
#pragma unroll
    for (int n = 0; n < 8; ++n) {
        int col = h * HD + n * 16 + lr;
        qf[(size_t)(q0 + lc * 4 + 0) * HID + col] = oacc[n][0] / l0;
        qf[(size_t)(q0 + lc * 4 + 1) * HID + col] = oacc[n][1] / l1;
        qf[(size_t)(q0 + lc * 4 + 2) * HID + col] = oacc[n][2] / l2;
        qf[(size_t)(q0 + lc * 4 + 3) * HID + col] = oacc[n][3] / l3;
    }
}

// ---------------- Hadamard head-mix (register FWHT) + int4 requant ----------
__global__ __launch_bounds__(256) void k_hadq(const float* __restrict__ attn,
        s8* __restrict__ a2, float* __restrict__ sa) {
    int t = blockIdx.x, tid = threadIdx.x;
    int w = tid >> 6, lane = tid & 63;
    int d = (w & 1) * 64 + lane;
    int half = w >> 1;
    __shared__ float rowb[HID];
    const float* ar = attn + (size_t)t * HID;
#pragma unroll
    for (int i = 0; i < 4; ++i)
        *(f32x4*)&rowb[i * 1024 + tid * 4] = *(const f32x4*)(ar + i * 1024 + tid * 4);
    __syncthreads();
    float u[16];
#pragma unroll
    for (int i = 0; i < 16; ++i) u[i] = rowb[(half * 16 + i) * 128 + d];
#pragma unroll
    for (int s = 1; s < 16; s <<= 1)
#pragma unroll
        for (int i = 0; i < 16; ++i)
            if (!(i & s)) {
                float a = u[i], b = u[i | s];
                u[i] = a + b;
                u[i | s] = a - b;
            }
#pragma unroll
    for (int i = 0; i < 16; ++i) rowb[(half * 16 + i) * 128 + d] = u[i];
    __syncthreads();
    float y[16], amax = 0.f;
#pragma unroll
    for (int i = 0; i < 16; ++i) {
        float o = rowb[((half ^ 1) * 16 + i) * 128 + d];
        float yv = half ? (o - u[i]) : (u[i] + o);
        yv *= 0.17677669529663687f;
        y[i] = yv;
        amax = fmaxf(amax, fabsf(yv));
    }
#pragma unroll
    for (int off = 32; off >= 1; off >>= 1)
        amax = fmaxf(amax, __shfl_xor(amax, off));
    __shared__ float red[4];
    if ((tid & 63) == 0) red[tid >> 6] = amax;
    __syncthreads();
    amax = fmaxf(fmaxf(red[0], red[1]), fmaxf(red[2], red[3]));
    float s = fmaxf(amax / 7.f, 1e-8f);
    if (tid == 0) sa[t] = s;
    s8* o2 = a2 + (size_t)t * HID;
#pragma unroll
    for (int i = 0; i < 16; ++i) {
        float q = rintf(y[i] / s);
        q = fminf(fmaxf(q, -8.f), 7.f);
        o2[(half * 16 + i) * 128 + d] = (s8)(int)q;
    }
}

extern "C" void kernel_launch(void* const* d_in, const int* in_sizes, int n_in,
                              void* d_out, int out_size, void* d_ws, size_t ws_size,
                              hipStream_t stream) {
    const int* positions = (const int*)d_in[0];
    const float* hidden = (const float*)d_in[1];
    const int* wq = (const int*)d_in[2];
    const float* wq_s = (const float*)d_in[3];
    const int* wk = (const int*)d_in[4];
    const float* wk_s = (const float*)d_in[5];
    const int* wv = (const int*)d_in[6];
    const float* wv_s = (const float*)d_in[7];
    const int* wo = (const int*)d_in[8];
    const float* wo_s = (const float*)d_in[9];

    char* ws = (char*)d_ws;
    float* s_x = (float*)(ws);
    float* s_a = (float*)(ws + 8192);
    float* ctab = (float*)(ws + 16384);
    float* stab = (float*)(ws + 16384 + 524288);
    char* base1 = ws + 16384 + 1048576;
    s8* a8 = (s8*)base1;                                 // 8.39 MB
    float* q_f = (float*)(base1 + 8388608);              // 33.55 MB
    float* k_f = (float*)(base1 + 8388608 + 33554432);   // 8.39 MB
    char* X = base1 + 8388608 + 33554432 + 8388608;      // 16.78 MB
    char* W2 = X + 16777216;                             // 8.39 MB
    s8* wq8 = (s8*)X;                 // dead after Q-GEMM
    u16* khf = (u16*)(X);             // written by ropek (after Q-GEMM)
    u16* klf = (u16*)(X + 4194304);
    u16* vf = (u16*)(X + 8388608);    // fp16 frag V^T, written by KV-GEMM
    s8* wk8 = (s8*)W2;
    s8* wv8 = (s8*)(W2 + 4194304);
    s8* wo8 = (s8*)X;                 // packed after attn

    k_pre<<<8704, 256, 0, stream>>>(positions, hidden, wq, wk, wv, ctab, stab,
                                    a8, s_x, wq8, wk8, wv8);
    k_gemm8<<<dim3(16, 32), 256, 0, stream>>>(a8, wq8, s_x, wq_s, q_f,
                                              T_SEQ, HID, KDIM);
    k_gemmkv<<<dim3(16, 16), 256, 0, stream>>>(a8, wk8, wv8, s_x, wk_s, wv_s,
                                               k_f, vf);
    k_ropek<<<T_SEQ, 256, 0, stream>>>(k_f, ctab, stab, khf, klf);
    k_attn<<<512, 512, 0, stream>>>(q_f, khf, klf, vf, ctab, stab);
    k_w8<<<4096, 256, 0, stream>>>(wo, wo8);
    k_hadq<<<T_SEQ, 256, 0, stream>>>(q_f, a8, s_a);
    k_gemm8<<<dim3(16, 32), 256, 0, stream>>>(a8, wo8, s_a, wo_s,
                                              (float*)d_out, T_SEQ, HID, KDIM);
}

// Round 9
// 276.915 us; speedup vs baseline: 5.2749x; 1.0802x over previous
//
#include <hip/hip_runtime.h>

#define T_SEQ 2048
#define HID 4096
#define NH 32
#define NKV 8
#define HD 128
#define KDIM 4096

typedef unsigned short u16;
typedef signed char s8;
typedef __attribute__((ext_vector_type(4))) float f32x4;
typedef __attribute__((ext_vector_type(4))) int i32x4;
typedef __attribute__((ext_vector_type(8))) short s16x8;
typedef __attribute__((ext_vector_type(4))) short s16x4;
typedef __attribute__((ext_vector_type(8))) __bf16 bf16x8;
typedef __attribute__((ext_vector_type(8))) _Float16 f16x8;

static __device__ __forceinline__ u16 f2bf(float f) {
    __bf16 b = (__bf16)f;
    return __builtin_bit_cast(unsigned short, b);
}
static __device__ __forceinline__ float bf2f(u16 b) {
    unsigned u = ((unsigned)b) << 16;
    return __builtin_bit_cast(float, u);
}
static __device__ __forceinline__ __bf16 bfbits(u16 b) {
    return __builtin_bit_cast(__bf16, b);
}
static __device__ __forceinline__ u16 f2h(float f) {
    _Float16 h = (_Float16)f;
    return __builtin_bit_cast(unsigned short, h);
}

typedef __attribute__((address_space(1))) const void gas_t;
typedef __attribute__((address_space(3))) void las_t;
static __device__ __forceinline__ void gll16(const void* g, void* l) {
    __builtin_amdgcn_global_load_lds((gas_t*)g, (las_t*)l, 16, 0, 0);
}

// ---- fused pre-pass: trig tables | activation int4-quant | QKV weight pack --
__global__ __launch_bounds__(256) void k_pre(const int* __restrict__ pos,
        const float* __restrict__ x, const int* __restrict__ wq,
        const int* __restrict__ wk, const int* __restrict__ wv,
        float* __restrict__ ctab, float* __restrict__ stab,
        s8* __restrict__ a8, float* __restrict__ srow,
        s8* __restrict__ q8, s8* __restrict__ k8, s8* __restrict__ v8) {
    int b = blockIdx.x, tid = threadIdx.x;
    if (b < 512) {
        int idx = b * 256 + tid;
        int t = idx >> 6, d = idx & 63;
        float p = (float)pos[t];
        float inv = (float)pow(10000.0, -(double)d / 64.0);
        float ang = p * inv;
        double dsn, dcs;
        sincos((double)ang, &dsn, &dcs);
        ctab[idx] = (float)dcs;
        stab[idx] = (float)dsn;
    } else if (b < 512 + 2048) {
        int row = b - 512;
        const float* xr = x + (size_t)row * HID;
        f32x4 v[4];
        float amax = 0.f;
#pragma unroll
        for (int i = 0; i < 4; ++i) {
            v[i] = *(const f32x4*)(xr + i * 1024 + tid * 4);
#pragma unroll
            for (int j = 0; j < 4; ++j) amax = fmaxf(amax, fabsf(v[i][j]));
        }
#pragma unroll
        for (int off = 32; off >= 1; off >>= 1)
            amax = fmaxf(amax, __shfl_xor(amax, off));
        __shared__ float red[4];
        if ((tid & 63) == 0) red[tid >> 6] = amax;
        __syncthreads();
        amax = fmaxf(fmaxf(red[0], red[1]), fmaxf(red[2], red[3]));
        float s = fmaxf(amax / 7.f, 1e-8f);
        if (tid == 0) srow[row] = s;
        int* qr = (int*)(a8 + (size_t)row * HID);
#pragma unroll
        for (int i = 0; i < 4; ++i) {
            int p = 0;
#pragma unroll
            for (int j = 0; j < 4; ++j) {
                float q = rintf(v[i][j] / s);
                q = fminf(fmaxf(q, -8.f), 7.f);
                p |= ((int)q & 0xff) << (8 * j);
            }
            qr[i * 256 + tid] = p;
        }
    } else {
        size_t i = ((size_t)(b - 2560) * 256 + tid) * 16;
        const int* src; s8* dst; size_t off;
        if (i < 16777216) { src = wq; dst = q8; off = i; }
        else if (i < 20971520) { src = wk; dst = k8; off = i - 16777216; }
        else { src = wv; dst = v8; off = i - 20971520; }
        i32x4 o;
#pragma unroll
        for (int j = 0; j < 4; ++j) {
            i32x4 v = *(const i32x4*)(src + off + j * 4);
            o[j] = (v[0] & 0xff) | ((v[1] & 0xff) << 8) |
                   ((v[2] & 0xff) << 16) | (v[3] << 24);
        }
        *(i32x4*)(dst + off) = o;
    }
}

// ---------------- unified QKV int8 GEMM, double-buffered T3 pipeline --------
// by in [0,32): Q -> q_f (f32 row-major, N=4096)
// by in [32,40): K -> k_f (f32 row-major, N=1024)
// by in [40,48): V -> vf (fragment-ordered fp16 V^T)
__global__ __launch_bounds__(256) void k_qkv(const s8* __restrict__ A,
        const s8* __restrict__ Wq, const s8* __restrict__ Wk,
        const s8* __restrict__ Wv, const float* __restrict__ sRow,
        const float* __restrict__ sq, const float* __restrict__ sk,
        const float* __restrict__ sv, float* __restrict__ qout,
        float* __restrict__ kout, u16* __restrict__ voutf) {
    __shared__ __align__(16) s8 sA[2][16384], sB[2][16384];
    int tid = threadIdx.x;
    int by = blockIdx.y;
    int mode = by < 32 ? 0 : (by < 40 ? 1 : 2);
    const s8* W = mode == 0 ? Wq : (mode == 1 ? Wk : Wv);
    const float* sCol = mode == 0 ? sq : (mode == 1 ? sk : sv);
    int bcolb = mode == 0 ? by : (mode == 1 ? by - 32 : by - 40);
    int brow = blockIdx.x * 128, bcol = bcolb * 128;
    const int K = KDIM;
    int wid = tid >> 6, lane = tid & 63;
    int wr = (wid >> 1) * 64, wc = (wid & 1) * 64;
    int lr = lane & 15, lc = lane >> 4;
    i32x4 acc[4][4] = {};
    auto stage = [&](int buf, int k0) {
#pragma unroll
        for (int j = 0; j < 4; ++j) {
            int base = wid * 1024 + j * 4096;
            int o = base + lane * 16;
            int r = o >> 7;
            int c = (o & 127) ^ ((r & 7) << 4);
            gll16(A + (size_t)(brow + r) * K + (k0 + c), (char*)sA[buf] + base);
            gll16(W + (size_t)(bcol + r) * K + (k0 + c), (char*)sB[buf] + base);
        }
    };
    stage(0, 0);
    asm volatile("s_waitcnt vmcnt(0)" ::: "memory");
    __syncthreads();
    int cur = 0;
    for (int k0 = 0; k0 < K; k0 += 128) {
        if (k0 + 128 < K) stage(cur ^ 1, k0 + 128);
#pragma unroll
        for (int kk = 0; kk < 2; ++kk) {
            i32x4 af[4], bf[4];
#pragma unroll
            for (int m = 0; m < 4; ++m) {
                int r = wr + m * 16 + lr;
                int sl = ((kk * 4 + lc) ^ (r & 7)) * 16;
                af[m] = *(const i32x4*)&sA[cur][r * 128 + sl];
            }
#pragma unroll
            for (int n = 0; n < 4; ++n) {
                int r = wc + n * 16 + lr;
                int sl = ((kk * 4 + lc) ^ (r & 7)) * 16;
                bf[n] = *(const i32x4*)&sB[cur][r * 128 + sl];
            }
#pragma unroll
            for (int m = 0; m < 4; ++m)
#pragma unroll
                for (int n = 0; n < 4; ++n)
                    acc[m][n] = __builtin_amdgcn_mfma_i32_16x16x64_i8(
                        af[m], bf[n], acc[m][n], 0, 0, 0);
        }
        asm volatile("s_waitcnt vmcnt(0)" ::: "memory");
        __syncthreads();
        cur ^= 1;
    }
#pragma unroll
    for (int m = 0; m < 4; ++m) {
        int row0 = brow + wr + m * 16 + lc * 4;
#pragma unroll
        for (int n = 0; n < 4; ++n) {
            int col = bcol + wc + n * 16 + lr;
            float scl = sCol[col];
            if (mode == 0) {
#pragma unroll
                for (int r = 0; r < 4; ++r)
                    qout[(size_t)(row0 + r) * HID + col] =
                        (float)acc[m][n][r] * sRow[row0 + r] * scl;
            } else if (mode == 1) {
#pragma unroll
                for (int r = 0; r < 4; ++r)
                    kout[(size_t)(row0 + r) * (NKV * HD) + col] =
                        (float)acc[m][n][r] * sRow[row0 + r] * scl;
            } else {
                int kvh = col >> 7, d = col & 127;
                int nn = d >> 4, lrv = d & 15;
                int kt = row0 >> 6, rem = row0 & 63;
                int kc = rem >> 5, lcv = (rem & 31) >> 3, j0 = rem & 7;
                size_t base =
                    ((((size_t)(kvh * 32 + kt) * 2 + kc) * 8 + nn) * 64 +
                     lcv * 16 + lrv) * 8 + j0;
                s16x4 hh;
#pragma unroll
                for (int r = 0; r < 4; ++r) {
                    float val = (float)acc[m][n][r] * sRow[row0 + r] * scl;
                    hh[r] = (short)f2h(val);
                }
                *(s16x4*)(voutf + base) = hh;
            }
        }
    }
}

// ---------------- O-proj int8 GEMM, same double-buffered pipeline -----------
__global__ __launch_bounds__(256) void k_gemm8(const s8* __restrict__ A,
        const s8* __restrict__ W, const float* __restrict__ sRow,
        const float* __restrict__ sCol, float* __restrict__ outp) {
    __shared__ __align__(16) s8 sA[2][16384], sB[2][16384];
    int tid = threadIdx.x;
    int brow = blockIdx.x * 128, bcol = blockIdx.y * 128;
    const int K = KDIM;
    int wid = tid >> 6, lane = tid & 63;
    int wr = (wid >> 1) * 64, wc = (wid & 1) * 64;
    int lr = lane & 15, lc = lane >> 4;
    i32x4 acc[4][4] = {};
    auto stage = [&](int buf, int k0) {
#pragma unroll
        for (int j = 0; j < 4; ++j) {
            int base = wid * 1024 + j * 4096;
            int o = base + lane * 16;
            int r = o >> 7;
            int c = (o & 127) ^ ((r & 7) << 4);
            gll16(A + (size_t)(brow + r) * K + (k0 + c), (char*)sA[buf] + base);
            gll16(W + (size_t)(bcol + r) * K + (k0 + c), (char*)sB[buf] + base);
        }
    };
    stage(0, 0);
    asm volatile("s_waitcnt vmcnt(0)" ::: "memory");
    __syncthreads();
    int cur = 0;
    for (int k0 = 0; k0 < K; k0 += 128) {
        if (k0 + 128 < K) stage(cur ^ 1, k0 + 128);
#pragma unroll
        for (int kk = 0; kk < 2; ++kk) {
            i32x4 af[4], bf[4];
#pragma unroll
            for (int m = 0; m < 4; ++m) {
                int r = wr + m * 16 + lr;
                int sl = ((kk * 4 + lc) ^ (r & 7)) * 16;
                af[m] = *(const i32x4*)&sA[cur][r * 128 + sl];
            }
#pragma unroll
            for (int n = 0; n < 4; ++n) {
                int r = wc + n * 16 + lr;
                int sl = ((kk * 4 + lc) ^ (r & 7)) * 16;
                bf[n] = *(const i32x4*)&sB[cur][r * 128 + sl];
            }
#pragma unroll
            for (int m = 0; m < 4; ++m)
#pragma unroll
                for (int n = 0; n < 4; ++n)
                    acc[m][n] = __builtin_amdgcn_mfma_i32_16x16x64_i8(
                        af[m], bf[n], acc[m][n], 0, 0, 0);
        }
        asm volatile("s_waitcnt vmcnt(0)" ::: "memory");
        __syncthreads();
        cur ^= 1;
    }
#pragma unroll
    for (int m = 0; m < 4; ++m) {
        int row0 = brow + wr + m * 16 + lc * 4;
#pragma unroll
        for (int n = 0; n < 4; ++n) {
            int col = bcol + wc + n * 16 + lr;
            float scl = sCol[col];
#pragma unroll
            for (int r = 0; r < 4; ++r)
                outp[(size_t)(row0 + r) * HID + col] =
                    (float)acc[m][n][r] * sRow[row0 + r] * scl;
        }
    }
}

// ---------------- RoPE on K only -> fragment-ordered hi/lo bf16 -------------
__global__ __launch_bounds__(256) void k_ropek(const float* __restrict__ kf,
        const float* __restrict__ ctab, const float* __restrict__ stab,
        u16* __restrict__ khf, u16* __restrict__ klf) {
    int t = blockIdx.x, tid = threadIdx.x;
    int kt = t >> 6, rem = t & 63, cblk = rem >> 4, lrk = rem & 15;
    for (int idx = tid; idx < NKV * 64; idx += 256) {
        int kh = idx >> 6, d = idx & 63;
        float cs = ctab[t * 64 + d], sn = stab[t * 64 + d];
        size_t base = (size_t)t * (NKV * HD) + kh * HD;
        float x1 = kf[base + d], x2 = kf[base + d + 64];
        float r1 = x1 * cs - x2 * sn;
        float r2 = x2 * cs + x1 * sn;
        size_t tb = (((size_t)(kh * 32 + kt) * 4 + cblk) * 4) * 512;
#pragma unroll
        for (int half = 0; half < 2; ++half) {
            int x = d + half * 64;
            float rv = half ? r2 : r1;
            int dcx = x >> 5, lcx = (x & 31) >> 3, jx = x & 7;
            size_t ii = tb + (size_t)dcx * 512 + (lcx * 16 + lrk) * 8 + jx;
            u16 hb = f2bf(rv);
            khf[ii] = hb;
            klf[ii] = f2bf(rv - bf2f(hb));
        }
    }
}

// ---------------- GQA causal flash attention ---------------------------------
// 512 blocks (pair swizzle), 8 waves. KVBLK=64; K single-buf, V double-buf.
// stageV hoisted to loop top (dbuf target free); stageK after K-consumed
// barrier. Swapped QK^T, in-lane softmax, defer-max, fp16 PV.
__global__ __launch_bounds__(512, 4) void k_attn(float* __restrict__ qf,
        const u16* __restrict__ khf, const u16* __restrict__ klf,
        const u16* __restrict__ vf,
        const float* __restrict__ ctab, const float* __restrict__ stab) {
    int bid = blockIdx.x;
    int lo = bid & 255, hi = bid >> 8;
    int h = lo & 31;
    int bx = hi ? 15 - (lo >> 5) : (lo >> 5);
    int kvh = h >> 2;
    int tid = threadIdx.x, wid = tid >> 6, lane = tid & 63;
    int lr = lane & 15, lc = lane >> 4;
    int q0 = bx * 128 + wid * 16, q_hi = q0 + 15;
    __shared__ __align__(16) u16 smem[37888];
    u16* pb = smem + 32768 + wid * 640;  // per-wave [16][40]
    const float SCL = 0.12751744f;       // 1/sqrt(128) * log2(e)
    size_t kvbase = (size_t)kvh * 32 * 8192;
    auto stageK = [&](int kt) {
        const char* gk = (const char*)(khf + kvbase + (size_t)kt * 8192);
        const char* gl = (const char*)(klf + kvbase + (size_t)kt * 8192);
#pragma unroll
        for (int j = 0; j < 4; ++j) {
            int c = wid * 4 + j;
            int sel = c >> 4;
            int inner = (c & 15) * 1024;
            gll16((sel ? gl : gk) + inner + lane * 16,
                  (char*)smem + sel * 16384 + inner);
        }
    };
    auto stageV = [&](int kt, int buf) {
        const char* gv = (const char*)(vf + kvbase + (size_t)kt * 8192);
#pragma unroll
        for (int j = 0; j < 2; ++j) {
            int c = wid * 2 + j;
            gll16(gv + c * 1024 + lane * 16,
                  (char*)smem + 32768 + buf * 16384 + c * 1024);
        }
    };
    // ---- Q load + fused RoPE + scale + hi/lo split ----
    bf16x8 aqh[4], aql[4];
    {
        const float* qrow = qf + (size_t)(q0 + lr) * HID + h * HD;
        const float* ct = ctab + (size_t)(q0 + lr) * 64 + lc * 8;
        const float* st = stab + (size_t)(q0 + lr) * 64 + lc * 8;
        float qv[4][8];
#pragma unroll
        for (int dc = 0; dc < 4; ++dc) {
            f32x4 a = *(const f32x4*)(qrow + dc * 32 + lc * 8);
            f32x4 b = *(const f32x4*)(qrow + dc * 32 + lc * 8 + 4);
#pragma unroll
            for (int j = 0; j < 4; ++j) { qv[dc][j] = a[j]; qv[dc][j + 4] = b[j]; }
        }
        float cs[2][8], sn[2][8];
#pragma unroll
        for (int hf = 0; hf < 2; ++hf) {
            f32x4 c0 = *(const f32x4*)(ct + hf * 32);
            f32x4 c1 = *(const f32x4*)(ct + hf * 32 + 4);
            f32x4 s0 = *(const f32x4*)(st + hf * 32);
            f32x4 s1 = *(const f32x4*)(st + hf * 32 + 4);
#pragma unroll
            for (int j = 0; j < 4; ++j) {
                cs[hf][j] = c0[j]; cs[hf][j + 4] = c1[j];
                sn[hf][j] = s0[j]; sn[hf][j + 4] = s1[j];
            }
        }
#pragma unroll
        for (int dc0 = 0; dc0 < 2; ++dc0)
#pragma unroll
            for (int j = 0; j < 8; ++j) {
                float c = cs[dc0][j], s2 = sn[dc0][j];
                float x1 = qv[dc0][j], x2 = qv[dc0 + 2][j];
                qv[dc0][j] = x1 * c - x2 * s2;
                qv[dc0 + 2][j] = x2 * c + x1 * s2;
            }
#pragma unroll
        for (int dc = 0; dc < 4; ++dc)
#pragma unroll
            for (int j = 0; j < 8; ++j) {
                float v = qv[dc][j] * SCL;
                u16 hb = f2bf(v);
                aqh[dc][j] = bfbits(hb);
                aql[dc][j] = bfbits(f2bf(v - bf2f(hb)));
            }
    }
    f32x4 oacc[8] = {};
    float m = -1e30f, l = 0.f;  // per-lane: q-row q0+lr
    int NT = 2 * bx + 2;
    stageK(0);
    stageV(0, 0);
    asm volatile("s_waitcnt vmcnt(0)" ::: "memory");
    __syncthreads();
    int cur = 0;
    for (int kt = 0; kt < NT; ++kt) {
        int k0 = kt * 64;
        if (kt + 1 < NT) stageV(kt + 1, cur ^ 1);  // V dbuf target free now
        // ---- QK^T swapped: s[c] rows=keys(lc*4+r), cols=q(lr) ----
        f32x4 s[4] = {};
        __builtin_amdgcn_s_setprio(1);
#pragma unroll
        for (int c = 0; c < 4; ++c) {
            if (k0 + c * 16 <= q_hi) {
                f32x4 a = {};
#pragma unroll
                for (int dc = 0; dc < 4; ++dc) {
                    bf16x8 kh8 = *(const bf16x8*)&smem[((c * 4 + dc) * 64 + lane) * 8];
                    bf16x8 kl8 =
                        *(const bf16x8*)&smem[8192 + ((c * 4 + dc) * 64 + lane) * 8];
                    a = __builtin_amdgcn_mfma_f32_16x16x32_bf16(kh8, aqh[dc], a, 0, 0, 0);
                    a = __builtin_amdgcn_mfma_f32_16x16x32_bf16(kh8, aql[dc], a, 0, 0, 0);
                    a = __builtin_amdgcn_mfma_f32_16x16x32_bf16(kl8, aqh[dc], a, 0, 0, 0);
                }
                s[c] = a;
            }
        }
        __builtin_amdgcn_s_setprio(0);
        __syncthreads();  // K consumed by all waves -> safe to restage K
        if (kt + 1 < NT) stageK(kt + 1);
        // ---- mask + in-lane row max ----
        int q = q0 + lr;
        float tmax = -1e30f;
#pragma unroll
        for (int c = 0; c < 4; ++c) {
            bool active = (k0 + c * 16 <= q_hi);
            bool edge = (k0 + c * 16 + 15 >= q0);
#pragma unroll
            for (int r = 0; r < 4; ++r) {
                float sv = active ? s[c][r] : -1e30f;
                if (active && edge) {
                    int key = k0 + c * 16 + lc * 4 + r;
                    if (key > q) sv = -1e30f;
                }
                s[c][r] = sv;
                tmax = fmaxf(tmax, sv);
            }
        }
        tmax = fmaxf(tmax, __shfl_xor(tmax, 16));
        tmax = fmaxf(tmax, __shfl_xor(tmax, 32));
        // ---- defer-max: rescale only when the row max grew by > 8 ----
        if (__any(tmax > m + 8.0f)) {
            float mn = fmaxf(m, tmax);
            float alpha = exp2f(m - mn);
            m = mn;
            l *= alpha;
            float a0 = __shfl(alpha, lc * 4 + 0);
            float a1 = __shfl(alpha, lc * 4 + 1);
            float a2 = __shfl(alpha, lc * 4 + 2);
            float a3 = __shfl(alpha, lc * 4 + 3);
#pragma unroll
            for (int n = 0; n < 8; ++n) {
                oacc[n][0] *= a0; oacc[n][1] *= a1;
                oacc[n][2] *= a2; oacc[n][3] *= a3;
            }
        }
        // ---- P = exp2(s-m) in fp16 (l-consistent), in-lane psum ----
        u16 pbf[4][4];
        float psum = 0.f;
#pragma unroll
        for (int c = 0; c < 4; ++c)
#pragma unroll
            for (int r = 0; r < 4; ++r) {
                float pv = exp2f(s[c][r] - m);
                _Float16 ph = (_Float16)pv;
                pbf[c][r] = __builtin_bit_cast(unsigned short, ph);
                psum += (float)ph;
            }
        psum += __shfl_xor(psum, 16);
        psum += __shfl_xor(psum, 32);
        l += psum;
        // ---- PV per 32-key chunk: 2x ds_write_b64 pack, 1-term fp16 MFMA ----
#pragma unroll
        for (int kc = 0; kc < 2; ++kc) {
            if (k0 + kc * 32 <= q_hi) {
                s16x4 w0, w1;
#pragma unroll
                for (int r = 0; r < 4; ++r) {
                    w0[r] = (short)pbf[kc * 2][r];
                    w1[r] = (short)pbf[kc * 2 + 1][r];
                }
                *(s16x4*)&pb[lr * 40 + lc * 4] = w0;
                *(s16x4*)&pb[lr * 40 + 16 + lc * 4] = w1;
                asm volatile("s_waitcnt lgkmcnt(0)" ::: "memory");
                f16x8 pa = *(const f16x8*)&pb[lr * 40 + lc * 8];
                __builtin_amdgcn_s_setprio(1);
#pragma unroll
                for (int n = 0; n < 8; ++n) {
                    f16x8 v8 = *(const f16x8*)&smem[16384 + cur * 8192 +
                                                    ((kc * 8 + n) * 64 + lane) * 8];
                    oacc[n] = __builtin_amdgcn_mfma_f32_16x16x32_f16(pa, v8, oacc[n], 0, 0, 0);
                }
                __builtin_amdgcn_s_setprio(0);
            }
        }
        asm volatile("s_waitcnt vmcnt(0)" ::: "memory");
        __syncthreads();
        cur ^= 1;
    }
    // ---- write O in-place; l lives at lane (lr = q-row), redistribute ----
    float l0 = __shfl(l, lc * 4 + 0);
    float l1 = __shfl(l, lc * 4 + 1);
    float l2 = __shfl(l, lc * 4 + 2);
    float l3 = __shfl(l, lc * 4 + 3);
#pragma unroll
    for (int n = 0; n < 8; ++n) {
        int col = h * HD + n * 16 + lr;
        qf[(size_t)(q0 + lc * 4 + 0) * HID + col] = oacc[n][0] / l0;
        qf[(size_t)(q0 + lc * 4 + 1) * HID + col] = oacc[n][1] / l1;
        qf[(size_t)(q0 + lc * 4 + 2) * HID + col] = oacc[n][2] / l2;
        qf[(size_t)(q0 + lc * 4 + 3) * HID + col] = oacc[n][3] / l3;
    }
}

// ------- Hadamard head-mix (register FWHT) + int4 requant + wo pack ---------
__global__ __launch_bounds__(256) void k_hadq(const float* __restrict__ attn,
        s8* __restrict__ a2, float* __restrict__ sa,
        const int* __restrict__ wo, s8* __restrict__ wo8) {
    int t = blockIdx.x, tid = threadIdx.x;
    // fold wo int32->int8 pack: 2 x 16B units per thread (2048*256*2 = 1M units)
    {
        size_t u0 = ((size_t)t * 256 + tid) * 2;
#pragma unroll
        for (int k = 0; k < 2; ++k) {
            size_t i = (u0 + k) * 16;
            i32x4 o;
#pragma unroll
            for (int j = 0; j < 4; ++j) {
                i32x4 v = *(const i32x4*)(wo + i + j * 4);
                o[j] = (v[0] & 0xff) | ((v[1] & 0xff) << 8) |
                       ((v[2] & 0xff) << 16) | (v[3] << 24);
            }
            *(i32x4*)(wo8 + i) = o;
        }
    }
    int w = tid >> 6, lane = tid & 63;
    int d = (w & 1) * 64 + lane;
    int half = w >> 1;
    __shared__ float rowb[HID];
    const float* ar = attn + (size_t)t * HID;
#pragma unroll
    for (int i = 0; i < 4; ++i)
        *(f32x4*)&rowb[i * 1024 + tid * 4] = *(const f32x4*)(ar + i * 1024 + tid * 4);
    __syncthreads();
    float u[16];
#pragma unroll
    for (int i = 0; i < 16; ++i) u[i] = rowb[(half * 16 + i) * 128 + d];
#pragma unroll
    for (int s = 1; s < 16; s <<= 1)
#pragma unroll
        for (int i = 0; i < 16; ++i)
            if (!(i & s)) {
                float a = u[i], b = u[i | s];
                u[i] = a + b;
                u[i | s] = a - b;
            }
#pragma unroll
    for (int i = 0; i < 16; ++i) rowb[(half * 16 + i) * 128 + d] = u[i];
    __syncthreads();
    float y[16], amax = 0.f;
#pragma unroll
    for (int i = 0; i < 16; ++i) {
        float o = rowb[((half ^ 1) * 16 + i) * 128 + d];
        float yv = half ? (o - u[i]) : (u[i] + o);
        yv *= 0.17677669529663687f;
        y[i] = yv;
        amax = fmaxf(amax, fabsf(yv));
    }
#pragma unroll
    for (int off = 32; off >= 1; off >>= 1)
        amax = fmaxf(amax, __shfl_xor(amax, off));
    __shared__ float red[4];
    if ((tid & 63) == 0) red[tid >> 6] = amax;
    __syncthreads();
    amax = fmaxf(fmaxf(red[0], red[1]), fmaxf(red[2], red[3]));
    float s = fmaxf(amax / 7.f, 1e-8f);
    if (tid == 0) sa[t] = s;
    s8* o2 = a2 + (size_t)t * HID;
#pragma unroll
    for (int i = 0; i < 16; ++i) {
        float q = rintf(y[i] / s);
        q = fminf(fmaxf(q, -8.f), 7.f);
        o2[(half * 16 + i) * 128 + d] = (s8)(int)q;
    }
}

extern "C" void kernel_launch(void* const* d_in, const int* in_sizes, int n_in,
                              void* d_out, int out_size, void* d_ws, size_t ws_size,
                              hipStream_t stream) {
    const int* positions = (const int*)d_in[0];
    const float* hidden = (const float*)d_in[1];
    const int* wq = (const int*)d_in[2];
    const float* wq_s = (const float*)d_in[3];
    const int* wk = (const int*)d_in[4];
    const float* wk_s = (const float*)d_in[5];
    const int* wv = (const int*)d_in[6];
    const float* wv_s = (const float*)d_in[7];
    const int* wo = (const int*)d_in[8];
    const float* wo_s = (const float*)d_in[9];

    char* ws = (char*)d_ws;
    float* s_x = (float*)(ws);
    float* s_a = (float*)(ws + 8192);
    float* ctab = (float*)(ws + 16384);
    float* stab = (float*)(ws + 16384 + 524288);
    char* base1 = ws + 16384 + 1048576;
    s8* a8 = (s8*)base1;                                 // 8.39 MB
    float* q_f = (float*)(base1 + 8388608);              // 33.55 MB
    float* k_f = (float*)(base1 + 8388608 + 33554432);   // 8.39 MB
    char* X = base1 + 8388608 + 33554432 + 8388608;      // 16.78 MB
    char* W2 = X + 16777216;                             // 8.39 MB
    s8* wq8 = (s8*)X;                 // dead after QKV-GEMM
    u16* khf = (u16*)(X);             // written by ropek (after QKV-GEMM)
    u16* klf = (u16*)(X + 4194304);
    u16* vf = (u16*)(X + 8388608);    // fp16 frag V^T, written by QKV-GEMM
    s8* wk8 = (s8*)W2;
    s8* wv8 = (s8*)(W2 + 4194304);
    s8* wo8 = (s8*)X;                 // packed by k_hadq after attn

    k_pre<<<8704, 256, 0, stream>>>(positions, hidden, wq, wk, wv, ctab, stab,
                                    a8, s_x, wq8, wk8, wv8);
    k_qkv<<<dim3(16, 48), 256, 0, stream>>>(a8, wq8, wk8, wv8, s_x,
                                            wq_s, wk_s, wv_s, q_f, k_f, vf);
    k_ropek<<<T_SEQ, 256, 0, stream>>>(k_f, ctab, stab, khf, klf);
    k_attn<<<512, 512, 0, stream>>>(q_f, khf, klf, vf, ctab, stab);
    k_hadq<<<T_SEQ, 256, 0, stream>>>(q_f, a8, s_a, wo, wo8);
    k_gemm8<<<dim3(16, 32), 256, 0, stream>>>(a8, wo8, s_a, wo_s,
                                              (float*)d_out);
}

// Round 10
// 269.587 us; speedup vs baseline: 5.4183x; 1.0272x over previous
//
#include <hip/hip_runtime.h>

#define T_SEQ 2048
#define HID 4096
#define NH 32
#define NKV 8
#define HD 128
#define KDIM 4096

typedef unsigned short u16;
typedef signed char s8;
typedef __attribute__((ext_vector_type(4))) float f32x4;
typedef __attribute__((ext_vector_type(4))) int i32x4;
typedef __attribute__((ext_vector_type(2))) unsigned int u32x2;
typedef __attribute__((ext_vector_type(8))) short s16x8;
typedef __attribute__((ext_vector_type(4))) short s16x4;
typedef __attribute__((ext_vector_type(8))) __bf16 bf16x8;
typedef __attribute__((ext_vector_type(8))) _Float16 f16x8;
typedef __attribute__((ext_vector_type(2))) _Float16 f16x2;

static __device__ __forceinline__ u16 f2bf(float f) {
    __bf16 b = (__bf16)f;
    return __builtin_bit_cast(unsigned short, b);
}
static __device__ __forceinline__ float bf2f(u16 b) {
    unsigned u = ((unsigned)b) << 16;
    return __builtin_bit_cast(float, u);
}
static __device__ __forceinline__ __bf16 bfbits(u16 b) {
    return __builtin_bit_cast(__bf16, b);
}
static __device__ __forceinline__ u16 f2h(float f) {
    _Float16 h = (_Float16)f;
    return __builtin_bit_cast(unsigned short, h);
}

typedef __attribute__((address_space(1))) const void gas_t;
typedef __attribute__((address_space(3))) void las_t;
static __device__ __forceinline__ void gll16(const void* g, void* l) {
    __builtin_amdgcn_global_load_lds((gas_t*)g, (las_t*)l, 16, 0, 0);
}

// ---- fused pre-pass: trig tables | activation int4-quant | QKV weight pack --
__global__ __launch_bounds__(256) void k_pre(const int* __restrict__ pos,
        const float* __restrict__ x, const int* __restrict__ wq,
        const int* __restrict__ wk, const int* __restrict__ wv,
        float* __restrict__ ctab, float* __restrict__ stab,
        s8* __restrict__ a8, float* __restrict__ srow,
        s8* __restrict__ q8, s8* __restrict__ k8, s8* __restrict__ v8) {
    int b = blockIdx.x, tid = threadIdx.x;
    if (b < 512) {
        int idx = b * 256 + tid;
        int t = idx >> 6, d = idx & 63;
        float p = (float)pos[t];
        float inv = (float)pow(10000.0, -(double)d / 64.0);
        float ang = p * inv;
        double dsn, dcs;
        sincos((double)ang, &dsn, &dcs);
        ctab[idx] = (float)dcs;
        stab[idx] = (float)dsn;
    } else if (b < 512 + 2048) {
        int row = b - 512;
        const float* xr = x + (size_t)row * HID;
        f32x4 v[4];
        float amax = 0.f;
#pragma unroll
        for (int i = 0; i < 4; ++i) {
            v[i] = *(const f32x4*)(xr + i * 1024 + tid * 4);
#pragma unroll
            for (int j = 0; j < 4; ++j) amax = fmaxf(amax, fabsf(v[i][j]));
        }
#pragma unroll
        for (int off = 32; off >= 1; off >>= 1)
            amax = fmaxf(amax, __shfl_xor(amax, off));
        __shared__ float red[4];
        if ((tid & 63) == 0) red[tid >> 6] = amax;
        __syncthreads();
        amax = fmaxf(fmaxf(red[0], red[1]), fmaxf(red[2], red[3]));
        float s = fmaxf(amax / 7.f, 1e-8f);
        if (tid == 0) srow[row] = s;
        int* qr = (int*)(a8 + (size_t)row * HID);
#pragma unroll
        for (int i = 0; i < 4; ++i) {
            int p = 0;
#pragma unroll
            for (int j = 0; j < 4; ++j) {
                float q = rintf(v[i][j] / s);
                q = fminf(fmaxf(q, -8.f), 7.f);
                p |= ((int)q & 0xff) << (8 * j);
            }
            qr[i * 256 + tid] = p;
        }
    } else {
        size_t i = ((size_t)(b - 2560) * 256 + tid) * 16;
        const int* src; s8* dst; size_t off;
        if (i < 16777216) { src = wq; dst = q8; off = i; }
        else if (i < 20971520) { src = wk; dst = k8; off = i - 16777216; }
        else { src = wv; dst = v8; off = i - 20971520; }
        i32x4 o;
#pragma unroll
        for (int j = 0; j < 4; ++j) {
            i32x4 v = *(const i32x4*)(src + off + j * 4);
            o[j] = (v[0] & 0xff) | ((v[1] & 0xff) << 8) |
                   ((v[2] & 0xff) << 16) | (v[3] << 24);
        }
        *(i32x4*)(dst + off) = o;
    }
}

// ---------------- unified QKV int8 GEMM, double-buffered T3 pipeline --------
__global__ __launch_bounds__(256) void k_qkv(const s8* __restrict__ A,
        const s8* __restrict__ Wq, const s8* __restrict__ Wk,
        const s8* __restrict__ Wv, const float* __restrict__ sRow,
        const float* __restrict__ sq, const float* __restrict__ sk,
        const float* __restrict__ sv, float* __restrict__ qout,
        float* __restrict__ kout, u16* __restrict__ voutf) {
    __shared__ __align__(16) s8 sA[2][16384], sB[2][16384];
    int tid = threadIdx.x;
    int by = blockIdx.y;
    int mode = by < 32 ? 0 : (by < 40 ? 1 : 2);
    const s8* W = mode == 0 ? Wq : (mode == 1 ? Wk : Wv);
    const float* sCol = mode == 0 ? sq : (mode == 1 ? sk : sv);
    int bcolb = mode == 0 ? by : (mode == 1 ? by - 32 : by - 40);
    int brow = blockIdx.x * 128, bcol = bcolb * 128;
    const int K = KDIM;
    int wid = tid >> 6, lane = tid & 63;
    int wr = (wid >> 1) * 64, wc = (wid & 1) * 64;
    int lr = lane & 15, lc = lane >> 4;
    i32x4 acc[4][4] = {};
    auto stage = [&](int buf, int k0) {
#pragma unroll
        for (int j = 0; j < 4; ++j) {
            int base = wid * 1024 + j * 4096;
            int o = base + lane * 16;
            int r = o >> 7;
            int c = (o & 127) ^ ((r & 7) << 4);
            gll16(A + (size_t)(brow + r) * K + (k0 + c), (char*)sA[buf] + base);
            gll16(W + (size_t)(bcol + r) * K + (k0 + c), (char*)sB[buf] + base);
        }
    };
    stage(0, 0);
    asm volatile("s_waitcnt vmcnt(0)" ::: "memory");
    __syncthreads();
    int cur = 0;
    for (int k0 = 0; k0 < K; k0 += 128) {
        if (k0 + 128 < K) stage(cur ^ 1, k0 + 128);
#pragma unroll
        for (int kk = 0; kk < 2; ++kk) {
            i32x4 af[4], bf[4];
#pragma unroll
            for (int m = 0; m < 4; ++m) {
                int r = wr + m * 16 + lr;
                int sl = ((kk * 4 + lc) ^ (r & 7)) * 16;
                af[m] = *(const i32x4*)&sA[cur][r * 128 + sl];
            }
#pragma unroll
            for (int n = 0; n < 4; ++n) {
                int r = wc + n * 16 + lr;
                int sl = ((kk * 4 + lc) ^ (r & 7)) * 16;
                bf[n] = *(const i32x4*)&sB[cur][r * 128 + sl];
            }
#pragma unroll
            for (int m = 0; m < 4; ++m)
#pragma unroll
                for (int n = 0; n < 4; ++n)
                    acc[m][n] = __builtin_amdgcn_mfma_i32_16x16x64_i8(
                        af[m], bf[n], acc[m][n], 0, 0, 0);
        }
        asm volatile("s_waitcnt vmcnt(0)" ::: "memory");
        __syncthreads();
        cur ^= 1;
    }
#pragma unroll
    for (int m = 0; m < 4; ++m) {
        int row0 = brow + wr + m * 16 + lc * 4;
#pragma unroll
        for (int n = 0; n < 4; ++n) {
            int col = bcol + wc + n * 16 + lr;
            float scl = sCol[col];
            if (mode == 0) {
#pragma unroll
                for (int r = 0; r < 4; ++r)
                    qout[(size_t)(row0 + r) * HID + col] =
                        (float)acc[m][n][r] * sRow[row0 + r] * scl;
            } else if (mode == 1) {
#pragma unroll
                for (int r = 0; r < 4; ++r)
                    kout[(size_t)(row0 + r) * (NKV * HD) + col] =
                        (float)acc[m][n][r] * sRow[row0 + r] * scl;
            } else {
                int kvh = col >> 7, d = col & 127;
                int nn = d >> 4, lrv = d & 15;
                int kt = row0 >> 6, rem = row0 & 63;
                int kc = rem >> 5, lcv = (rem & 31) >> 3, j0 = rem & 7;
                size_t base =
                    ((((size_t)(kvh * 32 + kt) * 2 + kc) * 8 + nn) * 64 +
                     lcv * 16 + lrv) * 8 + j0;
                s16x4 hh;
#pragma unroll
                for (int r = 0; r < 4; ++r) {
                    float val = (float)acc[m][n][r] * sRow[row0 + r] * scl;
                    hh[r] = (short)f2h(val);
                }
                *(s16x4*)(voutf + base) = hh;
            }
        }
    }
}

// ---------------- O-proj int8 GEMM, same double-buffered pipeline -----------
__global__ __launch_bounds__(256) void k_gemm8(const s8* __restrict__ A,
        const s8* __restrict__ W, const float* __restrict__ sRow,
        const float* __restrict__ sCol, float* __restrict__ outp) {
    __shared__ __align__(16) s8 sA[2][16384], sB[2][16384];
    int tid = threadIdx.x;
    int brow = blockIdx.x * 128, bcol = blockIdx.y * 128;
    const int K = KDIM;
    int wid = tid >> 6, lane = tid & 63;
    int wr = (wid >> 1) * 64, wc = (wid & 1) * 64;
    int lr = lane & 15, lc = lane >> 4;
    i32x4 acc[4][4] = {};
    auto stage = [&](int buf, int k0) {
#pragma unroll
        for (int j = 0; j < 4; ++j) {
            int base = wid * 1024 + j * 4096;
            int o = base + lane * 16;
            int r = o >> 7;
            int c = (o & 127) ^ ((r & 7) << 4);
            gll16(A + (size_t)(brow + r) * K + (k0 + c), (char*)sA[buf] + base);
            gll16(W + (size_t)(bcol + r) * K + (k0 + c), (char*)sB[buf] + base);
        }
    };
    stage(0, 0);
    asm volatile("s_waitcnt vmcnt(0)" ::: "memory");
    __syncthreads();
    int cur = 0;
    for (int k0 = 0; k0 < K; k0 += 128) {
        if (k0 + 128 < K) stage(cur ^ 1, k0 + 128);
#pragma unroll
        for (int kk = 0; kk < 2; ++kk) {
            i32x4 af[4], bf[4];
#pragma unroll
            for (int m = 0; m < 4; ++m) {
                int r = wr + m * 16 + lr;
                int sl = ((kk * 4 + lc) ^ (r & 7)) * 16;
                af[m] = *(const i32x4*)&sA[cur][r * 128 + sl];
            }
#pragma unroll
            for (int n = 0; n < 4; ++n) {
                int r = wc + n * 16 + lr;
                int sl = ((kk * 4 + lc) ^ (r & 7)) * 16;
                bf[n] = *(const i32x4*)&sB[cur][r * 128 + sl];
            }
#pragma unroll
            for (int m = 0; m < 4; ++m)
#pragma unroll
                for (int n = 0; n < 4; ++n)
                    acc[m][n] = __builtin_amdgcn_mfma_i32_16x16x64_i8(
                        af[m], bf[n], acc[m][n], 0, 0, 0);
        }
        asm volatile("s_waitcnt vmcnt(0)" ::: "memory");
        __syncthreads();
        cur ^= 1;
    }
#pragma unroll
    for (int m = 0; m < 4; ++m) {
        int row0 = brow + wr + m * 16 + lc * 4;
#pragma unroll
        for (int n = 0; n < 4; ++n) {
            int col = bcol + wc + n * 16 + lr;
            float scl = sCol[col];
#pragma unroll
            for (int r = 0; r < 4; ++r)
                outp[(size_t)(row0 + r) * HID + col] =
                    (float)acc[m][n][r] * sRow[row0 + r] * scl;
        }
    }
}

// ---------------- RoPE on K only -> fragment-ordered hi/lo bf16 -------------
__global__ __launch_bounds__(256) void k_ropek(const float* __restrict__ kf,
        const float* __restrict__ ctab, const float* __restrict__ stab,
        u16* __restrict__ khf, u16* __restrict__ klf) {
    int t = blockIdx.x, tid = threadIdx.x;
    int kt = t >> 6, rem = t & 63, cblk = rem >> 4, lrk = rem & 15;
    for (int idx = tid; idx < NKV * 64; idx += 256) {
        int kh = idx >> 6, d = idx & 63;
        float cs = ctab[t * 64 + d], sn = stab[t * 64 + d];
        size_t base = (size_t)t * (NKV * HD) + kh * HD;
        float x1 = kf[base + d], x2 = kf[base + d + 64];
        float r1 = x1 * cs - x2 * sn;
        float r2 = x2 * cs + x1 * sn;
        size_t tb = (((size_t)(kh * 32 + kt) * 4 + cblk) * 4) * 512;
#pragma unroll
        for (int half = 0; half < 2; ++half) {
            int x = d + half * 64;
            float rv = half ? r2 : r1;
            int dcx = x >> 5, lcx = (x & 31) >> 3, jx = x & 7;
            size_t ii = tb + (size_t)dcx * 512 + (lcx * 16 + lrk) * 8 + jx;
            u16 hb = f2bf(rv);
            khf[ii] = hb;
            klf[ii] = f2bf(rv - bf2f(hb));
        }
    }
}

// ---------------- GQA causal flash attention ---------------------------------
// 512 blocks, XCD-aware: kvh = bid&7 (all same-kvh blocks on one XCD's L2);
// co-resident pair (s, s+8) -> bx (s, 15-s) keeps per-CU work uniform (34).
// 8 waves, KVBLK=64; K single-buf, V double-buf (stageV at loop top).
// Swapped QK^T, in-lane softmax, defer-max, fp16 PV via cvt_pkrtz.
__global__ __launch_bounds__(512, 4) void k_attn(float* __restrict__ qf,
        const u16* __restrict__ khf, const u16* __restrict__ klf,
        const u16* __restrict__ vf,
        const float* __restrict__ ctab, const float* __restrict__ stab) {
    int bid = blockIdx.x;
    int kvh = bid & 7;
    int h = kvh * 4 + ((bid >> 3) & 3);
    int sidx = bid >> 5;                    // [0,16)
    int bx = sidx < 8 ? sidx : 23 - sidx;   // pair (s, s+8) -> (s, 15-s)
    int tid = threadIdx.x, wid = tid >> 6, lane = tid & 63;
    int lr = lane & 15, lc = lane >> 4;
    int q0 = bx * 128 + wid * 16, q_hi = q0 + 15;
    __shared__ __align__(16) u16 smem[37888];
    u16* pb = smem + 32768 + wid * 640;  // per-wave [16][40]
    const float SCL = 0.12751744f;       // 1/sqrt(128) * log2(e)
    size_t kvbase = (size_t)kvh * 32 * 8192;
    auto stageK = [&](int kt) {
        const char* gk = (const char*)(khf + kvbase + (size_t)kt * 8192);
        const char* gl = (const char*)(klf + kvbase + (size_t)kt * 8192);
#pragma unroll
        for (int j = 0; j < 4; ++j) {
            int c = wid * 4 + j;
            int sel = c >> 4;
            int inner = (c & 15) * 1024;
            gll16((sel ? gl : gk) + inner + lane * 16,
                  (char*)smem + sel * 16384 + inner);
        }
    };
    auto stageV = [&](int kt, int buf) {
        const char* gv = (const char*)(vf + kvbase + (size_t)kt * 8192);
#pragma unroll
        for (int j = 0; j < 2; ++j) {
            int c = wid * 2 + j;
            gll16(gv + c * 1024 + lane * 16,
                  (char*)smem + 32768 + buf * 16384 + c * 1024);
        }
    };
    // ---- Q load + fused RoPE + scale + hi/lo split ----
    bf16x8 aqh[4], aql[4];
    {
        const float* qrow = qf + (size_t)(q0 + lr) * HID + h * HD;
        const float* ct = ctab + (size_t)(q0 + lr) * 64 + lc * 8;
        const float* st = stab + (size_t)(q0 + lr) * 64 + lc * 8;
        float qv[4][8];
#pragma unroll
        for (int dc = 0; dc < 4; ++dc) {
            f32x4 a = *(const f32x4*)(qrow + dc * 32 + lc * 8);
            f32x4 b = *(const f32x4*)(qrow + dc * 32 + lc * 8 + 4);
#pragma unroll
            for (int j = 0; j < 4; ++j) { qv[dc][j] = a[j]; qv[dc][j + 4] = b[j]; }
        }
        float cs[2][8], sn[2][8];
#pragma unroll
        for (int hf = 0; hf < 2; ++hf) {
            f32x4 c0 = *(const f32x4*)(ct + hf * 32);
            f32x4 c1 = *(const f32x4*)(ct + hf * 32 + 4);
            f32x4 s0 = *(const f32x4*)(st + hf * 32);
            f32x4 s1 = *(const f32x4*)(st + hf * 32 + 4);
#pragma unroll
            for (int j = 0; j < 4; ++j) {
                cs[hf][j] = c0[j]; cs[hf][j + 4] = c1[j];
                sn[hf][j] = s0[j]; sn[hf][j + 4] = s1[j];
            }
        }
#pragma unroll
        for (int dc0 = 0; dc0 < 2; ++dc0)
#pragma unroll
            for (int j = 0; j < 8; ++j) {
                float c = cs[dc0][j], s2 = sn[dc0][j];
                float x1 = qv[dc0][j], x2 = qv[dc0 + 2][j];
                qv[dc0][j] = x1 * c - x2 * s2;
                qv[dc0 + 2][j] = x2 * c + x1 * s2;
            }
#pragma unroll
        for (int dc = 0; dc < 4; ++dc)
#pragma unroll
            for (int j = 0; j < 8; ++j) {
                float v = qv[dc][j] * SCL;
                u16 hb = f2bf(v);
                aqh[dc][j] = bfbits(hb);
                aql[dc][j] = bfbits(f2bf(v - bf2f(hb)));
            }
    }
    f32x4 oacc[8] = {};
    float m = -1e30f, l = 0.f;  // per-lane: q-row q0+lr
    int NT = 2 * bx + 2;
    stageK(0);
    stageV(0, 0);
    asm volatile("s_waitcnt vmcnt(0)" ::: "memory");
    __syncthreads();
    int cur = 0;
    for (int kt = 0; kt < NT; ++kt) {
        int k0 = kt * 64;
        if (kt + 1 < NT) stageV(kt + 1, cur ^ 1);  // V dbuf target free now
        // ---- QK^T swapped: s[c] rows=keys(lc*4+r), cols=q(lr) ----
        f32x4 s[4] = {};
        __builtin_amdgcn_s_setprio(1);
#pragma unroll
        for (int c = 0; c < 4; ++c) {
            if (k0 + c * 16 <= q_hi) {
                f32x4 a = {};
#pragma unroll
                for (int dc = 0; dc < 4; ++dc) {
                    bf16x8 kh8 = *(const bf16x8*)&smem[((c * 4 + dc) * 64 + lane) * 8];
                    bf16x8 kl8 =
                        *(const bf16x8*)&smem[8192 + ((c * 4 + dc) * 64 + lane) * 8];
                    a = __builtin_amdgcn_mfma_f32_16x16x32_bf16(kh8, aqh[dc], a, 0, 0, 0);
                    a = __builtin_amdgcn_mfma_f32_16x16x32_bf16(kh8, aql[dc], a, 0, 0, 0);
                    a = __builtin_amdgcn_mfma_f32_16x16x32_bf16(kl8, aqh[dc], a, 0, 0, 0);
                }
                s[c] = a;
            }
        }
        __builtin_amdgcn_s_setprio(0);
        __syncthreads();  // K consumed by all waves -> safe to restage K
        if (kt + 1 < NT) stageK(kt + 1);
        // ---- mask + in-lane row max ----
        int q = q0 + lr;
        float tmax = -1e30f;
#pragma unroll
        for (int c = 0; c < 4; ++c) {
            bool active = (k0 + c * 16 <= q_hi);
            bool edge = (k0 + c * 16 + 15 >= q0);
#pragma unroll
            for (int r = 0; r < 4; ++r) {
                float sv = active ? s[c][r] : -1e30f;
                if (active && edge) {
                    int key = k0 + c * 16 + lc * 4 + r;
                    if (key > q) sv = -1e30f;
                }
                s[c][r] = sv;
                tmax = fmaxf(tmax, sv);
            }
        }
        tmax = fmaxf(tmax, __shfl_xor(tmax, 16));
        tmax = fmaxf(tmax, __shfl_xor(tmax, 32));
        // ---- defer-max: rescale only when the row max grew by > 8 ----
        if (__any(tmax > m + 8.0f)) {
            float mn = fmaxf(m, tmax);
            float alpha = exp2f(m - mn);
            m = mn;
            l *= alpha;
            float a0 = __shfl(alpha, lc * 4 + 0);
            float a1 = __shfl(alpha, lc * 4 + 1);
            float a2 = __shfl(alpha, lc * 4 + 2);
            float a3 = __shfl(alpha, lc * 4 + 3);
#pragma unroll
            for (int n = 0; n < 8; ++n) {
                oacc[n][0] *= a0; oacc[n][1] *= a1;
                oacc[n][2] *= a2; oacc[n][3] *= a3;
            }
        }
        // ---- P = exp2(s-m); psum from f32; fp16 pack via cvt_pkrtz ----
        float pvv[4][4];
        float psum = 0.f;
#pragma unroll
        for (int c = 0; c < 4; ++c)
#pragma unroll
            for (int r = 0; r < 4; ++r) {
                float pv = __builtin_amdgcn_exp2f(s[c][r] - m);
                pvv[c][r] = pv;
                psum += pv;
            }
        psum += __shfl_xor(psum, 16);
        psum += __shfl_xor(psum, 32);
        l += psum;
        // ---- PV per 32-key chunk: pkrtz pack -> pb, 1-term fp16 MFMA ----
#pragma unroll
        for (int kc = 0; kc < 2; ++kc) {
            if (k0 + kc * 32 <= q_hi) {
                u32x2 w0, w1;
                w0[0] = __builtin_bit_cast(unsigned int,
                        __builtin_amdgcn_cvt_pkrtz(pvv[kc * 2][0], pvv[kc * 2][1]));
                w0[1] = __builtin_bit_cast(unsigned int,
                        __builtin_amdgcn_cvt_pkrtz(pvv[kc * 2][2], pvv[kc * 2][3]));
                w1[0] = __builtin_bit_cast(unsigned int,
                        __builtin_amdgcn_cvt_pkrtz(pvv[kc * 2 + 1][0], pvv[kc * 2 + 1][1]));
                w1[1] = __builtin_bit_cast(unsigned int,
                        __builtin_amdgcn_cvt_pkrtz(pvv[kc * 2 + 1][2], pvv[kc * 2 + 1][3]));
                *(u32x2*)&pb[lr * 40 + lc * 4] = w0;
                *(u32x2*)&pb[lr * 40 + 16 + lc * 4] = w1;
                asm volatile("s_waitcnt lgkmcnt(0)" ::: "memory");
                f16x8 pa = *(const f16x8*)&pb[lr * 40 + lc * 8];
                __builtin_amdgcn_s_setprio(1);
#pragma unroll
                for (int n = 0; n < 8; ++n) {
                    f16x8 v8 = *(const f16x8*)&smem[16384 + cur * 8192 +
                                                    ((kc * 8 + n) * 64 + lane) * 8];
                    oacc[n] = __builtin_amdgcn_mfma_f32_16x16x32_f16(pa, v8, oacc[n], 0, 0, 0);
                }
                __builtin_amdgcn_s_setprio(0);
            }
        }
        asm volatile("s_waitcnt vmcnt(0)" ::: "memory");
        __syncthreads();
        cur ^= 1;
    }
    // ---- write O in-place; l lives at lane (lr = q-row), redistribute ----
    float l0 = __shfl(l, lc * 4 + 0);
    float l1 = __shfl(l, lc * 4 + 1);
    float l2 = __shfl(l, lc * 4 + 2);
    float l3 = __shfl(l, lc * 4 + 3);
#pragma unroll
    for (int n = 0; n < 8; ++n) {
        int col = h * HD + n * 16 + lr;
        qf[(size_t)(q0 + lc * 4 + 0) * HID + col] = oacc[n][0] / l0;
        qf[(size_t)(q0 + lc * 4 + 1) * HID + col] = oacc[n][1] / l1;
        qf[(size_t)(q0 + lc * 4 + 2) * HID + col] = oacc[n][2] / l2;
        qf[(size_t)(q0 + lc * 4 + 3) * HID + col] = oacc[n][3] / l3;
    }
}

// ------- Hadamard head-mix (register FWHT) + int4 requant + wo pack ---------
__global__ __launch_bounds__(256) void k_hadq(const float* __restrict__ attn,
        s8* __restrict__ a2, float* __restrict__ sa,
        const int* __restrict__ wo, s8* __restrict__ wo8) {
    int t = blockIdx.x, tid = threadIdx.x;
    {
        size_t u0 = ((size_t)t * 256 + tid) * 2;
#pragma unroll
        for (int k = 0; k < 2; ++k) {
            size_t i = (u0 + k) * 16;
            i32x4 o;
#pragma unroll
            for (int j = 0; j < 4; ++j) {
                i32x4 v = *(const i32x4*)(wo + i + j * 4);
                o[j] = (v[0] & 0xff) | ((v[1] & 0xff) << 8) |
                       ((v[2] & 0xff) << 16) | (v[3] << 24);
            }
            *(i32x4*)(wo8 + i) = o;
        }
    }
    int w = tid >> 6, lane = tid & 63;
    int d = (w & 1) * 64 + lane;
    int half = w >> 1;
    __shared__ float rowb[HID];
    const float* ar = attn + (size_t)t * HID;
#pragma unroll
    for (int i = 0; i < 4; ++i)
        *(f32x4*)&rowb[i * 1024 + tid * 4] = *(const f32x4*)(ar + i * 1024 + tid * 4);
    __syncthreads();
    float u[16];
#pragma unroll
    for (int i = 0; i < 16; ++i) u[i] = rowb[(half * 16 + i) * 128 + d];
#pragma unroll
    for (int s = 1; s < 16; s <<= 1)
#pragma unroll
        for (int i = 0; i < 16; ++i)
            if (!(i & s)) {
                float a = u[i], b = u[i | s];
                u[i] = a + b;
                u[i | s] = a - b;
            }
#pragma unroll
    for (int i = 0; i < 16; ++i) rowb[(half * 16 + i) * 128 + d] = u[i];
    __syncthreads();
    float y[16], amax = 0.f;
#pragma unroll
    for (int i = 0; i < 16; ++i) {
        float o = rowb[((half ^ 1) * 16 + i) * 128 + d];
        float yv = half ? (o - u[i]) : (u[i] + o);
        yv *= 0.17677669529663687f;
        y[i] = yv;
        amax = fmaxf(amax, fabsf(yv));
    }
#pragma unroll
    for (int off = 32; off >= 1; off >>= 1)
        amax = fmaxf(amax, __shfl_xor(amax, off));
    __shared__ float red[4];
    if ((tid & 63) == 0) red[tid >> 6] = amax;
    __syncthreads();
    amax = fmaxf(fmaxf(red[0], red[1]), fmaxf(red[2], red[3]));
    float s = fmaxf(amax / 7.f, 1e-8f);
    if (tid == 0) sa[t] = s;
    s8* o2 = a2 + (size_t)t * HID;
#pragma unroll
    for (int i = 0; i < 16; ++i) {
        float q = rintf(y[i] / s);
        q = fminf(fmaxf(q, -8.f), 7.f);
        o2[(half * 16 + i) * 128 + d] = (s8)(int)q;
    }
}

extern "C" void kernel_launch(void* const* d_in, const int* in_sizes, int n_in,
                              void* d_out, int out_size, void* d_ws, size_t ws_size,
                              hipStream_t stream) {
    const int* positions = (const int*)d_in[0];
    const float* hidden = (const float*)d_in[1];
    const int* wq = (const int*)d_in[2];
    const float* wq_s = (const float*)d_in[3];
    const int* wk = (const int*)d_in[4];
    const float* wk_s = (const float*)d_in[5];
    const int* wv = (const int*)d_in[6];
    const float* wv_s = (const float*)d_in[7];
    const int* wo = (const int*)d_in[8];
    const float* wo_s = (const float*)d_in[9];

    char* ws = (char*)d_ws;
    float* s_x = (float*)(ws);
    float* s_a = (float*)(ws + 8192);
    float* ctab = (float*)(ws + 16384);
    float* stab = (float*)(ws + 16384 + 524288);
    char* base1 = ws + 16384 + 1048576;
    s8* a8 = (s8*)base1;                                 // 8.39 MB
    float* q_f = (float*)(base1 + 8388608);              // 33.55 MB
    float* k_f = (float*)(base1 + 8388608 + 33554432);   // 8.39 MB
    char* X = base1 + 8388608 + 33554432 + 8388608;      // 16.78 MB
    char* W2 = X + 16777216;                             // 8.39 MB
    s8* wq8 = (s8*)X;                 // dead after QKV-GEMM
    u16* khf = (u16*)(X);             // written by ropek (after QKV-GEMM)
    u16* klf = (u16*)(X + 4194304);
    u16* vf = (u16*)(X + 8388608);    // fp16 frag V^T, written by QKV-GEMM
    s8* wk8 = (s8*)W2;
    s8* wv8 = (s8*)(W2 + 4194304);
    s8* wo8 = (s8*)X;                 // packed by k_hadq after attn

    k_pre<<<8704, 256, 0, stream>>>(positions, hidden, wq, wk, wv, ctab, stab,
                                    a8, s_x, wq8, wk8, wv8);
    k_qkv<<<dim3(16, 48), 256, 0, stream>>>(a8, wq8, wk8, wv8, s_x,
                                            wq_s, wk_s, wv_s, q_f, k_f, vf);
    k_ropek<<<T_SEQ, 256, 0, stream>>>(k_f, ctab, stab, khf, klf);
    k_attn<<<512, 512, 0, stream>>>(q_f, khf, klf, vf, ctab, stab);
    k_hadq<<<T_SEQ, 256, 0, stream>>>(q_f, a8, s_a, wo, wo8);
    k_gemm8<<<dim3(16, 32), 256, 0, stream>>>(a8, wo8, s_a, wo_s,
                                              (float*)d_out);
}